// Round 3
// baseline (628.923 us; speedup 1.0000x reference)
//
#include <hip/hip_runtime.h>
#include <hip/hip_bf16.h>
#include <stdint.h>
#include <math.h>

#define AS1 __attribute__((address_space(1)))
#define AS3 __attribute__((address_space(3)))

typedef __bf16 bf16_t;
typedef __bf16 bf16x8 __attribute__((ext_vector_type(8)));
typedef float f32x4 __attribute__((ext_vector_type(4)));

static constexpr int B_ = 16, N_ = 616, C_ = 768, H_ = 12, HD = 64, HID = 3072;
static constexpr int NP = 640;           // padded seq len for q/k/vT
static constexpr int M_REAL = B_ * N_;   // 9856
static constexpr int M_PAD = 9984;       // 39*256
static constexpr int NT_ = 40, NI_ = 576;

__device__ __forceinline__ void gl_lds16(const void* g, void* l) {
  __builtin_amdgcn_global_load_lds((const AS1 void*)(uintptr_t)g,
                                   (AS3 void*)(uint32_t)(uintptr_t)l, 16, 0, 0);
}
__device__ __forceinline__ f32x4 mfma16(bf16x8 a, bf16x8 b, f32x4 c) {
  return __builtin_amdgcn_mfma_f32_16x16x32_bf16(a, b, c, 0, 0, 0);
}
// gelu (erf) via tanh approx
__device__ __forceinline__ float gelu_f(float x) {
  float u = x * (0.7978845608f + 0.0356774081f * x * x);
  return x / (1.f + __expf(-2.f * u));
}

// ---------------------------------------------------------------- utilities
__global__ void cast_f32_bf16(const float* __restrict__ in, bf16_t* __restrict__ out, int n) {
  int i = blockIdx.x * blockDim.x + threadIdx.x;
  int st = gridDim.x * blockDim.x;
  for (; i < n; i += st) out[i] = (bf16_t)in[i];
}
__global__ void zero_f4(float4* __restrict__ p, int n4) {
  int i = blockIdx.x * blockDim.x + threadIdx.x;
  int st = gridDim.x * blockDim.x;
  float4 z = {0.f, 0.f, 0.f, 0.f};
  for (; i < n4; i += st) p[i] = z;
}

// ---------------------------------------------------------------- layernorms
__global__ __launch_bounds__(256) void ln_rows(const float* __restrict__ x,
                                               const float* __restrict__ g,
                                               const float* __restrict__ b,
                                               bf16_t* __restrict__ out) {
  int r = blockIdx.x, t = threadIdx.x;
  bf16_t* orow = out + (size_t)r * C_;
  if (r >= M_REAL) { orow[t] = (bf16_t)0.f; orow[t+256] = (bf16_t)0.f; orow[t+512] = (bf16_t)0.f; return; }
  const float* xr = x + (size_t)r * C_;
  float v0 = xr[t], v1 = xr[t + 256], v2 = xr[t + 512];
  float s = v0 + v1 + v2, ss = v0 * v0 + v1 * v1 + v2 * v2;
#pragma unroll
  for (int off = 32; off > 0; off >>= 1) { s += __shfl_xor(s, off); ss += __shfl_xor(ss, off); }
  __shared__ float sm[8];
  int w = t >> 6;
  if ((t & 63) == 0) { sm[w] = s; sm[4 + w] = ss; }
  __syncthreads();
  s = sm[0] + sm[1] + sm[2] + sm[3];
  ss = sm[4] + sm[5] + sm[6] + sm[7];
  float mean = s * (1.f / C_);
  float var = ss * (1.f / C_) - mean * mean;
  float ri = rsqrtf(var + 1e-5f);
  orow[t]       = (bf16_t)((v0 - mean) * ri * g[t]       + b[t]);
  orow[t + 256] = (bf16_t)((v1 - mean) * ri * g[t + 256] + b[t + 256]);
  orow[t + 512] = (bf16_t)((v2 - mean) * ri * g[t + 512] + b[t + 512]);
}

// LN2 + pack: packed rows [0,640)=text, [640,768)=zero pad, [768,9984)=image
__global__ __launch_bounds__(256) void ln2_pack(const float* __restrict__ x1,
                                                const float* __restrict__ gt, const float* __restrict__ bt,
                                                const float* __restrict__ gi, const float* __restrict__ bi,
                                                bf16_t* __restrict__ out) {
  int m = blockIdx.x, t = threadIdx.x;
  if (m >= M_REAL) {
    bf16_t* orow = out + (size_t)(640 + (m - M_REAL)) * C_;
    orow[t] = (bf16_t)0.f; orow[t+256] = (bf16_t)0.f; orow[t+512] = (bf16_t)0.f;
    return;
  }
  int b_ = m / N_, nn = m - b_ * N_;
  const float* g; const float* bb; int dest;
  if (nn < NT_) { dest = b_ * NT_ + nn; g = gt; bb = bt; }
  else          { dest = 768 + b_ * NI_ + (nn - NT_); g = gi; bb = bi; }
  const float* xr = x1 + (size_t)m * C_;
  float v0 = xr[t], v1 = xr[t + 256], v2 = xr[t + 512];
  float s = v0 + v1 + v2, ss = v0 * v0 + v1 * v1 + v2 * v2;
#pragma unroll
  for (int off = 32; off > 0; off >>= 1) { s += __shfl_xor(s, off); ss += __shfl_xor(ss, off); }
  __shared__ float sm[8];
  int w = t >> 6;
  if ((t & 63) == 0) { sm[w] = s; sm[4 + w] = ss; }
  __syncthreads();
  s = sm[0] + sm[1] + sm[2] + sm[3];
  ss = sm[4] + sm[5] + sm[6] + sm[7];
  float mean = s * (1.f / C_);
  float var = ss * (1.f / C_) - mean * mean;
  float ri = rsqrtf(var + 1e-5f);
  bf16_t* orow = out + (size_t)dest * C_;
  orow[t]       = (bf16_t)((v0 - mean) * ri * g[t]       + bb[t]);
  orow[t + 256] = (bf16_t)((v1 - mean) * ri * g[t + 256] + bb[t + 256]);
  orow[t + 512] = (bf16_t)((v2 - mean) * ri * g[t + 512] + bb[t + 512]);
}

// ---------------------------------------------------------------- v transpose
__global__ __launch_bounds__(256) void transpose_v(const bf16_t* __restrict__ v,
                                                   bf16_t* __restrict__ vT) {
  __shared__ bf16_t t[64][80];
  int n0 = blockIdx.x * 64, bh = blockIdx.y;
  int tid = threadIdx.x;
  int r0 = tid >> 2, c0 = (tid & 3) * 16;
  int n = n0 + r0;
#pragma unroll
  for (int cc = 0; cc < 2; ++cc) {
    bf16x8 vv;
    if (n < N_) vv = *(const bf16x8*)(v + ((size_t)bh * N_ + n) * HD + c0 + cc * 8);
    else {
#pragma unroll
      for (int e = 0; e < 8; ++e) vv[e] = (bf16_t)0.f;
    }
#pragma unroll
    for (int e = 0; e < 8; ++e) t[c0 + cc * 8 + e][r0] = vv[e];
  }
  __syncthreads();
  int d = tid >> 2, nc = (tid & 3) * 16;
  bf16_t* dst = vT + ((size_t)(bh * HD + d)) * NP + n0 + nc;
  *(bf16x8*)dst       = *(const bf16x8*)&t[d][nc];
  *(bf16x8*)(dst + 8) = *(const bf16x8*)&t[d][nc + 8];
}

// ---------------------------------------------------------------- GEMM 256x256, 8-phase
// SWZ=1: XOR-permuted global source + XOR'd ds_read (round-2 config, A/B control)
// SWZ=0: linear source + linear reads (m198 config; 16-way read conflicts tolerated)
struct EpiP {
  const float* bias;
  const float* bias_i;
  const float* bias2;
  const float* gamma;
  const float* xres;
  float* outf;
  bf16_t* ob0;
  bf16_t* ob1;
  bf16_t* ob2;
};

extern __shared__ char smem_raw[];

#define MFMA_QUAD(MH, NH, BV)                                                  \
  _Pragma("unroll") for (int i_ = 0; i_ < 4; ++i_)                             \
  _Pragma("unroll") for (int j_ = 0; j_ < 2; ++j_)                             \
  _Pragma("unroll") for (int kk_ = 0; kk_ < 2; ++kk_)                          \
    acc[(MH)*4 + i_][(NH)*2 + j_] =                                            \
        mfma16(av[i_][kk_], BV[j_][kk_], acc[(MH)*4 + i_][(NH)*2 + j_]);

#define LDA_FRAG(MH)                                                           \
  _Pragma("unroll") for (int i_ = 0; i_ < 4; ++i_)                             \
  _Pragma("unroll") for (int kk_ = 0; kk_ < 2; ++kk_) {                        \
    int R_ = wr * 128 + (MH)*64 + i_ * 16 + l16;                               \
    av[i_][kk_] = *(const bf16x8*)(AsS + R_ * 64 +                             \
                   ((kk_ * 32 + lq * 8) ^ (SWZ ? ((R_ & 7) << 3) : 0))); }

#define LDB_FRAG(NH, BV)                                                       \
  _Pragma("unroll") for (int j_ = 0; j_ < 2; ++j_)                             \
  _Pragma("unroll") for (int kk_ = 0; kk_ < 2; ++kk_) {                        \
    int R_ = wc * 64 + (NH)*32 + j_ * 16 + l16;                                \
    BV[j_][kk_] = *(const bf16x8*)(BsS + R_ * 64 +                             \
                   ((kk_ * 32 + lq * 8) ^ (SWZ ? ((R_ & 7) << 3) : 0))); }

template <int EPI, int SWZ>
__global__ __launch_bounds__(512, 2) void gemm256(const bf16_t* __restrict__ A,
                                                  const bf16_t* __restrict__ Bt,
                                                  const bf16_t* __restrict__ Bi,
                                                  int K, int tb, EpiP P) {
  bf16_t* As = (bf16_t*)smem_raw;
  bf16_t* Bs = As + 32768;
  const int tid = threadIdx.x, lane = tid & 63, w = tid >> 6;
  const int l16 = lane & 15, lq = lane >> 4;
  const int wr = w >> 2, wc = w & 3;
  const int m0 = blockIdx.x * 256, n0 = blockIdx.y * 256;
  const bf16_t* Bw = (blockIdx.x < tb) ? Bt : Bi;
  const int NTt = K >> 6;

  f32x4 acc[8][4] = {};

  auto stageA = [&](int slot, int half, int T) {
#pragma unroll
    for (int r = 0; r < 2; ++r) {
      int gb = r * 512 + w * 64;
      int g = gb + lane;
      int row = ((g >> 3) & 63) | (half << 6) | ((g >> 9) << 7);
      int cc = SWZ ? ((g & 7) ^ ((g >> 3) & 7)) : (g & 7);
      gl_lds16(A + (size_t)(m0 + row) * K + T * 64 + cc * 8,
               As + slot * 16384 + (size_t)(w * 64 + r * 1024 + half * 512) * 8);
    }
  };
  auto stageB = [&](int slot, int half, int T) {
#pragma unroll
    for (int r = 0; r < 2; ++r) {
      int gb = r * 512 + w * 64;
      int g = gb + lane;
      int row = ((g >> 3) & 31) | (half << 5) | (((g >> 8) & 3) << 6);
      int cc = SWZ ? ((g & 7) ^ ((g >> 3) & 7)) : (g & 7);
      gl_lds16(Bw + (size_t)(n0 + row) * K + T * 64 + cc * 8,
               Bs + slot * 16384 + (size_t)((gb & 255) + half * 256 + ((gb >> 8) & 3) * 512) * 8);
    }
  };

  // prologue: T0 full, T1 partial (B-h0(T1) arrives at T0.ph1)
  stageA(0, 0, 0); stageA(0, 1, 0); stageB(0, 0, 0); stageB(0, 1, 0);
  if (NTt > 1) {
    stageA(1, 0, 1); stageB(1, 1, 1); stageA(1, 1, 1);
    asm volatile("s_waitcnt vmcnt(6)" ::: "memory");
  } else {
    asm volatile("s_waitcnt vmcnt(0)" ::: "memory");
  }
  __builtin_amdgcn_s_barrier();

  for (int T = 0; T < NTt; ++T) {
    const int s = T & 1;
    const bf16_t* AsS = As + s * 16384;
    const bf16_t* BsS = Bs + s * 16384;
    bf16x8 av[4][2], bv0[2][2], bv1[2][2];

    // ph1: quadrant (0,0)
    LDA_FRAG(0);
    LDB_FRAG(0, bv0);
    if (T + 1 < NTt) stageB(s ^ 1, 0, T + 1);
    __builtin_amdgcn_s_barrier();
    asm volatile("s_waitcnt lgkmcnt(0)" ::: "memory");
    __builtin_amdgcn_sched_barrier(0);
    __builtin_amdgcn_s_setprio(1);
    MFMA_QUAD(0, 0, bv0);
    __builtin_amdgcn_s_setprio(0);
    __builtin_amdgcn_s_barrier();

    // ph2: quadrant (0,1)
    LDB_FRAG(1, bv1);
    if (T + 2 < NTt) stageA(s, 0, T + 2);
    __builtin_amdgcn_s_barrier();
    asm volatile("s_waitcnt lgkmcnt(0)" ::: "memory");
    __builtin_amdgcn_sched_barrier(0);
    __builtin_amdgcn_s_setprio(1);
    MFMA_QUAD(0, 1, bv1);
    __builtin_amdgcn_s_setprio(0);
    __builtin_amdgcn_s_barrier();

    // ph3: quadrant (1,1)
    LDA_FRAG(1);
    if (T + 2 < NTt) stageB(s, 1, T + 2);
    __builtin_amdgcn_s_barrier();
    asm volatile("s_waitcnt lgkmcnt(0)" ::: "memory");
    __builtin_amdgcn_sched_barrier(0);
    __builtin_amdgcn_s_setprio(1);
    MFMA_QUAD(1, 1, bv1);
    __builtin_amdgcn_s_setprio(0);
    __builtin_amdgcn_s_barrier();

    // ph4: quadrant (1,0)
    LDB_FRAG(0, bv0);
    if (T + 2 < NTt) stageA(s, 1, T + 2);
    __builtin_amdgcn_s_barrier();
    asm volatile("s_waitcnt lgkmcnt(0)" ::: "memory");
    __builtin_amdgcn_sched_barrier(0);
    __builtin_amdgcn_s_setprio(1);
    MFMA_QUAD(1, 0, bv0);
    __builtin_amdgcn_s_setprio(0);
    if (T + 2 < NTt) asm volatile("s_waitcnt vmcnt(6)" ::: "memory");
    else             asm volatile("s_waitcnt vmcnt(0)" ::: "memory");
    __builtin_amdgcn_s_barrier();
  }

  // epilogue
  const float* bsel = (blockIdx.x < tb) ? P.bias : P.bias_i;
  (void)bsel;
  int which = n0 / C_;
#pragma unroll
  for (int im = 0; im < 8; ++im) {
    int mrow0 = m0 + wr * 128 + (im >> 2) * 64 + (im & 3) * 16 + lq * 4;
#pragma unroll
    for (int jn = 0; jn < 4; ++jn) {
      int jc = n0 + wc * 64 + (jn >> 1) * 32 + (jn & 1) * 16 + l16;
#pragma unroll
      for (int rr = 0; rr < 4; ++rr) {
        int m = mrow0 + rr;
        float v = acc[im][jn][rr];
        if constexpr (EPI == 0) {
          if (m < M_REAL) {
            int b_ = m / N_, nn = m - b_ * N_;
            int jj = jc - which * C_;
            int hh = jj >> 6, d = jj & 63;
            int bh = b_ * H_ + hh;
            if (which == 0) {
              P.ob0[((size_t)bh * NP + nn) * HD + d] = (bf16_t)((v + P.bias[jj]) * 0.125f);
            } else if (which == 1) {
              P.ob1[((size_t)bh * NP + nn) * HD + d] = (bf16_t)v;
            } else {
              P.ob2[((size_t)bh * N_ + nn) * HD + d] = (bf16_t)(v + P.bias2[jj]);
            }
          }
        } else if constexpr (EPI == 1) {
          if (m < M_REAL) {
            size_t idx = (size_t)m * C_ + jc;
            P.outf[idx] = P.xres[idx] + P.gamma[jc] * (v + P.bias[jc]);
          }
        } else if constexpr (EPI == 2) {
          P.ob0[(size_t)m * HID + jc] = (bf16_t)gelu_f(v + bsel[jc]);
        } else {
          int orig = -1;
          if (m < 640)      orig = (m / NT_) * N_ + (m - (m / NT_) * NT_);
          else if (m >= 768) {
            int mi = m - 768;
            int bb = mi / NI_;
            orig = bb * N_ + NT_ + (mi - bb * NI_);
          }
          if (orig >= 0) {
            size_t idx = (size_t)orig * C_ + jc;
            P.outf[idx] = P.xres[idx] + P.gamma[jc] * (v + bsel[jc]);
          }
        }
      }
    }
  }
}

// ---------------------------------------------------------------- attention (validated)
__global__ __launch_bounds__(256) void attn_fwd(const bf16_t* __restrict__ qb,
                                                const bf16_t* __restrict__ kb,
                                                const bf16_t* __restrict__ vT,
                                                const float* __restrict__ rel_bias,
                                                bf16_t* __restrict__ o_mat) {
  __shared__ bf16_t qs[64 * 64], ks[64 * 64], vs[64 * 64];
  __shared__ bf16_t ps[4][16 * 64];
  const int tid = threadIdx.x, lane = tid & 63, w = tid >> 6;
  const int l16 = lane & 15, lq = lane >> 4;
  const int qt = blockIdx.x, bh = blockIdx.y;
  const int b_ = bh / H_, h = bh - b_ * H_;
  const int q0 = qt * 64;

  const bf16_t* qsrc = qb + ((size_t)bh * NP + q0) * HD;
#pragma unroll
  for (int it = 0; it < 2; ++it) {
    int cb = it * 256 + w * 64, c = cb + lane;
    gl_lds16(qsrc + c * 8, qs + cb * 8);
  }
  __syncthreads();
  bf16x8 aq[2];
  aq[0] = *(const bf16x8*)(qs + (w * 16 + l16) * 64 + 0 + lq * 8);
  aq[1] = *(const bf16x8*)(qs + (w * 16 + l16) * 64 + 32 + lq * 8);

  float mrun[4], lrun[4];
  f32x4 oacc[4] = {};
#pragma unroll
  for (int r = 0; r < 4; ++r) { mrun[r] = -3e38f; lrun[r] = 0.f; }

  const int qrow_base = q0 + w * 16 + lq * 4;
  const float* biasr = rel_bias + (size_t)h * N_ * N_;

  for (int kt = 0; kt < NP / 64; ++kt) {
    int n0k = kt * 64;
    const bf16_t* ksrc = kb + ((size_t)bh * NP + n0k) * HD;
#pragma unroll
    for (int it = 0; it < 2; ++it) {
      int cb = it * 256 + w * 64, c = cb + lane;
      gl_lds16(ksrc + c * 8, ks + cb * 8);
      int d = c >> 3, kc = (c & 7) << 3;
      gl_lds16(vT + ((size_t)bh * HD + d) * NP + n0k + kc, vs + cb * 8);
    }
    __syncthreads();

    f32x4 sf[4];
#pragma unroll
    for (int f = 0; f < 4; ++f) {
      f32x4 z = {};
#pragma unroll
      for (int kk = 0; kk < 2; ++kk) {
        bf16x8 bk = *(const bf16x8*)(ks + (f * 16 + l16) * 64 + kk * 32 + lq * 8);
        z = mfma16(aq[kk], bk, z);
      }
      sf[f] = z;
    }
    float pm[4];
#pragma unroll
    for (int r = 0; r < 4; ++r) pm[r] = -3e38f;
#pragma unroll
    for (int f = 0; f < 4; ++f) {
      int kcol = n0k + f * 16 + l16;
#pragma unroll
      for (int r = 0; r < 4; ++r) {
        int qg = qrow_base + r;
        int qc = qg < N_ ? qg : (N_ - 1);
        float sv = (kcol < N_) ? (sf[f][r] + biasr[(size_t)qc * N_ + kcol]) : -3e38f;
        sf[f][r] = sv;
        pm[r] = fmaxf(pm[r], sv);
      }
    }
#pragma unroll
    for (int off = 1; off < 16; off <<= 1)
#pragma unroll
      for (int r = 0; r < 4; ++r)
        pm[r] = fmaxf(pm[r], __shfl_xor(pm[r], off, 16));

    float alpha[4], lsum[4];
#pragma unroll
    for (int r = 0; r < 4; ++r) {
      float mnew = fmaxf(mrun[r], pm[r]);
      alpha[r] = __expf(mrun[r] - mnew);
      mrun[r] = mnew;
      lsum[r] = 0.f;
    }
#pragma unroll
    for (int f = 0; f < 4; ++f)
#pragma unroll
      for (int r = 0; r < 4; ++r) {
        float p = __expf(sf[f][r] - mrun[r]);
        sf[f][r] = p;
        lsum[r] += p;
      }
#pragma unroll
    for (int off = 1; off < 16; off <<= 1)
#pragma unroll
      for (int r = 0; r < 4; ++r)
        lsum[r] += __shfl_xor(lsum[r], off, 16);
#pragma unroll
    for (int r = 0; r < 4; ++r) lrun[r] = lrun[r] * alpha[r] + lsum[r];
#pragma unroll
    for (int df = 0; df < 4; ++df)
#pragma unroll
      for (int r = 0; r < 4; ++r) oacc[df][r] *= alpha[r];

    bf16_t* psw = ps[w];
#pragma unroll
    for (int f = 0; f < 4; ++f)
#pragma unroll
      for (int r = 0; r < 4; ++r)
        psw[(lq * 4 + r) * 64 + f * 16 + l16] = (bf16_t)sf[f][r];
    __syncthreads();

#pragma unroll
    for (int kk = 0; kk < 2; ++kk) {
      bf16x8 pa = *(const bf16x8*)(psw + l16 * 64 + kk * 32 + lq * 8);
#pragma unroll
      for (int df = 0; df < 4; ++df) {
        bf16x8 bv = *(const bf16x8*)(vs + (df * 16 + l16) * 64 + kk * 32 + lq * 8);
        oacc[df] = mfma16(pa, bv, oacc[df]);
      }
    }
    __syncthreads();
  }

#pragma unroll
  for (int r = 0; r < 4; ++r) {
    int qg = qrow_base + r;
    if (qg < N_) {
      float rl = 1.f / lrun[r];
      size_t orow = ((size_t)(b_ * N_ + qg)) * C_ + h * HD;
#pragma unroll
      for (int df = 0; df < 4; ++df)
        o_mat[orow + df * 16 + l16] = (bf16_t)(oacc[df][r] * rl);
    }
  }
}

// ---------------------------------------------------------------- launch
extern "C" void kernel_launch(void* const* d_in, const int* in_sizes, int n_in,
                              void* d_out, int out_size, void* d_ws, size_t ws_size,
                              hipStream_t stream) {
  const float* x      = (const float*)d_in[0];
  const float* rel    = (const float*)d_in[1];
  const float* ln1_g  = (const float*)d_in[2];
  const float* ln1_b  = (const float*)d_in[3];
  const float* w_qkv  = (const float*)d_in[4];
  const float* q_bias = (const float*)d_in[5];
  const float* v_bias = (const float*)d_in[6];
  const float* w_proj = (const float*)d_in[7];
  const float* b_proj = (const float*)d_in[8];
  const float* gamma1 = (const float*)d_in[9];
  const float* gamma2 = (const float*)d_in[10];
  const float* ln2t_g = (const float*)d_in[11];
  const float* ln2t_b = (const float*)d_in[12];
  const float* ln2i_g = (const float*)d_in[13];
  const float* ln2i_b = (const float*)d_in[14];
  const float* wt1    = (const float*)d_in[15];
  const float* bt1    = (const float*)d_in[16];
  const float* wt2    = (const float*)d_in[17];
  const float* bt2    = (const float*)d_in[18];
  const float* wi1    = (const float*)d_in[19];
  const float* bi1    = (const float*)d_in[20];
  const float* wi2    = (const float*)d_in[21];
  const float* bi2    = (const float*)d_in[22];
  float* out = (float*)d_out;

  char* ws = (char*)d_ws;
  bf16_t* wqkvb  = (bf16_t*)(ws + 0);
  bf16_t* wprojb = (bf16_t*)(ws + 3538944);
  bf16_t* wt1b   = (bf16_t*)(ws + 4718592);
  bf16_t* wi1b   = (bf16_t*)(ws + 9437184);
  bf16_t* wt2b   = (bf16_t*)(ws + 14155776);
  bf16_t* wi2b   = (bf16_t*)(ws + 18874368);
  bf16_t* n1     = (bf16_t*)(ws + 23592960);    // 9984x768 bf16; also n2p, o_mat
  float*  x1     = (float*) (ws + 38928384);    // 30,277,632; head doubles as vtmp
  bf16_t* qbuf   = (bf16_t*)(ws + 69206016);
  bf16_t* kbuf   = (bf16_t*)(ws + 84934656);
  bf16_t* vTbuf  = (bf16_t*)(ws + 100663296);
  bf16_t* vtmp   = (bf16_t*)(ws + 38928384);
  bf16_t* o_mat  = n1;
  bf16_t* n2p    = n1;
  bf16_t* hbuf   = qbuf;

  hipFuncSetAttribute((const void*)gemm256<0,0>, hipFuncAttributeMaxDynamicSharedMemorySize, 131072);
  hipFuncSetAttribute((const void*)gemm256<1,1>, hipFuncAttributeMaxDynamicSharedMemorySize, 131072);
  hipFuncSetAttribute((const void*)gemm256<2,0>, hipFuncAttributeMaxDynamicSharedMemorySize, 131072);
  hipFuncSetAttribute((const void*)gemm256<3,0>, hipFuncAttributeMaxDynamicSharedMemorySize, 131072);

  cast_f32_bf16<<<1024, 256, 0, stream>>>(w_qkv,  wqkvb,  3 * C_ * C_);
  cast_f32_bf16<<<512,  256, 0, stream>>>(w_proj, wprojb, C_ * C_);
  cast_f32_bf16<<<1024, 256, 0, stream>>>(wt1, wt1b, HID * C_);
  cast_f32_bf16<<<1024, 256, 0, stream>>>(wi1, wi1b, HID * C_);
  cast_f32_bf16<<<1024, 256, 0, stream>>>(wt2, wt2b, C_ * HID);
  cast_f32_bf16<<<1024, 256, 0, stream>>>(wi2, wi2b, C_ * HID);
  zero_f4<<<2048, 256, 0, stream>>>((float4*)qbuf, 47185920 / 16);
  ln_rows<<<M_PAD, 256, 0, stream>>>(x, ln1_g, ln1_b, n1);

  // QKV GEMM — LINEAR variant (A/B: big GEMMs linear, proj swizzled)
  {
    EpiP P{}; P.bias = q_bias; P.bias2 = v_bias;
    P.ob0 = qbuf; P.ob1 = kbuf; P.ob2 = vtmp;
    gemm256<0,0><<<dim3(M_PAD / 256, (3 * C_) / 256), 512, 131072, stream>>>(n1, wqkvb, wqkvb, C_, 0, P);
  }
  transpose_v<<<dim3(NP / 64, B_ * H_), 256, 0, stream>>>(vtmp, vTbuf);
  attn_fwd<<<dim3(NP / 64, B_ * H_), 256, 0, stream>>>(qbuf, kbuf, vTbuf, rel, o_mat);
  zero_f4<<<64, 256, 0, stream>>>((float4*)(ws + 38731776), 196608 / 16);

  // proj — SWIZZLED variant (round-2 control)
  {
    EpiP P{}; P.bias = b_proj; P.bias_i = b_proj; P.gamma = gamma1; P.xres = x; P.outf = x1;
    gemm256<1,1><<<dim3(M_PAD / 256, C_ / 256), 512, 131072, stream>>>(o_mat, wprojb, wprojb, C_, 0, P);
  }
  ln2_pack<<<M_PAD, 256, 0, stream>>>(x1, ln2t_g, ln2t_b, ln2i_g, ln2i_b, n2p);

  // MLP fc1 — LINEAR
  {
    EpiP P{}; P.bias = bt1; P.bias_i = bi1; P.ob0 = hbuf;
    gemm256<2,0><<<dim3(M_PAD / 256, HID / 256), 512, 131072, stream>>>(n2p, wt1b, wi1b, C_, 3, P);
  }
  // MLP fc2 — LINEAR
  {
    EpiP P{}; P.bias = bt2; P.bias_i = bi2; P.gamma = gamma2; P.xres = x1; P.outf = out;
    gemm256<3,0><<<dim3(M_PAD / 256, C_ / 256), 512, 131072, stream>>>(hbuf, wt2b, wi2b, HID, 3, P);
  }
}

// Round 4
// 515.057 us; speedup vs baseline: 1.2211x; 1.2211x over previous
//
#include <hip/hip_runtime.h>
#include <hip/hip_bf16.h>
#include <stdint.h>
#include <math.h>

#define AS1 __attribute__((address_space(1)))
#define AS3 __attribute__((address_space(3)))

typedef __bf16 bf16_t;
typedef __bf16 bf16x8 __attribute__((ext_vector_type(8)));
typedef float f32x4 __attribute__((ext_vector_type(4)));

static constexpr int B_ = 16, N_ = 616, C_ = 768, H_ = 12, HD = 64, HID = 3072;
static constexpr int NP = 640;           // padded seq len for q/k/vT
static constexpr int M_REAL = B_ * N_;   // 9856 = 77*128
static constexpr int M_PAD = 9984;       // 78*128 (packed MLP rows)
static constexpr int NT_ = 40, NI_ = 576;

__device__ __forceinline__ void gl_lds16(const void* g, void* l) {
  __builtin_amdgcn_global_load_lds((const AS1 void*)(uintptr_t)g,
                                   (AS3 void*)(uint32_t)(uintptr_t)l, 16, 0, 0);
}
__device__ __forceinline__ f32x4 mfma16(bf16x8 a, bf16x8 b, f32x4 c) {
  return __builtin_amdgcn_mfma_f32_16x16x32_bf16(a, b, c, 0, 0, 0);
}
__device__ __forceinline__ float gelu_f(float x) {
  float u = x * (0.7978845608f + 0.0356774081f * x * x);
  return x / (1.f + __expf(-2.f * u));
}

// ---------------------------------------------------------------- utilities
__global__ void cast_f32_bf16(const float* __restrict__ in, bf16_t* __restrict__ out, int n) {
  int i = blockIdx.x * blockDim.x + threadIdx.x;
  int st = gridDim.x * blockDim.x;
  for (; i < n; i += st) out[i] = (bf16_t)in[i];
}

// ---------------------------------------------------------------- layernorms
__global__ __launch_bounds__(256) void ln_rows(const float* __restrict__ x,
                                               const float* __restrict__ g,
                                               const float* __restrict__ b,
                                               bf16_t* __restrict__ out) {
  int r = blockIdx.x, t = threadIdx.x;
  bf16_t* orow = out + (size_t)r * C_;
  const float* xr = x + (size_t)r * C_;
  float v0 = xr[t], v1 = xr[t + 256], v2 = xr[t + 512];
  float s = v0 + v1 + v2, ss = v0 * v0 + v1 * v1 + v2 * v2;
#pragma unroll
  for (int off = 32; off > 0; off >>= 1) { s += __shfl_xor(s, off); ss += __shfl_xor(ss, off); }
  __shared__ float sm[8];
  int w = t >> 6;
  if ((t & 63) == 0) { sm[w] = s; sm[4 + w] = ss; }
  __syncthreads();
  s = sm[0] + sm[1] + sm[2] + sm[3];
  ss = sm[4] + sm[5] + sm[6] + sm[7];
  float mean = s * (1.f / C_);
  float var = ss * (1.f / C_) - mean * mean;
  float ri = rsqrtf(var + 1e-5f);
  orow[t]       = (bf16_t)((v0 - mean) * ri * g[t]       + b[t]);
  orow[t + 256] = (bf16_t)((v1 - mean) * ri * g[t + 256] + b[t + 256]);
  orow[t + 512] = (bf16_t)((v2 - mean) * ri * g[t + 512] + b[t + 512]);
}

// LN2 + pack: packed rows [0,640)=text, [640,768)=zero pad, [768,9984)=image
__global__ __launch_bounds__(256) void ln2_pack(const float* __restrict__ x1,
                                                const float* __restrict__ gt, const float* __restrict__ bt,
                                                const float* __restrict__ gi, const float* __restrict__ bi,
                                                bf16_t* __restrict__ out) {
  int m = blockIdx.x, t = threadIdx.x;
  if (m >= M_REAL) {
    bf16_t* orow = out + (size_t)(640 + (m - M_REAL)) * C_;
    orow[t] = (bf16_t)0.f; orow[t+256] = (bf16_t)0.f; orow[t+512] = (bf16_t)0.f;
    return;
  }
  int b_ = m / N_, nn = m - b_ * N_;
  const float* g; const float* bb; int dest;
  if (nn < NT_) { dest = b_ * NT_ + nn; g = gt; bb = bt; }
  else          { dest = 768 + b_ * NI_ + (nn - NT_); g = gi; bb = bi; }
  const float* xr = x1 + (size_t)m * C_;
  float v0 = xr[t], v1 = xr[t + 256], v2 = xr[t + 512];
  float s = v0 + v1 + v2, ss = v0 * v0 + v1 * v1 + v2 * v2;
#pragma unroll
  for (int off = 32; off > 0; off >>= 1) { s += __shfl_xor(s, off); ss += __shfl_xor(ss, off); }
  __shared__ float sm[8];
  int w = t >> 6;
  if ((t & 63) == 0) { sm[w] = s; sm[4 + w] = ss; }
  __syncthreads();
  s = sm[0] + sm[1] + sm[2] + sm[3];
  ss = sm[4] + sm[5] + sm[6] + sm[7];
  float mean = s * (1.f / C_);
  float var = ss * (1.f / C_) - mean * mean;
  float ri = rsqrtf(var + 1e-5f);
  bf16_t* orow = out + (size_t)dest * C_;
  orow[t]       = (bf16_t)((v0 - mean) * ri * g[t]       + bb[t]);
  orow[t + 256] = (bf16_t)((v1 - mean) * ri * g[t + 256] + bb[t + 256]);
  orow[t + 512] = (bf16_t)((v2 - mean) * ri * g[t + 512] + bb[t + 512]);
}

// ---------------------------------------------------------------- v transpose
// vT[bh][d][0..640) <- v[bh][n<616][d], zeros for n>=616 (so PV pads are clean)
__global__ __launch_bounds__(256) void transpose_v(const bf16_t* __restrict__ v,
                                                   bf16_t* __restrict__ vT) {
  __shared__ bf16_t t[64][80];
  int n0 = blockIdx.x * 64, bh = blockIdx.y;
  int tid = threadIdx.x;
  int r0 = tid >> 2, c0 = (tid & 3) * 16;
  int n = n0 + r0;
#pragma unroll
  for (int cc = 0; cc < 2; ++cc) {
    bf16x8 vv;
    if (n < N_) vv = *(const bf16x8*)(v + ((size_t)bh * N_ + n) * HD + c0 + cc * 8);
    else {
#pragma unroll
      for (int e = 0; e < 8; ++e) vv[e] = (bf16_t)0.f;
    }
#pragma unroll
    for (int e = 0; e < 8; ++e) t[c0 + cc * 8 + e][r0] = vv[e];
  }
  __syncthreads();
  int d = tid >> 2, nc = (tid & 3) * 16;
  bf16_t* dst = vT + ((size_t)(bh * HD + d)) * NP + n0 + nc;
  *(bf16x8*)dst       = *(const bf16x8*)&t[d][nc];
  *(bf16x8*)(dst + 8) = *(const bf16x8*)&t[d][nc + 8];
}

// ---------------------------------------------------------------- GEMM 128x128, 2-phase dbuf
// Fragment-ordered LDS: tile staged in MFMA-fragment order, so every
// ds_read_b128 is base + lane*16B + imm (linear, conflict-free).
// A-tile granule slot s in [0,1024): h=s>>9, fid=(s>>6)&7 (i=fid>>1,kk=fid&1),
//   holds A[m0 + h*64 + i*16 + (s&15)][64k-col kk*4 + ((s>>4)&3)]  (16B granule)
// B identical with cols. Buf c at c*32KB; B at +16KB.
struct EpiP {
  const float* bias;
  const float* bias_i;
  const float* bias2;
  const float* gamma;
  const float* xres;
  float* outf;
  bf16_t* ob0;
  bf16_t* ob1;
  bf16_t* ob2;
};

extern __shared__ char smem_raw[];

template <int EPI>
__global__ __launch_bounds__(256, 2) void gemm128(const bf16_t* __restrict__ A,
                                                  const bf16_t* __restrict__ Bt,
                                                  const bf16_t* __restrict__ Bi,
                                                  int K, int tb, EpiP P) {
  bf16_t* sm = (bf16_t*)smem_raw;   // 2 bufs x 16384 elements (32KB each)
  const int tid = threadIdx.x, lane = tid & 63, w = tid >> 6;
  const int l16 = lane & 15, lq = lane >> 4;
  const int wr = w >> 1, wc = w & 1;
  const int m0 = blockIdx.x * 128, n0 = blockIdx.y * 128;
  const bf16_t* Bw = (blockIdx.x < tb) ? Bt : Bi;
  const int NTk = K >> 6;

  f32x4 acc[4][4] = {};

  // per-thread staging source offsets (element units), frag-order decode
  size_t aoff[4], boff[4];
  int ldsoff[4];
#pragma unroll
  for (int r = 0; r < 4; ++r) {
    int slot = w * 256 + r * 64 + lane;
    int h = slot >> 9, fid = (slot >> 6) & 7;
    int i = fid >> 1, kk = fid & 1;
    int rowc = h * 64 + i * 16 + (lane & 15);     // row (A) / col (B) in tile
    int gc = kk * 4 + (lane >> 4);                // 16B granule within K=64
    aoff[r] = (size_t)(m0 + rowc) * K + gc * 8;
    boff[r] = (size_t)(n0 + rowc) * K + gc * 8;
    ldsoff[r] = (w * 256 + r * 64) * 8;           // wave-uniform elem offset
  }

  auto STAGE = [&](int c, int t) {
    int cb = c * 16384;
    size_t kadd = (size_t)t * 64;
#pragma unroll
    for (int r = 0; r < 4; ++r) gl_lds16(A + aoff[r] + kadd, sm + cb + ldsoff[r]);
#pragma unroll
    for (int r = 0; r < 4; ++r) gl_lds16(Bw + boff[r] + kadd, sm + cb + 8192 + ldsoff[r]);
  };

  STAGE(0, 0);
  asm volatile("s_waitcnt vmcnt(0)" ::: "memory");
  __builtin_amdgcn_s_barrier();

  int c = 0;
  for (int t = 0; t < NTk; ++t) {
    if (t + 1 < NTk) STAGE(c ^ 1, t + 1);
    const bf16_t* Ac = sm + c * 16384 + ((size_t)wr * 512 + lane) * 8;
    const bf16_t* Bc = sm + c * 16384 + 8192 + ((size_t)wc * 512 + lane) * 8;
    bf16x8 av[4][2], bv[4][2];
#pragma unroll
    for (int i = 0; i < 4; ++i) {
#pragma unroll
      for (int kk = 0; kk < 2; ++kk) {
        av[i][kk] = *(const bf16x8*)(Ac + (i * 2 + kk) * 512);
        bv[i][kk] = *(const bf16x8*)(Bc + (i * 2 + kk) * 512);
      }
    }
#pragma unroll
    for (int kk = 0; kk < 2; ++kk)
#pragma unroll
      for (int i = 0; i < 4; ++i)
#pragma unroll
        for (int j = 0; j < 4; ++j)
          acc[i][j] = mfma16(av[i][kk], bv[j][kk], acc[i][j]);
    asm volatile("s_waitcnt vmcnt(0)" ::: "memory");
    __builtin_amdgcn_s_barrier();
    c ^= 1;
  }

  // epilogue: C/D frag: row = 16i + lq*4 + rr, col = 16j + l16  (wave 64x64)
  const float* bsel = (blockIdx.x < tb) ? P.bias : P.bias_i;
  (void)bsel;
  int which = n0 / C_;
#pragma unroll
  for (int i = 0; i < 4; ++i) {
    int mb = m0 + wr * 64 + i * 16 + lq * 4;
#pragma unroll
    for (int j = 0; j < 4; ++j) {
      int jc = n0 + wc * 64 + j * 16 + l16;
#pragma unroll
      for (int rr = 0; rr < 4; ++rr) {
        int m = mb + rr;
        float v = acc[i][j][rr];
        if constexpr (EPI == 0) {       // QKV split; q,k -> [bh][640][64], v -> [bh][616][64]
          int b_ = m / N_, nn = m - b_ * N_;
          int jj = jc - which * C_;
          int hh = jj >> 6, d = jj & 63;
          int bh = b_ * H_ + hh;
          if (which == 0) {
            P.ob0[((size_t)bh * NP + nn) * HD + d] = (bf16_t)((v + P.bias[jj]) * 0.125f);
          } else if (which == 1) {
            P.ob1[((size_t)bh * NP + nn) * HD + d] = (bf16_t)v;
          } else {
            P.ob2[((size_t)bh * N_ + nn) * HD + d] = (bf16_t)(v + P.bias2[jj]);
          }
        } else if constexpr (EPI == 1) {  // proj: x1 = x + gamma1*(o+b)
          size_t idx = (size_t)m * C_ + jc;
          P.outf[idx] = P.xres[idx] + P.gamma[jc] * (v + P.bias[jc]);
        } else if constexpr (EPI == 2) {  // mlp1: gelu -> hbuf
          P.ob0[(size_t)m * HID + jc] = (bf16_t)gelu_f(v + bsel[jc]);
        } else {                          // mlp2: residual scatter to d_out
          int orig = -1;
          if (m < 640)      orig = (m / NT_) * N_ + (m - (m / NT_) * NT_);
          else if (m >= 768) {
            int mi = m - 768;
            int bb = mi / NI_;
            orig = bb * N_ + NT_ + (mi - bb * NI_);
          }
          if (orig >= 0) {
            size_t idx = (size_t)orig * C_ + jc;
            P.outf[idx] = P.xres[idx] + P.gamma[jc] * (v + bsel[jc]);
          }
        }
      }
    }
  }
}

// ---------------------------------------------------------------- attention (validated r1)
__global__ __launch_bounds__(256) void attn_fwd(const bf16_t* __restrict__ qb,
                                                const bf16_t* __restrict__ kb,
                                                const bf16_t* __restrict__ vT,
                                                const float* __restrict__ rel_bias,
                                                bf16_t* __restrict__ o_mat) {
  __shared__ bf16_t qs[64 * 64], ks[64 * 64], vs[64 * 64];
  __shared__ bf16_t ps[4][16 * 64];
  const int tid = threadIdx.x, lane = tid & 63, w = tid >> 6;
  const int l16 = lane & 15, lq = lane >> 4;
  const int qt = blockIdx.x, bh = blockIdx.y;
  const int b_ = bh / H_, h = bh - b_ * H_;
  const int q0 = qt * 64;

  const bf16_t* qsrc = qb + ((size_t)bh * NP + q0) * HD;
#pragma unroll
  for (int it = 0; it < 2; ++it) {
    int cb = it * 256 + w * 64, c = cb + lane;
    gl_lds16(qsrc + c * 8, qs + cb * 8);
  }
  __syncthreads();
  bf16x8 aq[2];
  aq[0] = *(const bf16x8*)(qs + (w * 16 + l16) * 64 + 0 + lq * 8);
  aq[1] = *(const bf16x8*)(qs + (w * 16 + l16) * 64 + 32 + lq * 8);

  float mrun[4], lrun[4];
  f32x4 oacc[4] = {};
#pragma unroll
  for (int r = 0; r < 4; ++r) { mrun[r] = -3e38f; lrun[r] = 0.f; }

  const int qrow_base = q0 + w * 16 + lq * 4;
  const float* biasr = rel_bias + (size_t)h * N_ * N_;

  for (int kt = 0; kt < NP / 64; ++kt) {
    int n0k = kt * 64;
    const bf16_t* ksrc = kb + ((size_t)bh * NP + n0k) * HD;
#pragma unroll
    for (int it = 0; it < 2; ++it) {
      int cb = it * 256 + w * 64, c = cb + lane;
      gl_lds16(ksrc + c * 8, ks + cb * 8);
      int d = c >> 3, kc = (c & 7) << 3;
      gl_lds16(vT + ((size_t)bh * HD + d) * NP + n0k + kc, vs + cb * 8);
    }
    __syncthreads();

    f32x4 sf[4];
#pragma unroll
    for (int f = 0; f < 4; ++f) {
      f32x4 z = {};
#pragma unroll
      for (int kk = 0; kk < 2; ++kk) {
        bf16x8 bk = *(const bf16x8*)(ks + (f * 16 + l16) * 64 + kk * 32 + lq * 8);
        z = mfma16(aq[kk], bk, z);
      }
      sf[f] = z;
    }
    float pm[4];
#pragma unroll
    for (int r = 0; r < 4; ++r) pm[r] = -3e38f;
#pragma unroll
    for (int f = 0; f < 4; ++f) {
      int kcol = n0k + f * 16 + l16;
#pragma unroll
      for (int r = 0; r < 4; ++r) {
        int qg = qrow_base + r;
        int qc = qg < N_ ? qg : (N_ - 1);
        float sv = (kcol < N_) ? (sf[f][r] + biasr[(size_t)qc * N_ + kcol]) : -3e38f;
        sf[f][r] = sv;
        pm[r] = fmaxf(pm[r], sv);
      }
    }
#pragma unroll
    for (int off = 1; off < 16; off <<= 1)
#pragma unroll
      for (int r = 0; r < 4; ++r)
        pm[r] = fmaxf(pm[r], __shfl_xor(pm[r], off, 16));

    float alpha[4], lsum[4];
#pragma unroll
    for (int r = 0; r < 4; ++r) {
      float mnew = fmaxf(mrun[r], pm[r]);
      alpha[r] = __expf(mrun[r] - mnew);
      mrun[r] = mnew;
      lsum[r] = 0.f;
    }
#pragma unroll
    for (int f = 0; f < 4; ++f)
#pragma unroll
      for (int r = 0; r < 4; ++r) {
        float p = __expf(sf[f][r] - mrun[r]);
        sf[f][r] = p;
        lsum[r] += p;
      }
#pragma unroll
    for (int off = 1; off < 16; off <<= 1)
#pragma unroll
      for (int r = 0; r < 4; ++r)
        lsum[r] += __shfl_xor(lsum[r], off, 16);
#pragma unroll
    for (int r = 0; r < 4; ++r) lrun[r] = lrun[r] * alpha[r] + lsum[r];
#pragma unroll
    for (int df = 0; df < 4; ++df)
#pragma unroll
      for (int r = 0; r < 4; ++r) oacc[df][r] *= alpha[r];

    bf16_t* psw = ps[w];
#pragma unroll
    for (int f = 0; f < 4; ++f)
#pragma unroll
      for (int r = 0; r < 4; ++r)
        psw[(lq * 4 + r) * 64 + f * 16 + l16] = (bf16_t)sf[f][r];
    __syncthreads();

#pragma unroll
    for (int kk = 0; kk < 2; ++kk) {
      bf16x8 pa = *(const bf16x8*)(psw + l16 * 64 + kk * 32 + lq * 8);
#pragma unroll
      for (int df = 0; df < 4; ++df) {
        bf16x8 bv = *(const bf16x8*)(vs + (df * 16 + l16) * 64 + kk * 32 + lq * 8);
        oacc[df] = mfma16(pa, bv, oacc[df]);
      }
    }
    __syncthreads();
  }

#pragma unroll
  for (int r = 0; r < 4; ++r) {
    int qg = qrow_base + r;
    if (qg < N_) {
      float rl = 1.f / lrun[r];
      size_t orow = ((size_t)(b_ * N_ + qg)) * C_ + h * HD;
#pragma unroll
      for (int df = 0; df < 4; ++df)
        o_mat[orow + df * 16 + l16] = (bf16_t)(oacc[df][r] * rl);
    }
  }
}

// ---------------------------------------------------------------- launch
extern "C" void kernel_launch(void* const* d_in, const int* in_sizes, int n_in,
                              void* d_out, int out_size, void* d_ws, size_t ws_size,
                              hipStream_t stream) {
  const float* x      = (const float*)d_in[0];
  const float* rel    = (const float*)d_in[1];
  const float* ln1_g  = (const float*)d_in[2];
  const float* ln1_b  = (const float*)d_in[3];
  const float* w_qkv  = (const float*)d_in[4];
  const float* q_bias = (const float*)d_in[5];
  const float* v_bias = (const float*)d_in[6];
  const float* w_proj = (const float*)d_in[7];
  const float* b_proj = (const float*)d_in[8];
  const float* gamma1 = (const float*)d_in[9];
  const float* gamma2 = (const float*)d_in[10];
  const float* ln2t_g = (const float*)d_in[11];
  const float* ln2t_b = (const float*)d_in[12];
  const float* ln2i_g = (const float*)d_in[13];
  const float* ln2i_b = (const float*)d_in[14];
  const float* wt1    = (const float*)d_in[15];
  const float* bt1    = (const float*)d_in[16];
  const float* wt2    = (const float*)d_in[17];
  const float* bt2    = (const float*)d_in[18];
  const float* wi1    = (const float*)d_in[19];
  const float* bi1    = (const float*)d_in[20];
  const float* wi2    = (const float*)d_in[21];
  const float* bi2    = (const float*)d_in[22];
  float* out = (float*)d_out;

  char* ws = (char*)d_ws;
  bf16_t* wqkvb  = (bf16_t*)(ws + 0);
  bf16_t* wprojb = (bf16_t*)(ws + 3538944);
  bf16_t* wt1b   = (bf16_t*)(ws + 4718592);
  bf16_t* wi1b   = (bf16_t*)(ws + 9437184);
  bf16_t* wt2b   = (bf16_t*)(ws + 14155776);
  bf16_t* wi2b   = (bf16_t*)(ws + 18874368);
  bf16_t* n1     = (bf16_t*)(ws + 23592960);    // 9984x768 bf16; also n2p, o_mat
  float*  x1     = (float*) (ws + 38928384);    // 30.3MB; head doubles as vtmp
  bf16_t* qbuf   = (bf16_t*)(ws + 69206016);
  bf16_t* kbuf   = (bf16_t*)(ws + 84934656);
  bf16_t* vTbuf  = (bf16_t*)(ws + 100663296);
  bf16_t* vtmp   = (bf16_t*)(ws + 38928384);
  bf16_t* o_mat  = n1;
  bf16_t* n2p    = n1;
  bf16_t* hbuf   = qbuf;

  hipFuncSetAttribute((const void*)gemm128<0>, hipFuncAttributeMaxDynamicSharedMemorySize, 65536);
  hipFuncSetAttribute((const void*)gemm128<1>, hipFuncAttributeMaxDynamicSharedMemorySize, 65536);
  hipFuncSetAttribute((const void*)gemm128<2>, hipFuncAttributeMaxDynamicSharedMemorySize, 65536);
  hipFuncSetAttribute((const void*)gemm128<3>, hipFuncAttributeMaxDynamicSharedMemorySize, 65536);

  cast_f32_bf16<<<1024, 256, 0, stream>>>(w_qkv,  wqkvb,  3 * C_ * C_);
  cast_f32_bf16<<<512,  256, 0, stream>>>(w_proj, wprojb, C_ * C_);
  cast_f32_bf16<<<1024, 256, 0, stream>>>(wt1, wt1b, HID * C_);
  cast_f32_bf16<<<1024, 256, 0, stream>>>(wi1, wi1b, HID * C_);
  cast_f32_bf16<<<1024, 256, 0, stream>>>(wt2, wt2b, C_ * HID);
  cast_f32_bf16<<<1024, 256, 0, stream>>>(wi2, wi2b, C_ * HID);
  ln_rows<<<M_REAL, 256, 0, stream>>>(x, ln1_g, ln1_b, n1);

  // QKV GEMM: M=9856 (77 blocks), N=2304 (18 blocks), K=768
  {
    EpiP P{}; P.bias = q_bias; P.bias2 = v_bias;
    P.ob0 = qbuf; P.ob1 = kbuf; P.ob2 = vtmp;
    gemm128<0><<<dim3(M_REAL / 128, (3 * C_) / 128), 256, 65536, stream>>>(n1, wqkvb, wqkvb, C_, 0, P);
  }
  transpose_v<<<dim3(NP / 64, B_ * H_), 256, 0, stream>>>(vtmp, vTbuf);
  attn_fwd<<<dim3(NP / 64, B_ * H_), 256, 0, stream>>>(qbuf, kbuf, vTbuf, rel, o_mat);

  // proj + residual -> x1
  {
    EpiP P{}; P.bias = b_proj; P.bias_i = b_proj; P.gamma = gamma1; P.xres = x; P.outf = x1;
    gemm128<1><<<dim3(M_REAL / 128, C_ / 128), 256, 65536, stream>>>(o_mat, wprojb, wprojb, C_, 0, P);
  }
  ln2_pack<<<M_PAD, 256, 0, stream>>>(x1, ln2t_g, ln2t_b, ln2i_g, ln2i_b, n2p);

  // MLP fc1 + gelu (text m-blocks 0-5 incl. zero-pad block, image 6-77)
  {
    EpiP P{}; P.bias = bt1; P.bias_i = bi1; P.ob0 = hbuf;
    gemm128<2><<<dim3(M_PAD / 128, HID / 128), 256, 65536, stream>>>(n2p, wt1b, wi1b, C_, 6, P);
  }
  // MLP fc2 + gamma2 residual -> d_out
  {
    EpiP P{}; P.bias = bt2; P.bias_i = bi2; P.gamma = gamma2; P.xres = x1; P.outf = out;
    gemm128<3><<<dim3(M_PAD / 128, C_ / 128), 256, 65536, stream>>>(hbuf, wt2b, wi2b, HID, 6, P);
  }
}

// Round 5
// 503.187 us; speedup vs baseline: 1.2499x; 1.0236x over previous
//
#include <hip/hip_runtime.h>
#include <hip/hip_bf16.h>
#include <stdint.h>
#include <math.h>

#define AS1 __attribute__((address_space(1)))
#define AS3 __attribute__((address_space(3)))

typedef __bf16 bf16_t;
typedef __bf16 bf16x8 __attribute__((ext_vector_type(8)));
typedef float f32x4 __attribute__((ext_vector_type(4)));

static constexpr int B_ = 16, N_ = 616, C_ = 768, H_ = 12, HD = 64, HID = 3072;
static constexpr int NP = 640;           // padded seq len for q/k/vT
static constexpr int M_REAL = B_ * N_;   // 9856 = 77*128
static constexpr int M_PAD = 9984;       // 78*128 (packed MLP rows)
static constexpr int NT_ = 40, NI_ = 576;

__device__ __forceinline__ void gl_lds16(const void* g, void* l) {
  __builtin_amdgcn_global_load_lds((const AS1 void*)(uintptr_t)g,
                                   (AS3 void*)(uint32_t)(uintptr_t)l, 16, 0, 0);
}
__device__ __forceinline__ f32x4 mfma16(bf16x8 a, bf16x8 b, f32x4 c) {
  return __builtin_amdgcn_mfma_f32_16x16x32_bf16(a, b, c, 0, 0, 0);
}
__device__ __forceinline__ float gelu_f(float x) {
  float u = x * (0.7978845608f + 0.0356774081f * x * x);
  return x / (1.f + __expf(-2.f * u));
}

// ---------------------------------------------------------------- utilities
__global__ void cast_f32_bf16(const float* __restrict__ in, bf16_t* __restrict__ out, int n) {
  int i = blockIdx.x * blockDim.x + threadIdx.x;
  int st = gridDim.x * blockDim.x;
  for (; i < n; i += st) out[i] = (bf16_t)in[i];
}

// ---------------------------------------------------------------- layernorms
__global__ __launch_bounds__(256) void ln_rows(const float* __restrict__ x,
                                               const float* __restrict__ g,
                                               const float* __restrict__ b,
                                               bf16_t* __restrict__ out) {
  int r = blockIdx.x, t = threadIdx.x;
  bf16_t* orow = out + (size_t)r * C_;
  const float* xr = x + (size_t)r * C_;
  float v0 = xr[t], v1 = xr[t + 256], v2 = xr[t + 512];
  float s = v0 + v1 + v2, ss = v0 * v0 + v1 * v1 + v2 * v2;
#pragma unroll
  for (int off = 32; off > 0; off >>= 1) { s += __shfl_xor(s, off); ss += __shfl_xor(ss, off); }
  __shared__ float sm[8];
  int w = t >> 6;
  if ((t & 63) == 0) { sm[w] = s; sm[4 + w] = ss; }
  __syncthreads();
  s = sm[0] + sm[1] + sm[2] + sm[3];
  ss = sm[4] + sm[5] + sm[6] + sm[7];
  float mean = s * (1.f / C_);
  float var = ss * (1.f / C_) - mean * mean;
  float ri = rsqrtf(var + 1e-5f);
  orow[t]       = (bf16_t)((v0 - mean) * ri * g[t]       + b[t]);
  orow[t + 256] = (bf16_t)((v1 - mean) * ri * g[t + 256] + b[t + 256]);
  orow[t + 512] = (bf16_t)((v2 - mean) * ri * g[t + 512] + b[t + 512]);
}

// LN2 + pack: packed rows [0,640)=text, [640,768)=zero pad, [768,9984)=image
__global__ __launch_bounds__(256) void ln2_pack(const float* __restrict__ x1,
                                                const float* __restrict__ gt, const float* __restrict__ bt,
                                                const float* __restrict__ gi, const float* __restrict__ bi,
                                                bf16_t* __restrict__ out) {
  int m = blockIdx.x, t = threadIdx.x;
  if (m >= M_REAL) {
    bf16_t* orow = out + (size_t)(640 + (m - M_REAL)) * C_;
    orow[t] = (bf16_t)0.f; orow[t+256] = (bf16_t)0.f; orow[t+512] = (bf16_t)0.f;
    return;
  }
  int b_ = m / N_, nn = m - b_ * N_;
  const float* g; const float* bb; int dest;
  if (nn < NT_) { dest = b_ * NT_ + nn; g = gt; bb = bt; }
  else          { dest = 768 + b_ * NI_ + (nn - NT_); g = gi; bb = bi; }
  const float* xr = x1 + (size_t)m * C_;
  float v0 = xr[t], v1 = xr[t + 256], v2 = xr[t + 512];
  float s = v0 + v1 + v2, ss = v0 * v0 + v1 * v1 + v2 * v2;
#pragma unroll
  for (int off = 32; off > 0; off >>= 1) { s += __shfl_xor(s, off); ss += __shfl_xor(ss, off); }
  __shared__ float sm[8];
  int w = t >> 6;
  if ((t & 63) == 0) { sm[w] = s; sm[4 + w] = ss; }
  __syncthreads();
  s = sm[0] + sm[1] + sm[2] + sm[3];
  ss = sm[4] + sm[5] + sm[6] + sm[7];
  float mean = s * (1.f / C_);
  float var = ss * (1.f / C_) - mean * mean;
  float ri = rsqrtf(var + 1e-5f);
  bf16_t* orow = out + (size_t)dest * C_;
  orow[t]       = (bf16_t)((v0 - mean) * ri * g[t]       + bb[t]);
  orow[t + 256] = (bf16_t)((v1 - mean) * ri * g[t + 256] + bb[t + 256]);
  orow[t + 512] = (bf16_t)((v2 - mean) * ri * g[t + 512] + bb[t + 512]);
}

// ---------------------------------------------------------------- v transpose
// vT[bh][d][0..640) <- v[bh][n<616][d], zeros for n>=616 (so PV pads are clean)
__global__ __launch_bounds__(256) void transpose_v(const bf16_t* __restrict__ v,
                                                   bf16_t* __restrict__ vT) {
  __shared__ bf16_t t[64][80];
  int n0 = blockIdx.x * 64, bh = blockIdx.y;
  int tid = threadIdx.x;
  int r0 = tid >> 2, c0 = (tid & 3) * 16;
  int n = n0 + r0;
#pragma unroll
  for (int cc = 0; cc < 2; ++cc) {
    bf16x8 vv;
    if (n < N_) vv = *(const bf16x8*)(v + ((size_t)bh * N_ + n) * HD + c0 + cc * 8);
    else {
#pragma unroll
      for (int e = 0; e < 8; ++e) vv[e] = (bf16_t)0.f;
    }
#pragma unroll
    for (int e = 0; e < 8; ++e) t[c0 + cc * 8 + e][r0] = vv[e];
  }
  __syncthreads();
  int d = tid >> 2, nc = (tid & 3) * 16;
  bf16_t* dst = vT + ((size_t)(bh * HD + d)) * NP + n0 + nc;
  *(bf16x8*)dst       = *(const bf16x8*)&t[d][nc];
  *(bf16x8*)(dst + 8) = *(const bf16x8*)&t[d][nc + 8];
}

// ---------------------------------------------------------------- GEMM 128x128
// Fragment-ordered LDS (r4, conflict-free) + counted-vmcnt 2-deep pipeline (r5):
//   prologue: L0,L1 issued.  iter t: vmcnt(8) [tile t retired; t+1 stays in
//   flight] -> barrier A -> ds_read frags -> lgkmcnt(0) -> barrier B ->
//   STAGE(buf[t&1], t+2) -> MFMA.  Never vmcnt(0) mid-loop (T4, m218).
struct EpiP {
  const float* bias;
  const float* bias_i;
  const float* bias2;
  const float* gamma;
  const float* xres;
  float* outf;
  bf16_t* ob0;
  bf16_t* ob1;
  bf16_t* ob2;
};

extern __shared__ char smem_raw[];

template <int EPI>
__global__ __launch_bounds__(256, 2) void gemm128(const bf16_t* __restrict__ A,
                                                  const bf16_t* __restrict__ Bt,
                                                  const bf16_t* __restrict__ Bi,
                                                  int K, int tb, EpiP P) {
  bf16_t* sm = (bf16_t*)smem_raw;   // 2 bufs x 16384 elements (32KB each)
  const int tid = threadIdx.x, lane = tid & 63, w = tid >> 6;
  const int l16 = lane & 15, lq = lane >> 4;
  const int wr = w >> 1, wc = w & 1;
  const int m0 = blockIdx.x * 128, n0 = blockIdx.y * 128;
  const bf16_t* Bw = (blockIdx.x < tb) ? Bt : Bi;
  const int NTk = K >> 6;

  f32x4 acc[4][4] = {};

  // per-thread staging source offsets (element units), frag-order decode
  size_t aoff[4], boff[4];
  int ldsoff[4];
#pragma unroll
  for (int r = 0; r < 4; ++r) {
    int slot = w * 256 + r * 64 + lane;
    int h = slot >> 9, fid = (slot >> 6) & 7;
    int i = fid >> 1, kk = fid & 1;
    int rowc = h * 64 + i * 16 + (lane & 15);     // row (A) / col (B) in tile
    int gc = kk * 4 + (lane >> 4);                // 16B granule within K=64
    aoff[r] = (size_t)(m0 + rowc) * K + gc * 8;
    boff[r] = (size_t)(n0 + rowc) * K + gc * 8;
    ldsoff[r] = (w * 256 + r * 64) * 8;           // wave-uniform elem offset
  }

  auto STAGE = [&](int c, int t) {
    int cb = c * 16384;
    size_t kadd = (size_t)t * 64;
#pragma unroll
    for (int r = 0; r < 4; ++r) gl_lds16(A + aoff[r] + kadd, sm + cb + ldsoff[r]);
#pragma unroll
    for (int r = 0; r < 4; ++r) gl_lds16(Bw + boff[r] + kadd, sm + cb + 8192 + ldsoff[r]);
  };

  STAGE(0, 0);
  if (NTk > 1) STAGE(1, 1);

  for (int t = 0; t < NTk; ++t) {
    const int cur = t & 1;
    // tile t complete (8 = one tile's loads/wave remain = tile t+1 in flight)
    if (t + 1 < NTk) asm volatile("s_waitcnt vmcnt(8)" ::: "memory");
    else             asm volatile("s_waitcnt vmcnt(0)" ::: "memory");
    __builtin_amdgcn_s_barrier();           // A: cross-wave LDS-write visibility

    const bf16_t* Ac = sm + cur * 16384 + ((size_t)wr * 512 + lane) * 8;
    const bf16_t* Bc = sm + cur * 16384 + 8192 + ((size_t)wc * 512 + lane) * 8;
    bf16x8 av[4][2], bv[4][2];
#pragma unroll
    for (int i = 0; i < 4; ++i) {
#pragma unroll
      for (int kk = 0; kk < 2; ++kk) {
        av[i][kk] = *(const bf16x8*)(Ac + (i * 2 + kk) * 512);
        bv[i][kk] = *(const bf16x8*)(Bc + (i * 2 + kk) * 512);
      }
    }
    asm volatile("s_waitcnt lgkmcnt(0)" ::: "memory");
    __builtin_amdgcn_s_barrier();           // B: all waves done reading buf[cur]
    if (t + 2 < NTk) STAGE(cur, t + 2);     // overwrite safe; lands in ~2 iters

    __builtin_amdgcn_s_setprio(1);
#pragma unroll
    for (int kk = 0; kk < 2; ++kk)
#pragma unroll
      for (int i = 0; i < 4; ++i)
#pragma unroll
        for (int j = 0; j < 4; ++j)
          acc[i][j] = mfma16(av[i][kk], bv[j][kk], acc[i][j]);
    __builtin_amdgcn_s_setprio(0);
  }

  // epilogue: C/D frag: row = 16i + lq*4 + rr, col = 16j + l16  (wave 64x64)
  const float* bsel = (blockIdx.x < tb) ? P.bias : P.bias_i;
  (void)bsel;
  int which = n0 / C_;
#pragma unroll
  for (int i = 0; i < 4; ++i) {
    int mb = m0 + wr * 64 + i * 16 + lq * 4;
#pragma unroll
    for (int j = 0; j < 4; ++j) {
      int jc = n0 + wc * 64 + j * 16 + l16;
#pragma unroll
      for (int rr = 0; rr < 4; ++rr) {
        int m = mb + rr;
        float v = acc[i][j][rr];
        if constexpr (EPI == 0) {       // QKV split; q,k -> [bh][640][64], v -> [bh][616][64]
          int b_ = m / N_, nn = m - b_ * N_;
          int jj = jc - which * C_;
          int hh = jj >> 6, d = jj & 63;
          int bh = b_ * H_ + hh;
          if (which == 0) {
            P.ob0[((size_t)bh * NP + nn) * HD + d] = (bf16_t)((v + P.bias[jj]) * 0.125f);
          } else if (which == 1) {
            P.ob1[((size_t)bh * NP + nn) * HD + d] = (bf16_t)v;
          } else {
            P.ob2[((size_t)bh * N_ + nn) * HD + d] = (bf16_t)(v + P.bias2[jj]);
          }
        } else if constexpr (EPI == 1) {  // proj: x1 = x + gamma1*(o+b)
          size_t idx = (size_t)m * C_ + jc;
          P.outf[idx] = P.xres[idx] + P.gamma[jc] * (v + P.bias[jc]);
        } else if constexpr (EPI == 2) {  // mlp1: gelu -> hbuf
          P.ob0[(size_t)m * HID + jc] = (bf16_t)gelu_f(v + bsel[jc]);
        } else {                          // mlp2: residual scatter to d_out
          int orig = -1;
          if (m < 640)      orig = (m / NT_) * N_ + (m - (m / NT_) * NT_);
          else if (m >= 768) {
            int mi = m - 768;
            int bb = mi / NI_;
            orig = bb * N_ + NT_ + (mi - bb * NI_);
          }
          if (orig >= 0) {
            size_t idx = (size_t)orig * C_ + jc;
            P.outf[idx] = P.xres[idx] + P.gamma[jc] * (v + bsel[jc]);
          }
        }
      }
    }
  }
}

// ---------------------------------------------------------------- attention (validated r1)
__global__ __launch_bounds__(256) void attn_fwd(const bf16_t* __restrict__ qb,
                                                const bf16_t* __restrict__ kb,
                                                const bf16_t* __restrict__ vT,
                                                const float* __restrict__ rel_bias,
                                                bf16_t* __restrict__ o_mat) {
  __shared__ bf16_t qs[64 * 64], ks[64 * 64], vs[64 * 64];
  __shared__ bf16_t ps[4][16 * 64];
  const int tid = threadIdx.x, lane = tid & 63, w = tid >> 6;
  const int l16 = lane & 15, lq = lane >> 4;
  const int qt = blockIdx.x, bh = blockIdx.y;
  const int b_ = bh / H_, h = bh - b_ * H_;
  const int q0 = qt * 64;

  const bf16_t* qsrc = qb + ((size_t)bh * NP + q0) * HD;
#pragma unroll
  for (int it = 0; it < 2; ++it) {
    int cb = it * 256 + w * 64, c = cb + lane;
    gl_lds16(qsrc + c * 8, qs + cb * 8);
  }
  __syncthreads();
  bf16x8 aq[2];
  aq[0] = *(const bf16x8*)(qs + (w * 16 + l16) * 64 + 0 + lq * 8);
  aq[1] = *(const bf16x8*)(qs + (w * 16 + l16) * 64 + 32 + lq * 8);

  float mrun[4], lrun[4];
  f32x4 oacc[4] = {};
#pragma unroll
  for (int r = 0; r < 4; ++r) { mrun[r] = -3e38f; lrun[r] = 0.f; }

  const int qrow_base = q0 + w * 16 + lq * 4;
  const float* biasr = rel_bias + (size_t)h * N_ * N_;

  for (int kt = 0; kt < NP / 64; ++kt) {
    int n0k = kt * 64;
    const bf16_t* ksrc = kb + ((size_t)bh * NP + n0k) * HD;
#pragma unroll
    for (int it = 0; it < 2; ++it) {
      int cb = it * 256 + w * 64, c = cb + lane;
      gl_lds16(ksrc + c * 8, ks + cb * 8);
      int d = c >> 3, kc = (c & 7) << 3;
      gl_lds16(vT + ((size_t)bh * HD + d) * NP + n0k + kc, vs + cb * 8);
    }
    __syncthreads();

    f32x4 sf[4];
#pragma unroll
    for (int f = 0; f < 4; ++f) {
      f32x4 z = {};
#pragma unroll
      for (int kk = 0; kk < 2; ++kk) {
        bf16x8 bk = *(const bf16x8*)(ks + (f * 16 + l16) * 64 + kk * 32 + lq * 8);
        z = mfma16(aq[kk], bk, z);
      }
      sf[f] = z;
    }
    float pm[4];
#pragma unroll
    for (int r = 0; r < 4; ++r) pm[r] = -3e38f;
#pragma unroll
    for (int f = 0; f < 4; ++f) {
      int kcol = n0k + f * 16 + l16;
#pragma unroll
      for (int r = 0; r < 4; ++r) {
        int qg = qrow_base + r;
        int qc = qg < N_ ? qg : (N_ - 1);
        float sv = (kcol < N_) ? (sf[f][r] + biasr[(size_t)qc * N_ + kcol]) : -3e38f;
        sf[f][r] = sv;
        pm[r] = fmaxf(pm[r], sv);
      }
    }
#pragma unroll
    for (int off = 1; off < 16; off <<= 1)
#pragma unroll
      for (int r = 0; r < 4; ++r)
        pm[r] = fmaxf(pm[r], __shfl_xor(pm[r], off, 16));

    float alpha[4], lsum[4];
#pragma unroll
    for (int r = 0; r < 4; ++r) {
      float mnew = fmaxf(mrun[r], pm[r]);
      alpha[r] = __expf(mrun[r] - mnew);
      mrun[r] = mnew;
      lsum[r] = 0.f;
    }
#pragma unroll
    for (int f = 0; f < 4; ++f)
#pragma unroll
      for (int r = 0; r < 4; ++r) {
        float p = __expf(sf[f][r] - mrun[r]);
        sf[f][r] = p;
        lsum[r] += p;
      }
#pragma unroll
    for (int off = 1; off < 16; off <<= 1)
#pragma unroll
      for (int r = 0; r < 4; ++r)
        lsum[r] += __shfl_xor(lsum[r], off, 16);
#pragma unroll
    for (int r = 0; r < 4; ++r) lrun[r] = lrun[r] * alpha[r] + lsum[r];
#pragma unroll
    for (int df = 0; df < 4; ++df)
#pragma unroll
      for (int r = 0; r < 4; ++r) oacc[df][r] *= alpha[r];

    bf16_t* psw = ps[w];
#pragma unroll
    for (int f = 0; f < 4; ++f)
#pragma unroll
      for (int r = 0; r < 4; ++r)
        psw[(lq * 4 + r) * 64 + f * 16 + l16] = (bf16_t)sf[f][r];
    __syncthreads();

#pragma unroll
    for (int kk = 0; kk < 2; ++kk) {
      bf16x8 pa = *(const bf16x8*)(psw + l16 * 64 + kk * 32 + lq * 8);
#pragma unroll
      for (int df = 0; df < 4; ++df) {
        bf16x8 bv = *(const bf16x8*)(vs + (df * 16 + l16) * 64 + kk * 32 + lq * 8);
        oacc[df] = mfma16(pa, bv, oacc[df]);
      }
    }
    __syncthreads();
  }

#pragma unroll
  for (int r = 0; r < 4; ++r) {
    int qg = qrow_base + r;
    if (qg < N_) {
      float rl = 1.f / lrun[r];
      size_t orow = ((size_t)(b_ * N_ + qg)) * C_ + h * HD;
#pragma unroll
      for (int df = 0; df < 4; ++df)
        o_mat[orow + df * 16 + l16] = (bf16_t)(oacc[df][r] * rl);
    }
  }
}

// ---------------------------------------------------------------- launch
extern "C" void kernel_launch(void* const* d_in, const int* in_sizes, int n_in,
                              void* d_out, int out_size, void* d_ws, size_t ws_size,
                              hipStream_t stream) {
  const float* x      = (const float*)d_in[0];
  const float* rel    = (const float*)d_in[1];
  const float* ln1_g  = (const float*)d_in[2];
  const float* ln1_b  = (const float*)d_in[3];
  const float* w_qkv  = (const float*)d_in[4];
  const float* q_bias = (const float*)d_in[5];
  const float* v_bias = (const float*)d_in[6];
  const float* w_proj = (const float*)d_in[7];
  const float* b_proj = (const float*)d_in[8];
  const float* gamma1 = (const float*)d_in[9];
  const float* gamma2 = (const float*)d_in[10];
  const float* ln2t_g = (const float*)d_in[11];
  const float* ln2t_b = (const float*)d_in[12];
  const float* ln2i_g = (const float*)d_in[13];
  const float* ln2i_b = (const float*)d_in[14];
  const float* wt1    = (const float*)d_in[15];
  const float* bt1    = (const float*)d_in[16];
  const float* wt2    = (const float*)d_in[17];
  const float* bt2    = (const float*)d_in[18];
  const float* wi1    = (const float*)d_in[19];
  const float* bi1    = (const float*)d_in[20];
  const float* wi2    = (const float*)d_in[21];
  const float* bi2    = (const float*)d_in[22];
  float* out = (float*)d_out;

  char* ws = (char*)d_ws;
  bf16_t* wqkvb  = (bf16_t*)(ws + 0);
  bf16_t* wprojb = (bf16_t*)(ws + 3538944);
  bf16_t* wt1b   = (bf16_t*)(ws + 4718592);
  bf16_t* wi1b   = (bf16_t*)(ws + 9437184);
  bf16_t* wt2b   = (bf16_t*)(ws + 14155776);
  bf16_t* wi2b   = (bf16_t*)(ws + 18874368);
  bf16_t* n1     = (bf16_t*)(ws + 23592960);    // 9984x768 bf16; also n2p, o_mat
  float*  x1     = (float*) (ws + 38928384);    // 30.3MB; head doubles as vtmp
  bf16_t* qbuf   = (bf16_t*)(ws + 69206016);
  bf16_t* kbuf   = (bf16_t*)(ws + 84934656);
  bf16_t* vTbuf  = (bf16_t*)(ws + 100663296);
  bf16_t* vtmp   = (bf16_t*)(ws + 38928384);
  bf16_t* o_mat  = n1;
  bf16_t* n2p    = n1;
  bf16_t* hbuf   = qbuf;

  hipFuncSetAttribute((const void*)gemm128<0>, hipFuncAttributeMaxDynamicSharedMemorySize, 65536);
  hipFuncSetAttribute((const void*)gemm128<1>, hipFuncAttributeMaxDynamicSharedMemorySize, 65536);
  hipFuncSetAttribute((const void*)gemm128<2>, hipFuncAttributeMaxDynamicSharedMemorySize, 65536);
  hipFuncSetAttribute((const void*)gemm128<3>, hipFuncAttributeMaxDynamicSharedMemorySize, 65536);

  cast_f32_bf16<<<1024, 256, 0, stream>>>(w_qkv,  wqkvb,  3 * C_ * C_);
  cast_f32_bf16<<<512,  256, 0, stream>>>(w_proj, wprojb, C_ * C_);
  cast_f32_bf16<<<1024, 256, 0, stream>>>(wt1, wt1b, HID * C_);
  cast_f32_bf16<<<1024, 256, 0, stream>>>(wi1, wi1b, HID * C_);
  cast_f32_bf16<<<1024, 256, 0, stream>>>(wt2, wt2b, C_ * HID);
  cast_f32_bf16<<<1024, 256, 0, stream>>>(wi2, wi2b, C_ * HID);
  ln_rows<<<M_REAL, 256, 0, stream>>>(x, ln1_g, ln1_b, n1);

  // QKV GEMM: M=9856 (77 blocks), N=2304 (18 blocks), K=768
  {
    EpiP P{}; P.bias = q_bias; P.bias2 = v_bias;
    P.ob0 = qbuf; P.ob1 = kbuf; P.ob2 = vtmp;
    gemm128<0><<<dim3(M_REAL / 128, (3 * C_) / 128), 256, 65536, stream>>>(n1, wqkvb, wqkvb, C_, 0, P);
  }
  transpose_v<<<dim3(NP / 64, B_ * H_), 256, 0, stream>>>(vtmp, vTbuf);
  attn_fwd<<<dim3(NP / 64, B_ * H_), 256, 0, stream>>>(qbuf, kbuf, vTbuf, rel, o_mat);

  // proj + residual -> x1
  {
    EpiP P{}; P.bias = b_proj; P.bias_i = b_proj; P.gamma = gamma1; P.xres = x; P.outf = x1;
    gemm128<1><<<dim3(M_REAL / 128, C_ / 128), 256, 65536, stream>>>(o_mat, wprojb, wprojb, C_, 0, P);
  }
  ln2_pack<<<M_PAD, 256, 0, stream>>>(x1, ln2t_g, ln2t_b, ln2i_g, ln2i_b, n2p);

  // MLP fc1 + gelu (text m-blocks 0-5 incl. zero-pad block, image 6-77)
  {
    EpiP P{}; P.bias = bt1; P.bias_i = bi1; P.ob0 = hbuf;
    gemm128<2><<<dim3(M_PAD / 128, HID / 128), 256, 65536, stream>>>(n2p, wt1b, wi1b, C_, 6, P);
  }
  // MLP fc2 + gamma2 residual -> d_out
  {
    EpiP P{}; P.bias = bt2; P.bias_i = bi2; P.gamma = gamma2; P.xres = x1; P.outf = out;
    gemm128<3><<<dim3(M_PAD / 128, C_ / 128), 256, 65536, stream>>>(hbuf, wt2b, wi2b, HID, 6, P);
  }
}

// Round 6
// 469.631 us; speedup vs baseline: 1.3392x; 1.0715x over previous
//
#include <hip/hip_runtime.h>
#include <hip/hip_bf16.h>
#include <stdint.h>
#include <math.h>

#define AS1 __attribute__((address_space(1)))
#define AS3 __attribute__((address_space(3)))

typedef __bf16 bf16_t;
typedef __bf16 bf16x8 __attribute__((ext_vector_type(8)));
typedef float f32x4 __attribute__((ext_vector_type(4)));

static constexpr int B_ = 16, N_ = 616, C_ = 768, H_ = 12, HD = 64, HID = 3072;
static constexpr int NP = 640;           // padded seq len for q/k/vT
static constexpr int M_REAL = B_ * N_;   // 9856
static constexpr int M_PAD = 9984;       // 39*256
static constexpr int NT_ = 40, NI_ = 576;
static constexpr int MB_ = 39;           // fixed M-block count (256-row blocks)

__device__ __forceinline__ void gl_lds16(const void* g, void* l) {
  __builtin_amdgcn_global_load_lds((const AS1 void*)(uintptr_t)g,
                                   (AS3 void*)(uint32_t)(uintptr_t)l, 16, 0, 0);
}
__device__ __forceinline__ f32x4 mfma16(bf16x8 a, bf16x8 b, f32x4 c) {
  return __builtin_amdgcn_mfma_f32_16x16x32_bf16(a, b, c, 0, 0, 0);
}
__device__ __forceinline__ float gelu_f(float x) {
  float u = x * (0.7978845608f + 0.0356774081f * x * x);
  return x / (1.f + __expf(-2.f * u));
}

// ---------------------------------------------------------------- utilities
__global__ void cast_f32_bf16(const float* __restrict__ in, bf16_t* __restrict__ out, int n) {
  int i = blockIdx.x * blockDim.x + threadIdx.x;
  int st = gridDim.x * blockDim.x;
  for (; i < n; i += st) out[i] = (bf16_t)in[i];
}

// ---------------------------------------------------------------- layernorms
__global__ __launch_bounds__(256) void ln_rows(const float* __restrict__ x,
                                               const float* __restrict__ g,
                                               const float* __restrict__ b,
                                               bf16_t* __restrict__ out) {
  int r = blockIdx.x, t = threadIdx.x;
  bf16_t* orow = out + (size_t)r * C_;
  const float* xr = x + (size_t)r * C_;
  float v0 = xr[t], v1 = xr[t + 256], v2 = xr[t + 512];
  float s = v0 + v1 + v2, ss = v0 * v0 + v1 * v1 + v2 * v2;
#pragma unroll
  for (int off = 32; off > 0; off >>= 1) { s += __shfl_xor(s, off); ss += __shfl_xor(ss, off); }
  __shared__ float sm[8];
  int w = t >> 6;
  if ((t & 63) == 0) { sm[w] = s; sm[4 + w] = ss; }
  __syncthreads();
  s = sm[0] + sm[1] + sm[2] + sm[3];
  ss = sm[4] + sm[5] + sm[6] + sm[7];
  float mean = s * (1.f / C_);
  float var = ss * (1.f / C_) - mean * mean;
  float ri = rsqrtf(var + 1e-5f);
  orow[t]       = (bf16_t)((v0 - mean) * ri * g[t]       + b[t]);
  orow[t + 256] = (bf16_t)((v1 - mean) * ri * g[t + 256] + b[t + 256]);
  orow[t + 512] = (bf16_t)((v2 - mean) * ri * g[t + 512] + b[t + 512]);
}

// LN2 + pack: packed rows [0,640)=text, [640,768)=zero pad, [768,9984)=image
__global__ __launch_bounds__(256) void ln2_pack(const float* __restrict__ x1,
                                                const float* __restrict__ gt, const float* __restrict__ bt,
                                                const float* __restrict__ gi, const float* __restrict__ bi,
                                                bf16_t* __restrict__ out) {
  int m = blockIdx.x, t = threadIdx.x;
  if (m >= M_REAL) {
    bf16_t* orow = out + (size_t)(640 + (m - M_REAL)) * C_;
    orow[t] = (bf16_t)0.f; orow[t+256] = (bf16_t)0.f; orow[t+512] = (bf16_t)0.f;
    return;
  }
  int b_ = m / N_, nn = m - b_ * N_;
  const float* g; const float* bb; int dest;
  if (nn < NT_) { dest = b_ * NT_ + nn; g = gt; bb = bt; }
  else          { dest = 768 + b_ * NI_ + (nn - NT_); g = gi; bb = bi; }
  const float* xr = x1 + (size_t)m * C_;
  float v0 = xr[t], v1 = xr[t + 256], v2 = xr[t + 512];
  float s = v0 + v1 + v2, ss = v0 * v0 + v1 * v1 + v2 * v2;
#pragma unroll
  for (int off = 32; off > 0; off >>= 1) { s += __shfl_xor(s, off); ss += __shfl_xor(ss, off); }
  __shared__ float sm[8];
  int w = t >> 6;
  if ((t & 63) == 0) { sm[w] = s; sm[4 + w] = ss; }
  __syncthreads();
  s = sm[0] + sm[1] + sm[2] + sm[3];
  ss = sm[4] + sm[5] + sm[6] + sm[7];
  float mean = s * (1.f / C_);
  float var = ss * (1.f / C_) - mean * mean;
  float ri = rsqrtf(var + 1e-5f);
  bf16_t* orow = out + (size_t)dest * C_;
  orow[t]       = (bf16_t)((v0 - mean) * ri * g[t]       + bb[t]);
  orow[t + 256] = (bf16_t)((v1 - mean) * ri * g[t + 256] + bb[t + 256]);
  orow[t + 512] = (bf16_t)((v2 - mean) * ri * g[t + 512] + bb[t + 512]);
}

// ---------------------------------------------------------------- v transpose
__global__ __launch_bounds__(256) void transpose_v(const bf16_t* __restrict__ v,
                                                   bf16_t* __restrict__ vT) {
  __shared__ bf16_t t[64][80];
  int n0 = blockIdx.x * 64, bh = blockIdx.y;
  int tid = threadIdx.x;
  int r0 = tid >> 2, c0 = (tid & 3) * 16;
  int n = n0 + r0;
#pragma unroll
  for (int cc = 0; cc < 2; ++cc) {
    bf16x8 vv;
    if (n < N_) vv = *(const bf16x8*)(v + ((size_t)bh * N_ + n) * HD + c0 + cc * 8);
    else {
#pragma unroll
      for (int e = 0; e < 8; ++e) vv[e] = (bf16_t)0.f;
    }
#pragma unroll
    for (int e = 0; e < 8; ++e) t[c0 + cc * 8 + e][r0] = vv[e];
  }
  __syncthreads();
  int d = tid >> 2, nc = (tid & 3) * 16;
  bf16_t* dst = vT + ((size_t)(bh * HD + d)) * NP + n0 + nc;
  *(bf16x8*)dst       = *(const bf16x8*)&t[d][nc];
  *(bf16x8*)(dst + 8) = *(const bf16x8*)&t[d][nc + 8];
}

// ---------------------------------------------------------------- GEMM 256x128, 8 waves
// Wave tile 128x64 (wr in 0..3 row-halves of 64... wr*64? NO: wr in 0..3 -> 64-row
// strips?  Layout: wr = w>>1 in 0..3 owns rows wr*64..wr*64+63?  -- see decode:
// wave w: wr=w>>1 (4 strips x 64 rows), wc=w&1 (2 strips x 64 cols). Each wave:
// 4x4 fragments of 16x16 = 64x64?  CORRECTION: geometry is BM=256 (4 x 64-row
// strips), BN=128 (2 x 64-col strips); wave tile 64x64, 8 waves tile the block.
// Frag-ordered LDS: A granule group g in 0..31: rows (g>>3)*64+((g>>1)&3)*16+l16,
// K-granule (g&1)*4+lq.  B groups g in 0..15 same with cols.  All ds_read_b128
// are base+lane*16B (conflict-free).  Counted-vmcnt 2-deep pipeline (T4):
// 6 loads/wave/tile, wait vmcnt(6) mid-loop, never 0.  XCD-chunked remap (m204).
struct EpiP {
  const float* bias;
  const float* bias_i;
  const float* bias2;
  const float* gamma;
  const float* xres;
  float* outf;
  bf16_t* ob0;
  bf16_t* ob1;
  bf16_t* ob2;
};

extern __shared__ char smem_raw[];

template <int EPI>
__global__ __launch_bounds__(512, 2) void gemm256x128(const bf16_t* __restrict__ A,
                                                      const bf16_t* __restrict__ Bt,
                                                      const bf16_t* __restrict__ Bi,
                                                      int K, int nb, int tb, EpiP P) {
  bf16_t* sm = (bf16_t*)smem_raw;   // 2 bufs x 24576 elems (48KB each): A 16384 + B 8192
  const int tid = threadIdx.x, lane = tid & 63, w = tid >> 6;
  const int l16 = lane & 15, lq = lane >> 4;
  const int wr = w >> 1, wc = w & 1;
  const int NTk = K >> 6;

  // ---- XCD-chunked bijective remap (m204): XCD k gets contiguous wg range;
  // decode wg over m-chunks (7 chunks of 5 + 1 of 4 over MB_=39), m-fast.
  int mblk, nblk;
  {
    int nwg = MB_ * nb;
    int bid = blockIdx.x;
    int q8 = nwg >> 3, r8 = nwg & 7;
    int xcd = bid & 7, sidx = bid >> 3;
    int wg = (xcd < r8 ? xcd * (q8 + 1) : r8 * (q8 + 1) + (xcd - r8) * q8) + sidx;
    int t1 = 35 * nb;
    if (wg < t1) { int k = wg / (5 * nb); int loc = wg - k * 5 * nb; mblk = k * 5 + loc % 5; nblk = loc / 5; }
    else         { int loc = wg - t1;     mblk = 35 + loc % 4;       nblk = loc / 4; }
  }
  const int m0 = mblk * 256, n0 = nblk * 128;
  const bf16_t* Bw = (mblk < tb) ? Bt : Bi;

  f32x4 acc[4][4] = {};

  // staging offsets: wave w stages A groups 4w..4w+3, B groups 2w..2w+1
  size_t aoff[4]; int alds[4];
  size_t boff[2]; int blds[2];
#pragma unroll
  for (int r = 0; r < 4; ++r) {
    int g = w * 4 + r;
    int row = (g >> 3) * 64 + ((g >> 1) & 3) * 16 + (lane & 15);
    int gc = (g & 1) * 4 + (lane >> 4);
    aoff[r] = (size_t)(m0 + row) * K + gc * 8;
    alds[r] = g * 512;
  }
#pragma unroll
  for (int r = 0; r < 2; ++r) {
    int g = w * 2 + r;
    int col = (g >> 3) * 64 + ((g >> 1) & 3) * 16 + (lane & 15);
    int gc = (g & 1) * 4 + (lane >> 4);
    boff[r] = (size_t)(n0 + col) * K + gc * 8;
    blds[r] = 16384 + g * 512;
  }

  auto STAGE = [&](int c, int t) {
    int cb = c * 24576;
    size_t kadd = (size_t)t * 64;
#pragma unroll
    for (int r = 0; r < 4; ++r) gl_lds16(A + aoff[r] + kadd, sm + cb + alds[r]);
#pragma unroll
    for (int r = 0; r < 2; ++r) gl_lds16(Bw + boff[r] + kadd, sm + cb + blds[r]);
  };

  STAGE(0, 0);
  if (NTk > 1) STAGE(1, 1);

  for (int t = 0; t < NTk; ++t) {
    const int cur = t & 1;
    if (t + 1 < NTk) asm volatile("s_waitcnt vmcnt(6)" ::: "memory");
    else             asm volatile("s_waitcnt vmcnt(0)" ::: "memory");
    __builtin_amdgcn_s_barrier();           // A: all waves' tile-t loads landed

    const bf16_t* Ac = sm + cur * 24576 + (size_t)wr * 8 * 512 + (size_t)lane * 8;
    const bf16_t* Bc = sm + cur * 24576 + 16384 + (size_t)wc * 8 * 512 + (size_t)lane * 8;
    bf16x8 av[4][2], bv[4][2];
#pragma unroll
    for (int i = 0; i < 4; ++i)
#pragma unroll
      for (int kk = 0; kk < 2; ++kk) {
        av[i][kk] = *(const bf16x8*)(Ac + (i * 2 + kk) * 512);
        bv[i][kk] = *(const bf16x8*)(Bc + (i * 2 + kk) * 512);
      }
    asm volatile("s_waitcnt lgkmcnt(0)" ::: "memory");
    __builtin_amdgcn_sched_barrier(0);
    __builtin_amdgcn_s_barrier();           // B: all waves done reading buf[cur]
    if (t + 2 < NTk) STAGE(cur, t + 2);

    __builtin_amdgcn_s_setprio(1);
#pragma unroll
    for (int kk = 0; kk < 2; ++kk)
#pragma unroll
      for (int i = 0; i < 4; ++i)
#pragma unroll
        for (int j = 0; j < 4; ++j)
          acc[i][j] = mfma16(av[i][kk], bv[j][kk], acc[i][j]);
    __builtin_amdgcn_s_setprio(0);
  }

  // epilogue: wave tile rows m0+wr*64+i*16+lq*4+rr, cols n0+wc*64+j*16+l16
  const float* bsel = (mblk < tb) ? P.bias : P.bias_i;
  (void)bsel;
  int which = n0 / C_;
#pragma unroll
  for (int i = 0; i < 4; ++i) {
    int mb = m0 + wr * 64 + i * 16 + lq * 4;
#pragma unroll
    for (int j = 0; j < 4; ++j) {
      int jc = n0 + wc * 64 + j * 16 + l16;
#pragma unroll
      for (int rr = 0; rr < 4; ++rr) {
        int m = mb + rr;
        float v = acc[i][j][rr];
        if constexpr (EPI == 0) {       // QKV split
          if (m < M_REAL) {
            int b_ = m / N_, nn = m - b_ * N_;
            int jj = jc - which * C_;
            int hh = jj >> 6, d = jj & 63;
            int bh = b_ * H_ + hh;
            if (which == 0) {
              P.ob0[((size_t)bh * NP + nn) * HD + d] = (bf16_t)((v + P.bias[jj]) * 0.125f);
            } else if (which == 1) {
              P.ob1[((size_t)bh * NP + nn) * HD + d] = (bf16_t)v;
            } else {
              P.ob2[((size_t)bh * N_ + nn) * HD + d] = (bf16_t)(v + P.bias2[jj]);
            }
          }
        } else if constexpr (EPI == 1) {  // proj: x1 = x + gamma1*(o+b)
          if (m < M_REAL) {
            size_t idx = (size_t)m * C_ + jc;
            P.outf[idx] = P.xres[idx] + P.gamma[jc] * (v + P.bias[jc]);
          }
        } else if constexpr (EPI == 2) {  // mlp1: gelu -> hbuf
          P.ob0[(size_t)m * HID + jc] = (bf16_t)gelu_f(v + bsel[jc]);
        } else {                          // mlp2: residual scatter to d_out
          int orig = -1;
          if (m < 640)      orig = (m / NT_) * N_ + (m - (m / NT_) * NT_);
          else if (m >= 768) {
            int mi = m - 768;
            int bb = mi / NI_;
            orig = bb * N_ + NT_ + (mi - bb * NI_);
          }
          if (orig >= 0) {
            size_t idx = (size_t)orig * C_ + jc;
            P.outf[idx] = P.xres[idx] + P.gamma[jc] * (v + bsel[jc]);
          }
        }
      }
    }
  }
}

// ---------------------------------------------------------------- attention (validated r1)
__global__ __launch_bounds__(256) void attn_fwd(const bf16_t* __restrict__ qb,
                                                const bf16_t* __restrict__ kb,
                                                const bf16_t* __restrict__ vT,
                                                const float* __restrict__ rel_bias,
                                                bf16_t* __restrict__ o_mat) {
  __shared__ bf16_t qs[64 * 64], ks[64 * 64], vs[64 * 64];
  __shared__ bf16_t ps[4][16 * 64];
  const int tid = threadIdx.x, lane = tid & 63, w = tid >> 6;
  const int l16 = lane & 15, lq = lane >> 4;
  const int qt = blockIdx.x, bh = blockIdx.y;
  const int b_ = bh / H_, h = bh - b_ * H_;
  const int q0 = qt * 64;

  const bf16_t* qsrc = qb + ((size_t)bh * NP + q0) * HD;
#pragma unroll
  for (int it = 0; it < 2; ++it) {
    int cb = it * 256 + w * 64, c = cb + lane;
    gl_lds16(qsrc + c * 8, qs + cb * 8);
  }
  __syncthreads();
  bf16x8 aq[2];
  aq[0] = *(const bf16x8*)(qs + (w * 16 + l16) * 64 + 0 + lq * 8);
  aq[1] = *(const bf16x8*)(qs + (w * 16 + l16) * 64 + 32 + lq * 8);

  float mrun[4], lrun[4];
  f32x4 oacc[4] = {};
#pragma unroll
  for (int r = 0; r < 4; ++r) { mrun[r] = -3e38f; lrun[r] = 0.f; }

  const int qrow_base = q0 + w * 16 + lq * 4;
  const float* biasr = rel_bias + (size_t)h * N_ * N_;

  for (int kt = 0; kt < NP / 64; ++kt) {
    int n0k = kt * 64;
    const bf16_t* ksrc = kb + ((size_t)bh * NP + n0k) * HD;
#pragma unroll
    for (int it = 0; it < 2; ++it) {
      int cb = it * 256 + w * 64, c = cb + lane;
      gl_lds16(ksrc + c * 8, ks + cb * 8);
      int d = c >> 3, kc = (c & 7) << 3;
      gl_lds16(vT + ((size_t)bh * HD + d) * NP + n0k + kc, vs + cb * 8);
    }
    __syncthreads();

    f32x4 sf[4];
#pragma unroll
    for (int f = 0; f < 4; ++f) {
      f32x4 z = {};
#pragma unroll
      for (int kk = 0; kk < 2; ++kk) {
        bf16x8 bk = *(const bf16x8*)(ks + (f * 16 + l16) * 64 + kk * 32 + lq * 8);
        z = mfma16(aq[kk], bk, z);
      }
      sf[f] = z;
    }
    float pm[4];
#pragma unroll
    for (int r = 0; r < 4; ++r) pm[r] = -3e38f;
#pragma unroll
    for (int f = 0; f < 4; ++f) {
      int kcol = n0k + f * 16 + l16;
#pragma unroll
      for (int r = 0; r < 4; ++r) {
        int qg = qrow_base + r;
        int qc = qg < N_ ? qg : (N_ - 1);
        float sv = (kcol < N_) ? (sf[f][r] + biasr[(size_t)qc * N_ + kcol]) : -3e38f;
        sf[f][r] = sv;
        pm[r] = fmaxf(pm[r], sv);
      }
    }
#pragma unroll
    for (int off = 1; off < 16; off <<= 1)
#pragma unroll
      for (int r = 0; r < 4; ++r)
        pm[r] = fmaxf(pm[r], __shfl_xor(pm[r], off, 16));

    float alpha[4], lsum[4];
#pragma unroll
    for (int r = 0; r < 4; ++r) {
      float mnew = fmaxf(mrun[r], pm[r]);
      alpha[r] = __expf(mrun[r] - mnew);
      mrun[r] = mnew;
      lsum[r] = 0.f;
    }
#pragma unroll
    for (int f = 0; f < 4; ++f)
#pragma unroll
      for (int r = 0; r < 4; ++r) {
        float p = __expf(sf[f][r] - mrun[r]);
        sf[f][r] = p;
        lsum[r] += p;
      }
#pragma unroll
    for (int off = 1; off < 16; off <<= 1)
#pragma unroll
      for (int r = 0; r < 4; ++r)
        lsum[r] += __shfl_xor(lsum[r], off, 16);
#pragma unroll
    for (int r = 0; r < 4; ++r) lrun[r] = lrun[r] * alpha[r] + lsum[r];
#pragma unroll
    for (int df = 0; df < 4; ++df)
#pragma unroll
      for (int r = 0; r < 4; ++r) oacc[df][r] *= alpha[r];

    bf16_t* psw = ps[w];
#pragma unroll
    for (int f = 0; f < 4; ++f)
#pragma unroll
      for (int r = 0; r < 4; ++r)
        psw[(lq * 4 + r) * 64 + f * 16 + l16] = (bf16_t)sf[f][r];
    __syncthreads();

#pragma unroll
    for (int kk = 0; kk < 2; ++kk) {
      bf16x8 pa = *(const bf16x8*)(psw + l16 * 64 + kk * 32 + lq * 8);
#pragma unroll
      for (int df = 0; df < 4; ++df) {
        bf16x8 bv = *(const bf16x8*)(vs + (df * 16 + l16) * 64 + kk * 32 + lq * 8);
        oacc[df] = mfma16(pa, bv, oacc[df]);
      }
    }
    __syncthreads();
  }

#pragma unroll
  for (int r = 0; r < 4; ++r) {
    int qg = qrow_base + r;
    if (qg < N_) {
      float rl = 1.f / lrun[r];
      size_t orow = ((size_t)(b_ * N_ + qg)) * C_ + h * HD;
#pragma unroll
      for (int df = 0; df < 4; ++df)
        o_mat[orow + df * 16 + l16] = (bf16_t)(oacc[df][r] * rl);
    }
  }
}

// ---------------------------------------------------------------- launch
extern "C" void kernel_launch(void* const* d_in, const int* in_sizes, int n_in,
                              void* d_out, int out_size, void* d_ws, size_t ws_size,
                              hipStream_t stream) {
  const float* x      = (const float*)d_in[0];
  const float* rel    = (const float*)d_in[1];
  const float* ln1_g  = (const float*)d_in[2];
  const float* ln1_b  = (const float*)d_in[3];
  const float* w_qkv  = (const float*)d_in[4];
  const float* q_bias = (const float*)d_in[5];
  const float* v_bias = (const float*)d_in[6];
  const float* w_proj = (const float*)d_in[7];
  const float* b_proj = (const float*)d_in[8];
  const float* gamma1 = (const float*)d_in[9];
  const float* gamma2 = (const float*)d_in[10];
  const float* ln2t_g = (const float*)d_in[11];
  const float* ln2t_b = (const float*)d_in[12];
  const float* ln2i_g = (const float*)d_in[13];
  const float* ln2i_b = (const float*)d_in[14];
  const float* wt1    = (const float*)d_in[15];
  const float* bt1    = (const float*)d_in[16];
  const float* wt2    = (const float*)d_in[17];
  const float* bt2    = (const float*)d_in[18];
  const float* wi1    = (const float*)d_in[19];
  const float* bi1    = (const float*)d_in[20];
  const float* wi2    = (const float*)d_in[21];
  const float* bi2    = (const float*)d_in[22];
  float* out = (float*)d_out;

  char* ws = (char*)d_ws;
  bf16_t* wqkvb  = (bf16_t*)(ws + 0);
  bf16_t* wprojb = (bf16_t*)(ws + 3538944);
  bf16_t* wt1b   = (bf16_t*)(ws + 4718592);
  bf16_t* wi1b   = (bf16_t*)(ws + 9437184);
  bf16_t* wt2b   = (bf16_t*)(ws + 14155776);
  bf16_t* wi2b   = (bf16_t*)(ws + 18874368);
  bf16_t* n1     = (bf16_t*)(ws + 23592960);    // 9984x768 bf16; also n2p, o_mat
  float*  x1     = (float*) (ws + 38928384);    // 30.3MB; head doubles as vtmp
  bf16_t* qbuf   = (bf16_t*)(ws + 69206016);
  bf16_t* kbuf   = (bf16_t*)(ws + 84934656);
  bf16_t* vTbuf  = (bf16_t*)(ws + 100663296);
  bf16_t* vtmp   = (bf16_t*)(ws + 38928384);
  bf16_t* o_mat  = n1;
  bf16_t* n2p    = n1;
  bf16_t* hbuf   = qbuf;

  hipFuncSetAttribute((const void*)gemm256x128<0>, hipFuncAttributeMaxDynamicSharedMemorySize, 98304);
  hipFuncSetAttribute((const void*)gemm256x128<1>, hipFuncAttributeMaxDynamicSharedMemorySize, 98304);
  hipFuncSetAttribute((const void*)gemm256x128<2>, hipFuncAttributeMaxDynamicSharedMemorySize, 98304);
  hipFuncSetAttribute((const void*)gemm256x128<3>, hipFuncAttributeMaxDynamicSharedMemorySize, 98304);

  cast_f32_bf16<<<1024, 256, 0, stream>>>(w_qkv,  wqkvb,  3 * C_ * C_);
  cast_f32_bf16<<<512,  256, 0, stream>>>(w_proj, wprojb, C_ * C_);
  cast_f32_bf16<<<1024, 256, 0, stream>>>(wt1, wt1b, HID * C_);
  cast_f32_bf16<<<1024, 256, 0, stream>>>(wi1, wi1b, HID * C_);
  cast_f32_bf16<<<1024, 256, 0, stream>>>(wt2, wt2b, C_ * HID);
  cast_f32_bf16<<<1024, 256, 0, stream>>>(wi2, wi2b, C_ * HID);
  ln_rows<<<M_REAL, 256, 0, stream>>>(x, ln1_g, ln1_b, n1);

  // QKV GEMM: grid 39*18 (A rows 9856..9983 read stale-but-finite; outputs guarded)
  {
    EpiP P{}; P.bias = q_bias; P.bias2 = v_bias;
    P.ob0 = qbuf; P.ob1 = kbuf; P.ob2 = vtmp;
    gemm256x128<0><<<MB_ * 18, 512, 98304, stream>>>(n1, wqkvb, wqkvb, C_, 18, 0, P);
  }
  transpose_v<<<dim3(NP / 64, B_ * H_), 256, 0, stream>>>(vtmp, vTbuf);
  attn_fwd<<<dim3(NP / 64, B_ * H_), 256, 0, stream>>>(qbuf, kbuf, vTbuf, rel, o_mat);

  // proj + residual -> x1
  {
    EpiP P{}; P.bias = b_proj; P.bias_i = b_proj; P.gamma = gamma1; P.xres = x; P.outf = x1;
    gemm256x128<1><<<MB_ * 6, 512, 98304, stream>>>(o_mat, wprojb, wprojb, C_, 6, 0, P);
  }
  ln2_pack<<<M_PAD, 256, 0, stream>>>(x1, ln2t_g, ln2t_b, ln2i_g, ln2i_b, n2p);

  // MLP fc1 + gelu (text m-blocks 0-2, image 3-38)
  {
    EpiP P{}; P.bias = bt1; P.bias_i = bi1; P.ob0 = hbuf;
    gemm256x128<2><<<MB_ * 24, 512, 98304, stream>>>(n2p, wt1b, wi1b, C_, 24, 3, P);
  }
  // MLP fc2 + gamma2 residual -> d_out
  {
    EpiP P{}; P.bias = bt2; P.bias_i = bi2; P.gamma = gamma2; P.xres = x1; P.outf = out;
    gemm256x128<3><<<MB_ * 6, 512, 98304, stream>>>(hbuf, wt2b, wi2b, HID, 6, 3, P);
  }
}

// Round 7
// 405.914 us; speedup vs baseline: 1.5494x; 1.1570x over previous
//
#include <hip/hip_runtime.h>
#include <hip/hip_bf16.h>
#include <stdint.h>
#include <math.h>

#define AS1 __attribute__((address_space(1)))
#define AS3 __attribute__((address_space(3)))

typedef __bf16 bf16_t;
typedef __bf16 bf16x8 __attribute__((ext_vector_type(8)));
typedef float f32x4 __attribute__((ext_vector_type(4)));

static constexpr int B_ = 16, N_ = 616, C_ = 768, H_ = 12, HD = 64, HID = 3072;
static constexpr int NP = 640;           // padded seq len for q/k/vT
static constexpr int M_REAL = B_ * N_;   // 9856 = 77*128
static constexpr int M_PAD = 9984;       // 78*128 (packed MLP rows)
static constexpr int NT_ = 40, NI_ = 576;

__device__ __forceinline__ void gl_lds16(const void* g, void* l) {
  __builtin_amdgcn_global_load_lds((const AS1 void*)(uintptr_t)g,
                                   (AS3 void*)(uint32_t)(uintptr_t)l, 16, 0, 0);
}
__device__ __forceinline__ f32x4 mfma16(bf16x8 a, bf16x8 b, f32x4 c) {
  return __builtin_amdgcn_mfma_f32_16x16x32_bf16(a, b, c, 0, 0, 0);
}
__device__ __forceinline__ float gelu_f(float x) {
  float u = x * (0.7978845608f + 0.0356774081f * x * x);
  return x / (1.f + __expf(-2.f * u));
}

// ---------------------------------------------------------------- utilities
__global__ void cast_f32_bf16(const float* __restrict__ in, bf16_t* __restrict__ out, int n) {
  int i = blockIdx.x * blockDim.x + threadIdx.x;
  int st = gridDim.x * blockDim.x;
  for (; i < n; i += st) out[i] = (bf16_t)in[i];
}

// ---------------------------------------------------------------- layernorms
__global__ __launch_bounds__(256) void ln_rows(const float* __restrict__ x,
                                               const float* __restrict__ g,
                                               const float* __restrict__ b,
                                               bf16_t* __restrict__ out) {
  int r = blockIdx.x, t = threadIdx.x;
  bf16_t* orow = out + (size_t)r * C_;
  const float* xr = x + (size_t)r * C_;
  float v0 = xr[t], v1 = xr[t + 256], v2 = xr[t + 512];
  float s = v0 + v1 + v2, ss = v0 * v0 + v1 * v1 + v2 * v2;
#pragma unroll
  for (int off = 32; off > 0; off >>= 1) { s += __shfl_xor(s, off); ss += __shfl_xor(ss, off); }
  __shared__ float sm[8];
  int w = t >> 6;
  if ((t & 63) == 0) { sm[w] = s; sm[4 + w] = ss; }
  __syncthreads();
  s = sm[0] + sm[1] + sm[2] + sm[3];
  ss = sm[4] + sm[5] + sm[6] + sm[7];
  float mean = s * (1.f / C_);
  float var = ss * (1.f / C_) - mean * mean;
  float ri = rsqrtf(var + 1e-5f);
  orow[t]       = (bf16_t)((v0 - mean) * ri * g[t]       + b[t]);
  orow[t + 256] = (bf16_t)((v1 - mean) * ri * g[t + 256] + b[t + 256]);
  orow[t + 512] = (bf16_t)((v2 - mean) * ri * g[t + 512] + b[t + 512]);
}

// LN2 + pack: packed rows [0,640)=text, [640,768)=zero pad, [768,9984)=image
__global__ __launch_bounds__(256) void ln2_pack(const float* __restrict__ x1,
                                                const float* __restrict__ gt, const float* __restrict__ bt,
                                                const float* __restrict__ gi, const float* __restrict__ bi,
                                                bf16_t* __restrict__ out) {
  int m = blockIdx.x, t = threadIdx.x;
  if (m >= M_REAL) {
    bf16_t* orow = out + (size_t)(640 + (m - M_REAL)) * C_;
    orow[t] = (bf16_t)0.f; orow[t+256] = (bf16_t)0.f; orow[t+512] = (bf16_t)0.f;
    return;
  }
  int b_ = m / N_, nn = m - b_ * N_;
  const float* g; const float* bb; int dest;
  if (nn < NT_) { dest = b_ * NT_ + nn; g = gt; bb = bt; }
  else          { dest = 768 + b_ * NI_ + (nn - NT_); g = gi; bb = bi; }
  const float* xr = x1 + (size_t)m * C_;
  float v0 = xr[t], v1 = xr[t + 256], v2 = xr[t + 512];
  float s = v0 + v1 + v2, ss = v0 * v0 + v1 * v1 + v2 * v2;
#pragma unroll
  for (int off = 32; off > 0; off >>= 1) { s += __shfl_xor(s, off); ss += __shfl_xor(ss, off); }
  __shared__ float sm[8];
  int w = t >> 6;
  if ((t & 63) == 0) { sm[w] = s; sm[4 + w] = ss; }
  __syncthreads();
  s = sm[0] + sm[1] + sm[2] + sm[3];
  ss = sm[4] + sm[5] + sm[6] + sm[7];
  float mean = s * (1.f / C_);
  float var = ss * (1.f / C_) - mean * mean;
  float ri = rsqrtf(var + 1e-5f);
  bf16_t* orow = out + (size_t)dest * C_;
  orow[t]       = (bf16_t)((v0 - mean) * ri * g[t]       + bb[t]);
  orow[t + 256] = (bf16_t)((v1 - mean) * ri * g[t + 256] + bb[t + 256]);
  orow[t + 512] = (bf16_t)((v2 - mean) * ri * g[t + 512] + bb[t + 512]);
}

// ---------------------------------------------------------------- v transpose
__global__ __launch_bounds__(256) void transpose_v(const bf16_t* __restrict__ v,
                                                   bf16_t* __restrict__ vT) {
  __shared__ bf16_t t[64][80];
  int n0 = blockIdx.x * 64, bh = blockIdx.y;
  int tid = threadIdx.x;
  int r0 = tid >> 2, c0 = (tid & 3) * 16;
  int n = n0 + r0;
#pragma unroll
  for (int cc = 0; cc < 2; ++cc) {
    bf16x8 vv;
    if (n < N_) vv = *(const bf16x8*)(v + ((size_t)bh * N_ + n) * HD + c0 + cc * 8);
    else {
#pragma unroll
      for (int e = 0; e < 8; ++e) vv[e] = (bf16_t)0.f;
    }
#pragma unroll
    for (int e = 0; e < 8; ++e) t[c0 + cc * 8 + e][r0] = vv[e];
  }
  __syncthreads();
  int d = tid >> 2, nc = (tid & 3) * 16;
  bf16_t* dst = vT + ((size_t)(bh * HD + d)) * NP + n0 + nc;
  *(bf16x8*)dst       = *(const bf16x8*)&t[d][nc];
  *(bf16x8*)(dst + 8) = *(const bf16x8*)&t[d][nc + 8];
}

// ---------------------------------------------------------------- GEMM 128x128, m97 structure
// Single-buffered 32 KB LDS, 4 waves, 3 blocks/CU (cross-block overlap covers
// the __syncthreads drains, m114).  Row-major [128][64] tiles with within-row
// XOR swizzle applied to BOTH stage-source and frag-read (rule 21):
//   stage: slot s=j*256+tid; row=s>>3, src granule=(s&7)^((s>>3)&7)
//          -> each wave-instruction = 8 full 128B rows, fully coalesced.
//   read:  row R (R&7 == l16&7), granule (kk*4+lq)^(l16&7)
//          -> 2-way bank aliasing only (free, m136).
struct EpiP {
  const float* bias;
  const float* bias_i;
  const float* bias2;
  const float* gamma;
  const float* xres;
  float* outf;
  bf16_t* ob0;
  bf16_t* ob1;
  bf16_t* ob2;
};

template <int EPI>
__global__ __launch_bounds__(256, 3) void gemm128(const bf16_t* __restrict__ A,
                                                  const bf16_t* __restrict__ Bt,
                                                  const bf16_t* __restrict__ Bi,
                                                  int K, int MBc, int nb, int tb, EpiP P) {
  __shared__ bf16_t As[8192], Bs[8192];   // 16 KB + 16 KB, single-buffered
  const int tid = threadIdx.x, lane = tid & 63, w = tid >> 6;
  const int l16 = lane & 15, lq = lane >> 4;
  const int wr = w >> 1, wc = w & 1;
  const int NTk = K >> 6;

  // XCD-bijective remap (m204), m-fast decode for A-panel L2 locality
  int mblk, nblk;
  {
    int nwg = MBc * nb;
    int bid = blockIdx.x;
    int q8 = nwg >> 3, r8 = nwg & 7;
    int xcd = bid & 7, sidx = bid >> 3;
    int wg = (xcd < r8 ? xcd * (q8 + 1) : r8 * (q8 + 1) + (xcd - r8) * q8) + sidx;
    nblk = wg / MBc; mblk = wg - nblk * MBc;
  }
  const int m0 = mblk * 128, n0 = nblk * 128;
  const bf16_t* Bw = (mblk < tb) ? Bt : Bi;

  f32x4 acc[4][4] = {};

  // staging: per-lane source (row, swizzled granule); LDS dest wave-uniform
  const int swsrc = ((lane & 7) ^ ((lane >> 3) & 7)) * 8;   // elems
  size_t aoff[4], boff[4];
  int ldsoff[4];
#pragma unroll
  for (int j = 0; j < 4; ++j) {
    int srow = j * 32 + w * 8 + (lane >> 3);
    aoff[j] = (size_t)(m0 + srow) * K + swsrc;
    boff[j] = (size_t)(n0 + srow) * K + swsrc;
    ldsoff[j] = (j * 256 + w * 64) * 8;     // wave-uniform elem offset
  }
  // frag-read lane-constant swizzled granule offsets (elems)
  const int sw0 = ((0 * 4 + lq) ^ (l16 & 7)) * 8;
  const int sw1 = ((1 * 4 + lq) ^ (l16 & 7)) * 8;
  const int rbA = (wr * 64 + l16) * 64;
  const int rbB = (wc * 64 + l16) * 64;

  for (int t = 0; t < NTk; ++t) {
    const size_t kadd = (size_t)t * 64;
#pragma unroll
    for (int j = 0; j < 4; ++j) gl_lds16(A + aoff[j] + kadd, As + ldsoff[j]);
#pragma unroll
    for (int j = 0; j < 4; ++j) gl_lds16(Bw + boff[j] + kadd, Bs + ldsoff[j]);
    __syncthreads();                        // drains vmcnt(0): DMA landed

    bf16x8 av[4][2], bv[4][2];
#pragma unroll
    for (int i = 0; i < 4; ++i) {
      av[i][0] = *(const bf16x8*)(As + rbA + i * 1024 + sw0);
      av[i][1] = *(const bf16x8*)(As + rbA + i * 1024 + sw1);
      bv[i][0] = *(const bf16x8*)(Bs + rbB + i * 1024 + sw0);
      bv[i][1] = *(const bf16x8*)(Bs + rbB + i * 1024 + sw1);
    }
#pragma unroll
    for (int kk = 0; kk < 2; ++kk)
#pragma unroll
      for (int i = 0; i < 4; ++i)
#pragma unroll
        for (int j = 0; j < 4; ++j)
          acc[i][j] = mfma16(av[i][kk], bv[j][kk], acc[i][j]);
    __syncthreads();                        // all reads done before next stage
  }

  // epilogue: wave 64x64: rows m0+wr*64+i*16+lq*4+rr, cols n0+wc*64+j*16+l16
  const float* bsel = (mblk < tb) ? P.bias : P.bias_i;
  (void)bsel;
  int which = n0 / C_;
#pragma unroll
  for (int i = 0; i < 4; ++i) {
    int mb = m0 + wr * 64 + i * 16 + lq * 4;
#pragma unroll
    for (int j = 0; j < 4; ++j) {
      int jc = n0 + wc * 64 + j * 16 + l16;
#pragma unroll
      for (int rr = 0; rr < 4; ++rr) {
        int m = mb + rr;
        float v = acc[i][j][rr];
        if constexpr (EPI == 0) {       // QKV split
          int b_ = m / N_, nn = m - b_ * N_;
          int jj = jc - which * C_;
          int hh = jj >> 6, d = jj & 63;
          int bh = b_ * H_ + hh;
          if (which == 0) {
            P.ob0[((size_t)bh * NP + nn) * HD + d] = (bf16_t)((v + P.bias[jj]) * 0.125f);
          } else if (which == 1) {
            P.ob1[((size_t)bh * NP + nn) * HD + d] = (bf16_t)v;
          } else {
            P.ob2[((size_t)bh * N_ + nn) * HD + d] = (bf16_t)(v + P.bias2[jj]);
          }
        } else if constexpr (EPI == 1) {  // proj: x1 = x + gamma1*(o+b)
          size_t idx = (size_t)m * C_ + jc;
          P.outf[idx] = P.xres[idx] + P.gamma[jc] * (v + P.bias[jc]);
        } else if constexpr (EPI == 2) {  // mlp1: gelu -> hbuf
          P.ob0[(size_t)m * HID + jc] = (bf16_t)gelu_f(v + bsel[jc]);
        } else {                          // mlp2: residual scatter to d_out
          int orig = -1;
          if (m < 640)      orig = (m / NT_) * N_ + (m - (m / NT_) * NT_);
          else if (m >= 768) {
            int mi = m - 768;
            int bb = mi / NI_;
            orig = bb * N_ + NT_ + (mi - bb * NI_);
          }
          if (orig >= 0) {
            size_t idx = (size_t)orig * C_ + jc;
            P.outf[idx] = P.xres[idx] + P.gamma[jc] * (v + bsel[jc]);
          }
        }
      }
    }
  }
}

// ---------------------------------------------------------------- attention (validated r1)
__global__ __launch_bounds__(256) void attn_fwd(const bf16_t* __restrict__ qb,
                                                const bf16_t* __restrict__ kb,
                                                const bf16_t* __restrict__ vT,
                                                const float* __restrict__ rel_bias,
                                                bf16_t* __restrict__ o_mat) {
  __shared__ bf16_t qs[64 * 64], ks[64 * 64], vs[64 * 64];
  __shared__ bf16_t ps[4][16 * 64];
  const int tid = threadIdx.x, lane = tid & 63, w = tid >> 6;
  const int l16 = lane & 15, lq = lane >> 4;
  const int qt = blockIdx.x, bh = blockIdx.y;
  const int b_ = bh / H_, h = bh - b_ * H_;
  const int q0 = qt * 64;

  const bf16_t* qsrc = qb + ((size_t)bh * NP + q0) * HD;
#pragma unroll
  for (int it = 0; it < 2; ++it) {
    int cb = it * 256 + w * 64, c = cb + lane;
    gl_lds16(qsrc + c * 8, qs + cb * 8);
  }
  __syncthreads();
  bf16x8 aq[2];
  aq[0] = *(const bf16x8*)(qs + (w * 16 + l16) * 64 + 0 + lq * 8);
  aq[1] = *(const bf16x8*)(qs + (w * 16 + l16) * 64 + 32 + lq * 8);

  float mrun[4], lrun[4];
  f32x4 oacc[4] = {};
#pragma unroll
  for (int r = 0; r < 4; ++r) { mrun[r] = -3e38f; lrun[r] = 0.f; }

  const int qrow_base = q0 + w * 16 + lq * 4;
  const float* biasr = rel_bias + (size_t)h * N_ * N_;

  for (int kt = 0; kt < NP / 64; ++kt) {
    int n0k = kt * 64;
    const bf16_t* ksrc = kb + ((size_t)bh * NP + n0k) * HD;
#pragma unroll
    for (int it = 0; it < 2; ++it) {
      int cb = it * 256 + w * 64, c = cb + lane;
      gl_lds16(ksrc + c * 8, ks + cb * 8);
      int d = c >> 3, kc = (c & 7) << 3;
      gl_lds16(vT + ((size_t)bh * HD + d) * NP + n0k + kc, vs + cb * 8);
    }
    __syncthreads();

    f32x4 sf[4];
#pragma unroll
    for (int f = 0; f < 4; ++f) {
      f32x4 z = {};
#pragma unroll
      for (int kk = 0; kk < 2; ++kk) {
        bf16x8 bk = *(const bf16x8*)(ks + (f * 16 + l16) * 64 + kk * 32 + lq * 8);
        z = mfma16(aq[kk], bk, z);
      }
      sf[f] = z;
    }
    float pm[4];
#pragma unroll
    for (int r = 0; r < 4; ++r) pm[r] = -3e38f;
#pragma unroll
    for (int f = 0; f < 4; ++f) {
      int kcol = n0k + f * 16 + l16;
#pragma unroll
      for (int r = 0; r < 4; ++r) {
        int qg = qrow_base + r;
        int qc = qg < N_ ? qg : (N_ - 1);
        float sv = (kcol < N_) ? (sf[f][r] + biasr[(size_t)qc * N_ + kcol]) : -3e38f;
        sf[f][r] = sv;
        pm[r] = fmaxf(pm[r], sv);
      }
    }
#pragma unroll
    for (int off = 1; off < 16; off <<= 1)
#pragma unroll
      for (int r = 0; r < 4; ++r)
        pm[r] = fmaxf(pm[r], __shfl_xor(pm[r], off, 16));

    float alpha[4], lsum[4];
#pragma unroll
    for (int r = 0; r < 4; ++r) {
      float mnew = fmaxf(mrun[r], pm[r]);
      alpha[r] = __expf(mrun[r] - mnew);
      mrun[r] = mnew;
      lsum[r] = 0.f;
    }
#pragma unroll
    for (int f = 0; f < 4; ++f)
#pragma unroll
      for (int r = 0; r < 4; ++r) {
        float p = __expf(sf[f][r] - mrun[r]);
        sf[f][r] = p;
        lsum[r] += p;
      }
#pragma unroll
    for (int off = 1; off < 16; off <<= 1)
#pragma unroll
      for (int r = 0; r < 4; ++r)
        lsum[r] += __shfl_xor(lsum[r], off, 16);
#pragma unroll
    for (int r = 0; r < 4; ++r) lrun[r] = lrun[r] * alpha[r] + lsum[r];
#pragma unroll
    for (int df = 0; df < 4; ++df)
#pragma unroll
      for (int r = 0; r < 4; ++r) oacc[df][r] *= alpha[r];

    bf16_t* psw = ps[w];
#pragma unroll
    for (int f = 0; f < 4; ++f)
#pragma unroll
      for (int r = 0; r < 4; ++r)
        psw[(lq * 4 + r) * 64 + f * 16 + l16] = (bf16_t)sf[f][r];
    __syncthreads();

#pragma unroll
    for (int kk = 0; kk < 2; ++kk) {
      bf16x8 pa = *(const bf16x8*)(psw + l16 * 64 + kk * 32 + lq * 8);
#pragma unroll
      for (int df = 0; df < 4; ++df) {
        bf16x8 bv = *(const bf16x8*)(vs + (df * 16 + l16) * 64 + kk * 32 + lq * 8);
        oacc[df] = mfma16(pa, bv, oacc[df]);
      }
    }
    __syncthreads();
  }

#pragma unroll
  for (int r = 0; r < 4; ++r) {
    int qg = qrow_base + r;
    if (qg < N_) {
      float rl = 1.f / lrun[r];
      size_t orow = ((size_t)(b_ * N_ + qg)) * C_ + h * HD;
#pragma unroll
      for (int df = 0; df < 4; ++df)
        o_mat[orow + df * 16 + l16] = (bf16_t)(oacc[df][r] * rl);
    }
  }
}

// ---------------------------------------------------------------- launch
extern "C" void kernel_launch(void* const* d_in, const int* in_sizes, int n_in,
                              void* d_out, int out_size, void* d_ws, size_t ws_size,
                              hipStream_t stream) {
  const float* x      = (const float*)d_in[0];
  const float* rel    = (const float*)d_in[1];
  const float* ln1_g  = (const float*)d_in[2];
  const float* ln1_b  = (const float*)d_in[3];
  const float* w_qkv  = (const float*)d_in[4];
  const float* q_bias = (const float*)d_in[5];
  const float* v_bias = (const float*)d_in[6];
  const float* w_proj = (const float*)d_in[7];
  const float* b_proj = (const float*)d_in[8];
  const float* gamma1 = (const float*)d_in[9];
  const float* gamma2 = (const float*)d_in[10];
  const float* ln2t_g = (const float*)d_in[11];
  const float* ln2t_b = (const float*)d_in[12];
  const float* ln2i_g = (const float*)d_in[13];
  const float* ln2i_b = (const float*)d_in[14];
  const float* wt1    = (const float*)d_in[15];
  const float* bt1    = (const float*)d_in[16];
  const float* wt2    = (const float*)d_in[17];
  const float* bt2    = (const float*)d_in[18];
  const float* wi1    = (const float*)d_in[19];
  const float* bi1    = (const float*)d_in[20];
  const float* wi2    = (const float*)d_in[21];
  const float* bi2    = (const float*)d_in[22];
  float* out = (float*)d_out;

  char* ws = (char*)d_ws;
  bf16_t* wqkvb  = (bf16_t*)(ws + 0);
  bf16_t* wprojb = (bf16_t*)(ws + 3538944);
  bf16_t* wt1b   = (bf16_t*)(ws + 4718592);
  bf16_t* wi1b   = (bf16_t*)(ws + 9437184);
  bf16_t* wt2b   = (bf16_t*)(ws + 14155776);
  bf16_t* wi2b   = (bf16_t*)(ws + 18874368);
  bf16_t* n1     = (bf16_t*)(ws + 23592960);    // 9984x768 bf16; also n2p, o_mat
  float*  x1     = (float*) (ws + 38928384);    // 30.3MB; head doubles as vtmp
  bf16_t* qbuf   = (bf16_t*)(ws + 69206016);
  bf16_t* kbuf   = (bf16_t*)(ws + 84934656);
  bf16_t* vTbuf  = (bf16_t*)(ws + 100663296);
  bf16_t* vtmp   = (bf16_t*)(ws + 38928384);
  bf16_t* o_mat  = n1;
  bf16_t* n2p    = n1;
  bf16_t* hbuf   = qbuf;

  cast_f32_bf16<<<1024, 256, 0, stream>>>(w_qkv,  wqkvb,  3 * C_ * C_);
  cast_f32_bf16<<<512,  256, 0, stream>>>(w_proj, wprojb, C_ * C_);
  cast_f32_bf16<<<1024, 256, 0, stream>>>(wt1, wt1b, HID * C_);
  cast_f32_bf16<<<1024, 256, 0, stream>>>(wi1, wi1b, HID * C_);
  cast_f32_bf16<<<1024, 256, 0, stream>>>(wt2, wt2b, C_ * HID);
  cast_f32_bf16<<<1024, 256, 0, stream>>>(wi2, wi2b, C_ * HID);
  ln_rows<<<M_REAL, 256, 0, stream>>>(x, ln1_g, ln1_b, n1);

  // QKV GEMM: 77 x 18 blocks
  {
    EpiP P{}; P.bias = q_bias; P.bias2 = v_bias;
    P.ob0 = qbuf; P.ob1 = kbuf; P.ob2 = vtmp;
    gemm128<0><<<77 * 18, 256, 0, stream>>>(n1, wqkvb, wqkvb, C_, 77, 18, 0, P);
  }
  transpose_v<<<dim3(NP / 64, B_ * H_), 256, 0, stream>>>(vtmp, vTbuf);
  attn_fwd<<<dim3(NP / 64, B_ * H_), 256, 0, stream>>>(qbuf, kbuf, vTbuf, rel, o_mat);

  // proj + residual -> x1 : 77 x 6 blocks
  {
    EpiP P{}; P.bias = b_proj; P.bias_i = b_proj; P.gamma = gamma1; P.xres = x; P.outf = x1;
    gemm128<1><<<77 * 6, 256, 0, stream>>>(o_mat, wprojb, wprojb, C_, 77, 6, 0, P);
  }
  ln2_pack<<<M_PAD, 256, 0, stream>>>(x1, ln2t_g, ln2t_b, ln2i_g, ln2i_b, n2p);

  // MLP fc1 + gelu: 78 x 24 blocks (text m-blocks 0-5)
  {
    EpiP P{}; P.bias = bt1; P.bias_i = bi1; P.ob0 = hbuf;
    gemm128<2><<<78 * 24, 256, 0, stream>>>(n2p, wt1b, wi1b, C_, 78, 24, 6, P);
  }
  // MLP fc2 + gamma2 residual -> d_out: 78 x 6 blocks
  {
    EpiP P{}; P.bias = bt2; P.bias_i = bi2; P.gamma = gamma2; P.xres = x1; P.outf = out;
    gemm128<3><<<78 * 6, 256, 0, stream>>>(hbuf, wt2b, wi2b, HID, 78, 6, 6, P);
  }
}

// Round 8
// 395.457 us; speedup vs baseline: 1.5904x; 1.0264x over previous
//
#include <hip/hip_runtime.h>
#include <hip/hip_bf16.h>
#include <stdint.h>
#include <math.h>

#define AS1 __attribute__((address_space(1)))
#define AS3 __attribute__((address_space(3)))

typedef __bf16 bf16_t;
typedef __bf16 bf16x8 __attribute__((ext_vector_type(8)));
typedef float f32x4 __attribute__((ext_vector_type(4)));

static constexpr int B_ = 16, N_ = 616, C_ = 768, H_ = 12, HD = 64, HID = 3072;
static constexpr int NP = 640;           // padded seq len for q/k/vT
static constexpr int M_REAL = B_ * N_;   // 9856 = 77*128
static constexpr int M_PAD = 9984;       // 78*128 (packed MLP rows)
static constexpr int NT_ = 40, NI_ = 576;

__device__ __forceinline__ void gl_lds16(const void* g, void* l) {
  __builtin_amdgcn_global_load_lds((const AS1 void*)(uintptr_t)g,
                                   (AS3 void*)(uint32_t)(uintptr_t)l, 16, 0, 0);
}
__device__ __forceinline__ f32x4 mfma16(bf16x8 a, bf16x8 b, f32x4 c) {
  return __builtin_amdgcn_mfma_f32_16x16x32_bf16(a, b, c, 0, 0, 0);
}
__device__ __forceinline__ float gelu_f(float x) {
  float u = x * (0.7978845608f + 0.0356774081f * x * x);
  return x / (1.f + __expf(-2.f * u));
}

// ---------------------------------------------------------------- utilities
__global__ void cast_f32_bf16(const float* __restrict__ in, bf16_t* __restrict__ out, int n) {
  int i = blockIdx.x * blockDim.x + threadIdx.x;
  int st = gridDim.x * blockDim.x;
  for (; i < n; i += st) out[i] = (bf16_t)in[i];
}

// ---------------------------------------------------------------- layernorms
__global__ __launch_bounds__(256) void ln_rows(const float* __restrict__ x,
                                               const float* __restrict__ g,
                                               const float* __restrict__ b,
                                               bf16_t* __restrict__ out) {
  int r = blockIdx.x, t = threadIdx.x;
  bf16_t* orow = out + (size_t)r * C_;
  const float* xr = x + (size_t)r * C_;
  float v0 = xr[t], v1 = xr[t + 256], v2 = xr[t + 512];
  float s = v0 + v1 + v2, ss = v0 * v0 + v1 * v1 + v2 * v2;
#pragma unroll
  for (int off = 32; off > 0; off >>= 1) { s += __shfl_xor(s, off); ss += __shfl_xor(ss, off); }
  __shared__ float sm[8];
  int w = t >> 6;
  if ((t & 63) == 0) { sm[w] = s; sm[4 + w] = ss; }
  __syncthreads();
  s = sm[0] + sm[1] + sm[2] + sm[3];
  ss = sm[4] + sm[5] + sm[6] + sm[7];
  float mean = s * (1.f / C_);
  float var = ss * (1.f / C_) - mean * mean;
  float ri = rsqrtf(var + 1e-5f);
  orow[t]       = (bf16_t)((v0 - mean) * ri * g[t]       + b[t]);
  orow[t + 256] = (bf16_t)((v1 - mean) * ri * g[t + 256] + b[t + 256]);
  orow[t + 512] = (bf16_t)((v2 - mean) * ri * g[t + 512] + b[t + 512]);
}

// LN2 + pack: packed rows [0,640)=text, [640,768)=zero pad, [768,9984)=image
__global__ __launch_bounds__(256) void ln2_pack(const float* __restrict__ x1,
                                                const float* __restrict__ gt, const float* __restrict__ bt,
                                                const float* __restrict__ gi, const float* __restrict__ bi,
                                                bf16_t* __restrict__ out) {
  int m = blockIdx.x, t = threadIdx.x;
  if (m >= M_REAL) {
    bf16_t* orow = out + (size_t)(640 + (m - M_REAL)) * C_;
    orow[t] = (bf16_t)0.f; orow[t+256] = (bf16_t)0.f; orow[t+512] = (bf16_t)0.f;
    return;
  }
  int b_ = m / N_, nn = m - b_ * N_;
  const float* g; const float* bb; int dest;
  if (nn < NT_) { dest = b_ * NT_ + nn; g = gt; bb = bt; }
  else          { dest = 768 + b_ * NI_ + (nn - NT_); g = gi; bb = bi; }
  const float* xr = x1 + (size_t)m * C_;
  float v0 = xr[t], v1 = xr[t + 256], v2 = xr[t + 512];
  float s = v0 + v1 + v2, ss = v0 * v0 + v1 * v1 + v2 * v2;
#pragma unroll
  for (int off = 32; off > 0; off >>= 1) { s += __shfl_xor(s, off); ss += __shfl_xor(ss, off); }
  __shared__ float sm[8];
  int w = t >> 6;
  if ((t & 63) == 0) { sm[w] = s; sm[4 + w] = ss; }
  __syncthreads();
  s = sm[0] + sm[1] + sm[2] + sm[3];
  ss = sm[4] + sm[5] + sm[6] + sm[7];
  float mean = s * (1.f / C_);
  float var = ss * (1.f / C_) - mean * mean;
  float ri = rsqrtf(var + 1e-5f);
  bf16_t* orow = out + (size_t)dest * C_;
  orow[t]       = (bf16_t)((v0 - mean) * ri * g[t]       + bb[t]);
  orow[t + 256] = (bf16_t)((v1 - mean) * ri * g[t + 256] + bb[t + 256]);
  orow[t + 512] = (bf16_t)((v2 - mean) * ri * g[t + 512] + bb[t + 512]);
}

// ---------------------------------------------------------------- v transpose
__global__ __launch_bounds__(256) void transpose_v(const bf16_t* __restrict__ v,
                                                   bf16_t* __restrict__ vT) {
  __shared__ bf16_t t[64][80];
  int n0 = blockIdx.x * 64, bh = blockIdx.y;
  int tid = threadIdx.x;
  int r0 = tid >> 2, c0 = (tid & 3) * 16;
  int n = n0 + r0;
#pragma unroll
  for (int cc = 0; cc < 2; ++cc) {
    bf16x8 vv;
    if (n < N_) vv = *(const bf16x8*)(v + ((size_t)bh * N_ + n) * HD + c0 + cc * 8);
    else {
#pragma unroll
      for (int e = 0; e < 8; ++e) vv[e] = (bf16_t)0.f;
    }
#pragma unroll
    for (int e = 0; e < 8; ++e) t[c0 + cc * 8 + e][r0] = vv[e];
  }
  __syncthreads();
  int d = tid >> 2, nc = (tid & 3) * 16;
  bf16_t* dst = vT + ((size_t)(bh * HD + d)) * NP + n0 + nc;
  *(bf16x8*)dst       = *(const bf16x8*)&t[d][nc];
  *(bf16x8*)(dst + 8) = *(const bf16x8*)&t[d][nc + 8];
}

// ---------------------------------------------------------------- GEMM 128x128, m97 structure (validated r7)
struct EpiP {
  const float* bias;
  const float* bias_i;
  const float* bias2;
  const float* gamma;
  const float* xres;
  float* outf;
  bf16_t* ob0;
  bf16_t* ob1;
  bf16_t* ob2;
};

template <int EPI>
__global__ __launch_bounds__(256, 3) void gemm128(const bf16_t* __restrict__ A,
                                                  const bf16_t* __restrict__ Bt,
                                                  const bf16_t* __restrict__ Bi,
                                                  int K, int MBc, int nb, int tb, EpiP P) {
  __shared__ bf16_t As[8192], Bs[8192];   // 16 KB + 16 KB, single-buffered
  const int tid = threadIdx.x, lane = tid & 63, w = tid >> 6;
  const int l16 = lane & 15, lq = lane >> 4;
  const int wr = w >> 1, wc = w & 1;
  const int NTk = K >> 6;

  int mblk, nblk;
  {
    int nwg = MBc * nb;
    int bid = blockIdx.x;
    int q8 = nwg >> 3, r8 = nwg & 7;
    int xcd = bid & 7, sidx = bid >> 3;
    int wg = (xcd < r8 ? xcd * (q8 + 1) : r8 * (q8 + 1) + (xcd - r8) * q8) + sidx;
    nblk = wg / MBc; mblk = wg - nblk * MBc;
  }
  const int m0 = mblk * 128, n0 = nblk * 128;
  const bf16_t* Bw = (mblk < tb) ? Bt : Bi;

  f32x4 acc[4][4] = {};

  const int swsrc = ((lane & 7) ^ ((lane >> 3) & 7)) * 8;   // elems
  size_t aoff[4], boff[4];
  int ldsoff[4];
#pragma unroll
  for (int j = 0; j < 4; ++j) {
    int srow = j * 32 + w * 8 + (lane >> 3);
    aoff[j] = (size_t)(m0 + srow) * K + swsrc;
    boff[j] = (size_t)(n0 + srow) * K + swsrc;
    ldsoff[j] = (j * 256 + w * 64) * 8;     // wave-uniform elem offset
  }
  const int sw0 = ((0 * 4 + lq) ^ (l16 & 7)) * 8;
  const int sw1 = ((1 * 4 + lq) ^ (l16 & 7)) * 8;
  const int rbA = (wr * 64 + l16) * 64;
  const int rbB = (wc * 64 + l16) * 64;

  for (int t = 0; t < NTk; ++t) {
    const size_t kadd = (size_t)t * 64;
#pragma unroll
    for (int j = 0; j < 4; ++j) gl_lds16(A + aoff[j] + kadd, As + ldsoff[j]);
#pragma unroll
    for (int j = 0; j < 4; ++j) gl_lds16(Bw + boff[j] + kadd, Bs + ldsoff[j]);
    __syncthreads();

    bf16x8 av[4][2], bv[4][2];
#pragma unroll
    for (int i = 0; i < 4; ++i) {
      av[i][0] = *(const bf16x8*)(As + rbA + i * 1024 + sw0);
      av[i][1] = *(const bf16x8*)(As + rbA + i * 1024 + sw1);
      bv[i][0] = *(const bf16x8*)(Bs + rbB + i * 1024 + sw0);
      bv[i][1] = *(const bf16x8*)(Bs + rbB + i * 1024 + sw1);
    }
#pragma unroll
    for (int kk = 0; kk < 2; ++kk)
#pragma unroll
      for (int i = 0; i < 4; ++i)
#pragma unroll
        for (int j = 0; j < 4; ++j)
          acc[i][j] = mfma16(av[i][kk], bv[j][kk], acc[i][j]);
    __syncthreads();
  }

  const float* bsel = (mblk < tb) ? P.bias : P.bias_i;
  (void)bsel;
  int which = n0 / C_;
#pragma unroll
  for (int i = 0; i < 4; ++i) {
    int mb = m0 + wr * 64 + i * 16 + lq * 4;
#pragma unroll
    for (int j = 0; j < 4; ++j) {
      int jc = n0 + wc * 64 + j * 16 + l16;
#pragma unroll
      for (int rr = 0; rr < 4; ++rr) {
        int m = mb + rr;
        float v = acc[i][j][rr];
        if constexpr (EPI == 0) {
          int b_ = m / N_, nn = m - b_ * N_;
          int jj = jc - which * C_;
          int hh = jj >> 6, d = jj & 63;
          int bh = b_ * H_ + hh;
          if (which == 0) {
            P.ob0[((size_t)bh * NP + nn) * HD + d] = (bf16_t)((v + P.bias[jj]) * 0.125f);
          } else if (which == 1) {
            P.ob1[((size_t)bh * NP + nn) * HD + d] = (bf16_t)v;
          } else {
            P.ob2[((size_t)bh * N_ + nn) * HD + d] = (bf16_t)(v + P.bias2[jj]);
          }
        } else if constexpr (EPI == 1) {
          size_t idx = (size_t)m * C_ + jc;
          P.outf[idx] = P.xres[idx] + P.gamma[jc] * (v + P.bias[jc]);
        } else if constexpr (EPI == 2) {
          P.ob0[(size_t)m * HID + jc] = (bf16_t)gelu_f(v + bsel[jc]);
        } else {
          int orig = -1;
          if (m < 640)      orig = (m / NT_) * N_ + (m - (m / NT_) * NT_);
          else if (m >= 768) {
            int mi = m - 768;
            int bb = mi / NI_;
            orig = bb * N_ + NT_ + (mi - bb * NI_);
          }
          if (orig >= 0) {
            size_t idx = (size_t)orig * C_ + jc;
            P.outf[idx] = P.xres[idx] + P.gamma[jc] * (v + bsel[jc]);
          }
        }
      }
    }
  }
}

// ---------------------------------------------------------------- attention
// r8: both-sides XOR swizzle on q/k/v tiles (stage granule (c&7)^((c>>3)&7),
// read granule ^(l16&7) -> 2-way only); P strip padded to 72 elems (144B row,
// 2-way); bf16 rel_bias; XCD-chunked grid wg=(h*16+b)*10+qt so each XCD owns
// ~1.5 bias panels (+ per-bh K/V) in its private L2.
__global__ __launch_bounds__(256) void attn_fwd(const bf16_t* __restrict__ qb,
                                                const bf16_t* __restrict__ kb,
                                                const bf16_t* __restrict__ vT,
                                                const bf16_t* __restrict__ biasb,
                                                bf16_t* __restrict__ o_mat) {
  __shared__ bf16_t qs[64 * 64], ks[64 * 64], vs[64 * 64];
  __shared__ bf16_t ps[4][16 * 72];
  const int tid = threadIdx.x, lane = tid & 63, w = tid >> 6;
  const int l16 = lane & 15, lq = lane >> 4;
  // XCD-chunked remap: nwg=1920 (%8==0): wg = (bid&7)*240 + (bid>>3)
  int wg = (blockIdx.x & 7) * 240 + (blockIdx.x >> 3);
  const int qt = wg % 10;
  const int rb = wg / 10;
  const int b_ = rb & 15, h = rb >> 4;
  const int bh = b_ * H_ + h;
  const int q0 = qt * 64;
  const int swr = (l16 & 7);               // read-side row parity

  const bf16_t* qsrc = qb + ((size_t)bh * NP + q0) * HD;
#pragma unroll
  for (int it = 0; it < 2; ++it) {
    int cb = it * 256 + w * 64, c = cb + lane;
    int row = c >> 3, sg = (c & 7) ^ ((c >> 3) & 7);
    gl_lds16(qsrc + row * 64 + sg * 8, qs + cb * 8);
  }
  __syncthreads();
  bf16x8 aq[2];
  aq[0] = *(const bf16x8*)(qs + (w * 16 + l16) * 64 + ((0 * 4 + lq) ^ swr) * 8);
  aq[1] = *(const bf16x8*)(qs + (w * 16 + l16) * 64 + ((1 * 4 + lq) ^ swr) * 8);

  float mrun[4], lrun[4];
  f32x4 oacc[4] = {};
#pragma unroll
  for (int r = 0; r < 4; ++r) { mrun[r] = -3e38f; lrun[r] = 0.f; }

  const int qrow_base = q0 + w * 16 + lq * 4;
  const bf16_t* biasr = biasb + (size_t)h * N_ * N_;

  for (int kt = 0; kt < NP / 64; ++kt) {
    int n0k = kt * 64;
    const bf16_t* ksrc = kb + ((size_t)bh * NP + n0k) * HD;
#pragma unroll
    for (int it = 0; it < 2; ++it) {
      int cb = it * 256 + w * 64, c = cb + lane;
      int row = c >> 3, sg = (c & 7) ^ ((c >> 3) & 7);
      gl_lds16(ksrc + row * 64 + sg * 8, ks + cb * 8);
      gl_lds16(vT + ((size_t)bh * HD + row) * NP + n0k + sg * 8, vs + cb * 8);
    }
    __syncthreads();

    f32x4 sf[4];
#pragma unroll
    for (int f = 0; f < 4; ++f) {
      f32x4 z = {};
#pragma unroll
      for (int kk = 0; kk < 2; ++kk) {
        bf16x8 bk = *(const bf16x8*)(ks + (f * 16 + l16) * 64 + ((kk * 4 + lq) ^ swr) * 8);
        z = mfma16(aq[kk], bk, z);
      }
      sf[f] = z;
    }
    float pm[4];
#pragma unroll
    for (int r = 0; r < 4; ++r) pm[r] = -3e38f;
#pragma unroll
    for (int f = 0; f < 4; ++f) {
      int kcol = n0k + f * 16 + l16;
#pragma unroll
      for (int r = 0; r < 4; ++r) {
        int qg = qrow_base + r;
        int qc = qg < N_ ? qg : (N_ - 1);
        float sv = (kcol < N_) ? (sf[f][r] + (float)biasr[(size_t)qc * N_ + kcol]) : -3e38f;
        sf[f][r] = sv;
        pm[r] = fmaxf(pm[r], sv);
      }
    }
#pragma unroll
    for (int off = 1; off < 16; off <<= 1)
#pragma unroll
      for (int r = 0; r < 4; ++r)
        pm[r] = fmaxf(pm[r], __shfl_xor(pm[r], off, 16));

    float alpha[4], lsum[4];
#pragma unroll
    for (int r = 0; r < 4; ++r) {
      float mnew = fmaxf(mrun[r], pm[r]);
      alpha[r] = __expf(mrun[r] - mnew);
      mrun[r] = mnew;
      lsum[r] = 0.f;
    }
#pragma unroll
    for (int f = 0; f < 4; ++f)
#pragma unroll
      for (int r = 0; r < 4; ++r) {
        float p = __expf(sf[f][r] - mrun[r]);
        sf[f][r] = p;
        lsum[r] += p;
      }
#pragma unroll
    for (int off = 1; off < 16; off <<= 1)
#pragma unroll
      for (int r = 0; r < 4; ++r)
        lsum[r] += __shfl_xor(lsum[r], off, 16);
#pragma unroll
    for (int r = 0; r < 4; ++r) lrun[r] = lrun[r] * alpha[r] + lsum[r];
#pragma unroll
    for (int df = 0; df < 4; ++df)
#pragma unroll
      for (int r = 0; r < 4; ++r) oacc[df][r] *= alpha[r];

    bf16_t* psw = ps[w];
#pragma unroll
    for (int f = 0; f < 4; ++f)
#pragma unroll
      for (int r = 0; r < 4; ++r)
        psw[(lq * 4 + r) * 72 + f * 16 + l16] = (bf16_t)sf[f][r];
    __syncthreads();

#pragma unroll
    for (int kk = 0; kk < 2; ++kk) {
      bf16x8 pa = *(const bf16x8*)(psw + l16 * 72 + kk * 32 + lq * 8);
#pragma unroll
      for (int df = 0; df < 4; ++df) {
        bf16x8 bv = *(const bf16x8*)(vs + (df * 16 + l16) * 64 + ((kk * 4 + lq) ^ swr) * 8);
        oacc[df] = mfma16(pa, bv, oacc[df]);
      }
    }
    __syncthreads();
  }

#pragma unroll
  for (int r = 0; r < 4; ++r) {
    int qg = qrow_base + r;
    if (qg < N_) {
      float rl = 1.f / lrun[r];
      size_t orow = ((size_t)(b_ * N_ + qg)) * C_ + h * HD;
#pragma unroll
      for (int df = 0; df < 4; ++df)
        o_mat[orow + df * 16 + l16] = (bf16_t)(oacc[df][r] * rl);
    }
  }
}

// ---------------------------------------------------------------- launch
extern "C" void kernel_launch(void* const* d_in, const int* in_sizes, int n_in,
                              void* d_out, int out_size, void* d_ws, size_t ws_size,
                              hipStream_t stream) {
  const float* x      = (const float*)d_in[0];
  const float* rel    = (const float*)d_in[1];
  const float* ln1_g  = (const float*)d_in[2];
  const float* ln1_b  = (const float*)d_in[3];
  const float* w_qkv  = (const float*)d_in[4];
  const float* q_bias = (const float*)d_in[5];
  const float* v_bias = (const float*)d_in[6];
  const float* w_proj = (const float*)d_in[7];
  const float* b_proj = (const float*)d_in[8];
  const float* gamma1 = (const float*)d_in[9];
  const float* gamma2 = (const float*)d_in[10];
  const float* ln2t_g = (const float*)d_in[11];
  const float* ln2t_b = (const float*)d_in[12];
  const float* ln2i_g = (const float*)d_in[13];
  const float* ln2i_b = (const float*)d_in[14];
  const float* wt1    = (const float*)d_in[15];
  const float* bt1    = (const float*)d_in[16];
  const float* wt2    = (const float*)d_in[17];
  const float* bt2    = (const float*)d_in[18];
  const float* wi1    = (const float*)d_in[19];
  const float* bi1    = (const float*)d_in[20];
  const float* wi2    = (const float*)d_in[21];
  const float* bi2    = (const float*)d_in[22];
  float* out = (float*)d_out;

  char* ws = (char*)d_ws;
  bf16_t* wqkvb  = (bf16_t*)(ws + 0);
  bf16_t* wprojb = (bf16_t*)(ws + 3538944);
  bf16_t* wt1b   = (bf16_t*)(ws + 4718592);
  bf16_t* wi1b   = (bf16_t*)(ws + 9437184);
  bf16_t* wt2b   = (bf16_t*)(ws + 14155776);
  bf16_t* wi2b   = (bf16_t*)(ws + 18874368);
  bf16_t* n1     = (bf16_t*)(ws + 23592960);    // 9984x768 bf16; also n2p, o_mat
  float*  x1     = (float*) (ws + 38928384);    // 30.3MB; head doubles as vtmp
  bf16_t* qbuf   = (bf16_t*)(ws + 69206016);
  bf16_t* kbuf   = (bf16_t*)(ws + 84934656);
  bf16_t* vTbuf  = (bf16_t*)(ws + 100663296);
  bf16_t* biasb  = (bf16_t*)(ws + 116391936);   // 9,105,024 B; dead before mlp1 reuses region
  bf16_t* vtmp   = (bf16_t*)(ws + 38928384);
  bf16_t* o_mat  = n1;
  bf16_t* n2p    = n1;
  bf16_t* hbuf   = qbuf;

  cast_f32_bf16<<<1024, 256, 0, stream>>>(w_qkv,  wqkvb,  3 * C_ * C_);
  cast_f32_bf16<<<512,  256, 0, stream>>>(w_proj, wprojb, C_ * C_);
  cast_f32_bf16<<<1024, 256, 0, stream>>>(wt1, wt1b, HID * C_);
  cast_f32_bf16<<<1024, 256, 0, stream>>>(wi1, wi1b, HID * C_);
  cast_f32_bf16<<<1024, 256, 0, stream>>>(wt2, wt2b, C_ * HID);
  cast_f32_bf16<<<1024, 256, 0, stream>>>(wi2, wi2b, C_ * HID);
  cast_f32_bf16<<<1024, 256, 0, stream>>>(rel, biasb, H_ * N_ * N_);
  ln_rows<<<M_REAL, 256, 0, stream>>>(x, ln1_g, ln1_b, n1);

  // QKV GEMM: 77 x 18 blocks
  {
    EpiP P{}; P.bias = q_bias; P.bias2 = v_bias;
    P.ob0 = qbuf; P.ob1 = kbuf; P.ob2 = vtmp;
    gemm128<0><<<77 * 18, 256, 0, stream>>>(n1, wqkvb, wqkvb, C_, 77, 18, 0, P);
  }
  transpose_v<<<dim3(NP / 64, B_ * H_), 256, 0, stream>>>(vtmp, vTbuf);
  attn_fwd<<<1920, 256, 0, stream>>>(qbuf, kbuf, vTbuf, biasb, o_mat);

  // proj + residual -> x1 : 77 x 6 blocks
  {
    EpiP P{}; P.bias = b_proj; P.bias_i = b_proj; P.gamma = gamma1; P.xres = x; P.outf = x1;
    gemm128<1><<<77 * 6, 256, 0, stream>>>(o_mat, wprojb, wprojb, C_, 77, 6, 0, P);
  }
  ln2_pack<<<M_PAD, 256, 0, stream>>>(x1, ln2t_g, ln2t_b, ln2i_g, ln2i_b, n2p);

  // MLP fc1 + gelu: 78 x 24 blocks (text m-blocks 0-5)
  {
    EpiP P{}; P.bias = bt1; P.bias_i = bi1; P.ob0 = hbuf;
    gemm128<2><<<78 * 24, 256, 0, stream>>>(n2p, wt1b, wi1b, C_, 78, 24, 6, P);
  }
  // MLP fc2 + gamma2 residual -> d_out: 78 x 6 blocks
  {
    EpiP P{}; P.bias = bt2; P.bias_i = bi2; P.gamma = gamma2; P.xres = x1; P.outf = out;
    gemm128<3><<<78 * 6, 256, 0, stream>>>(hbuf, wt2b, wi2b, HID, 78, 6, 6, P);
  }
}

// Round 9
// 388.649 us; speedup vs baseline: 1.6182x; 1.0175x over previous
//
#include <hip/hip_runtime.h>
#include <hip/hip_bf16.h>
#include <stdint.h>
#include <math.h>

#define AS1 __attribute__((address_space(1)))
#define AS3 __attribute__((address_space(3)))

typedef __bf16 bf16_t;
typedef __bf16 bf16x8 __attribute__((ext_vector_type(8)));
typedef float f32x4 __attribute__((ext_vector_type(4)));

static constexpr int B_ = 16, N_ = 616, C_ = 768, H_ = 12, HD = 64, HID = 3072;
static constexpr int NP = 640;           // padded seq len for q/k/vT
static constexpr int M_REAL = B_ * N_;   // 9856 = 77*128
static constexpr int M_PAD = 9984;       // 78*128 (packed MLP rows)
static constexpr int NT_ = 40, NI_ = 576;

__device__ __forceinline__ void gl_lds16(const void* g, void* l) {
  __builtin_amdgcn_global_load_lds((const AS1 void*)(uintptr_t)g,
                                   (AS3 void*)(uint32_t)(uintptr_t)l, 16, 0, 0);
}
__device__ __forceinline__ f32x4 mfma16(bf16x8 a, bf16x8 b, f32x4 c) {
  return __builtin_amdgcn_mfma_f32_16x16x32_bf16(a, b, c, 0, 0, 0);
}
__device__ __forceinline__ float gelu_f(float x) {
  float u = x * (0.7978845608f + 0.0356774081f * x * x);
  return x / (1.f + __expf(-2.f * u));
}

// ---------------------------------------------------------------- fused casts
// one launch for all weight casts + bias cast (bias gets -8 shift folded in,
// so attn's fixed-shift softmax is exp(S + biasb) directly)
struct CastArgs {
  const float* src[7];
  bf16_t* dst[7];
  int n4[7];        // quads per segment
};

__global__ __launch_bounds__(256) void cast_all(CastArgs a, int total4) {
  int i = blockIdx.x * blockDim.x + threadIdx.x;
  int st = gridDim.x * blockDim.x;
  for (; i < total4; i += st) {
    int off = i;
#pragma unroll
    for (int s = 0; s < 7; ++s) {
      if (off < a.n4[s]) {
        float4 v = ((const float4*)a.src[s])[off];
        float sub = (s == 6) ? 8.f : 0.f;
        bf16_t* d = a.dst[s] + (size_t)off * 4;
        d[0] = (bf16_t)(v.x - sub); d[1] = (bf16_t)(v.y - sub);
        d[2] = (bf16_t)(v.z - sub); d[3] = (bf16_t)(v.w - sub);
        break;
      }
      off -= a.n4[s];
    }
  }
}

// ---------------------------------------------------------------- layernorms
__global__ __launch_bounds__(256) void ln_rows(const float* __restrict__ x,
                                               const float* __restrict__ g,
                                               const float* __restrict__ b,
                                               bf16_t* __restrict__ out) {
  int r = blockIdx.x, t = threadIdx.x;
  bf16_t* orow = out + (size_t)r * C_;
  const float* xr = x + (size_t)r * C_;
  float v0 = xr[t], v1 = xr[t + 256], v2 = xr[t + 512];
  float s = v0 + v1 + v2, ss = v0 * v0 + v1 * v1 + v2 * v2;
#pragma unroll
  for (int off = 32; off > 0; off >>= 1) { s += __shfl_xor(s, off); ss += __shfl_xor(ss, off); }
  __shared__ float sm[8];
  int w = t >> 6;
  if ((t & 63) == 0) { sm[w] = s; sm[4 + w] = ss; }
  __syncthreads();
  s = sm[0] + sm[1] + sm[2] + sm[3];
  ss = sm[4] + sm[5] + sm[6] + sm[7];
  float mean = s * (1.f / C_);
  float var = ss * (1.f / C_) - mean * mean;
  float ri = rsqrtf(var + 1e-5f);
  orow[t]       = (bf16_t)((v0 - mean) * ri * g[t]       + b[t]);
  orow[t + 256] = (bf16_t)((v1 - mean) * ri * g[t + 256] + b[t + 256]);
  orow[t + 512] = (bf16_t)((v2 - mean) * ri * g[t + 512] + b[t + 512]);
}

// LN2 + pack: packed rows [0,640)=text, [640,768)=zero pad, [768,9984)=image
__global__ __launch_bounds__(256) void ln2_pack(const float* __restrict__ x1,
                                                const float* __restrict__ gt, const float* __restrict__ bt,
                                                const float* __restrict__ gi, const float* __restrict__ bi,
                                                bf16_t* __restrict__ out) {
  int m = blockIdx.x, t = threadIdx.x;
  if (m >= M_REAL) {
    bf16_t* orow = out + (size_t)(640 + (m - M_REAL)) * C_;
    orow[t] = (bf16_t)0.f; orow[t+256] = (bf16_t)0.f; orow[t+512] = (bf16_t)0.f;
    return;
  }
  int b_ = m / N_, nn = m - b_ * N_;
  const float* g; const float* bb; int dest;
  if (nn < NT_) { dest = b_ * NT_ + nn; g = gt; bb = bt; }
  else          { dest = 768 + b_ * NI_ + (nn - NT_); g = gi; bb = bi; }
  const float* xr = x1 + (size_t)m * C_;
  float v0 = xr[t], v1 = xr[t + 256], v2 = xr[t + 512];
  float s = v0 + v1 + v2, ss = v0 * v0 + v1 * v1 + v2 * v2;
#pragma unroll
  for (int off = 32; off > 0; off >>= 1) { s += __shfl_xor(s, off); ss += __shfl_xor(ss, off); }
  __shared__ float sm[8];
  int w = t >> 6;
  if ((t & 63) == 0) { sm[w] = s; sm[4 + w] = ss; }
  __syncthreads();
  s = sm[0] + sm[1] + sm[2] + sm[3];
  ss = sm[4] + sm[5] + sm[6] + sm[7];
  float mean = s * (1.f / C_);
  float var = ss * (1.f / C_) - mean * mean;
  float ri = rsqrtf(var + 1e-5f);
  bf16_t* orow = out + (size_t)dest * C_;
  orow[t]       = (bf16_t)((v0 - mean) * ri * g[t]       + bb[t]);
  orow[t + 256] = (bf16_t)((v1 - mean) * ri * g[t + 256] + bb[t + 256]);
  orow[t + 512] = (bf16_t)((v2 - mean) * ri * g[t + 512] + bb[t + 512]);
}

// ---------------------------------------------------------------- v transpose
__global__ __launch_bounds__(256) void transpose_v(const bf16_t* __restrict__ v,
                                                   bf16_t* __restrict__ vT) {
  __shared__ bf16_t t[64][80];
  int n0 = blockIdx.x * 64, bh = blockIdx.y;
  int tid = threadIdx.x;
  int r0 = tid >> 2, c0 = (tid & 3) * 16;
  int n = n0 + r0;
#pragma unroll
  for (int cc = 0; cc < 2; ++cc) {
    bf16x8 vv;
    if (n < N_) vv = *(const bf16x8*)(v + ((size_t)bh * N_ + n) * HD + c0 + cc * 8);
    else {
#pragma unroll
      for (int e = 0; e < 8; ++e) vv[e] = (bf16_t)0.f;
    }
#pragma unroll
    for (int e = 0; e < 8; ++e) t[c0 + cc * 8 + e][r0] = vv[e];
  }
  __syncthreads();
  int d = tid >> 2, nc = (tid & 3) * 16;
  bf16_t* dst = vT + ((size_t)(bh * HD + d)) * NP + n0 + nc;
  *(bf16x8*)dst       = *(const bf16x8*)&t[d][nc];
  *(bf16x8*)(dst + 8) = *(const bf16x8*)&t[d][nc + 8];
}

// ---------------------------------------------------------------- GEMM 128x128, m97 structure (validated r7)
struct EpiP {
  const float* bias;
  const float* bias_i;
  const float* bias2;
  const float* gamma;
  const float* xres;
  float* outf;
  bf16_t* ob0;
  bf16_t* ob1;
  bf16_t* ob2;
};

template <int EPI>
__global__ __launch_bounds__(256, 3) void gemm128(const bf16_t* __restrict__ A,
                                                  const bf16_t* __restrict__ Bt,
                                                  const bf16_t* __restrict__ Bi,
                                                  int K, int MBc, int nb, int tb, EpiP P) {
  __shared__ bf16_t As[8192], Bs[8192];   // 16 KB + 16 KB, single-buffered
  const int tid = threadIdx.x, lane = tid & 63, w = tid >> 6;
  const int l16 = lane & 15, lq = lane >> 4;
  const int wr = w >> 1, wc = w & 1;
  const int NTk = K >> 6;

  int mblk, nblk;
  {
    int nwg = MBc * nb;
    int bid = blockIdx.x;
    int q8 = nwg >> 3, r8 = nwg & 7;
    int xcd = bid & 7, sidx = bid >> 3;
    int wg = (xcd < r8 ? xcd * (q8 + 1) : r8 * (q8 + 1) + (xcd - r8) * q8) + sidx;
    nblk = wg / MBc; mblk = wg - nblk * MBc;
  }
  const int m0 = mblk * 128, n0 = nblk * 128;
  const bf16_t* Bw = (mblk < tb) ? Bt : Bi;

  f32x4 acc[4][4] = {};

  const int swsrc = ((lane & 7) ^ ((lane >> 3) & 7)) * 8;   // elems
  size_t aoff[4], boff[4];
  int ldsoff[4];
#pragma unroll
  for (int j = 0; j < 4; ++j) {
    int srow = j * 32 + w * 8 + (lane >> 3);
    aoff[j] = (size_t)(m0 + srow) * K + swsrc;
    boff[j] = (size_t)(n0 + srow) * K + swsrc;
    ldsoff[j] = (j * 256 + w * 64) * 8;     // wave-uniform elem offset
  }
  const int sw0 = ((0 * 4 + lq) ^ (l16 & 7)) * 8;
  const int sw1 = ((1 * 4 + lq) ^ (l16 & 7)) * 8;
  const int rbA = (wr * 64 + l16) * 64;
  const int rbB = (wc * 64 + l16) * 64;

  for (int t = 0; t < NTk; ++t) {
    const size_t kadd = (size_t)t * 64;
#pragma unroll
    for (int j = 0; j < 4; ++j) gl_lds16(A + aoff[j] + kadd, As + ldsoff[j]);
#pragma unroll
    for (int j = 0; j < 4; ++j) gl_lds16(Bw + boff[j] + kadd, Bs + ldsoff[j]);
    __syncthreads();

    bf16x8 av[4][2], bv[4][2];
#pragma unroll
    for (int i = 0; i < 4; ++i) {
      av[i][0] = *(const bf16x8*)(As + rbA + i * 1024 + sw0);
      av[i][1] = *(const bf16x8*)(As + rbA + i * 1024 + sw1);
      bv[i][0] = *(const bf16x8*)(Bs + rbB + i * 1024 + sw0);
      bv[i][1] = *(const bf16x8*)(Bs + rbB + i * 1024 + sw1);
    }
#pragma unroll
    for (int kk = 0; kk < 2; ++kk)
#pragma unroll
      for (int i = 0; i < 4; ++i)
#pragma unroll
        for (int j = 0; j < 4; ++j)
          acc[i][j] = mfma16(av[i][kk], bv[j][kk], acc[i][j]);
    __syncthreads();
  }

  const float* bsel = (mblk < tb) ? P.bias : P.bias_i;
  (void)bsel;
  int which = n0 / C_;
#pragma unroll
  for (int i = 0; i < 4; ++i) {
    int mb = m0 + wr * 64 + i * 16 + lq * 4;
#pragma unroll
    for (int j = 0; j < 4; ++j) {
      int jc = n0 + wc * 64 + j * 16 + l16;
#pragma unroll
      for (int rr = 0; rr < 4; ++rr) {
        int m = mb + rr;
        float v = acc[i][j][rr];
        if constexpr (EPI == 0) {
          int b_ = m / N_, nn = m - b_ * N_;
          int jj = jc - which * C_;
          int hh = jj >> 6, d = jj & 63;
          int bh = b_ * H_ + hh;
          if (which == 0) {
            P.ob0[((size_t)bh * NP + nn) * HD + d] = (bf16_t)((v + P.bias[jj]) * 0.125f);
          } else if (which == 1) {
            P.ob1[((size_t)bh * NP + nn) * HD + d] = (bf16_t)v;
          } else {
            P.ob2[((size_t)bh * N_ + nn) * HD + d] = (bf16_t)(v + P.bias2[jj]);
          }
        } else if constexpr (EPI == 1) {
          size_t idx = (size_t)m * C_ + jc;
          P.outf[idx] = P.xres[idx] + P.gamma[jc] * (v + P.bias[jc]);
        } else if constexpr (EPI == 2) {
          P.ob0[(size_t)m * HID + jc] = (bf16_t)gelu_f(v + bsel[jc]);
        } else {
          int orig = -1;
          if (m < 640)      orig = (m / NT_) * N_ + (m - (m / NT_) * NT_);
          else if (m >= 768) {
            int mi = m - 768;
            int bb = mi / NI_;
            orig = bb * N_ + NT_ + (mi - bb * NI_);
          }
          if (orig >= 0) {
            size_t idx = (size_t)orig * C_ + jc;
            P.outf[idx] = P.xres[idx] + P.gamma[jc] * (v + bsel[jc]);
          }
        }
      }
    }
  }
}

// ---------------------------------------------------------------- attention
// r9: FIXED-SHIFT softmax. biasb holds (rel_bias - 8) in bf16, so
// P = exp(S + biasb) = exp(S + bias - 8) — exact softmax after final
// normalization by the row sum (row-uniform shift). Deletes per-kt running
// max, both 16-lane shuffle reductions, alpha rescale. One 16-lane sum
// reduce after the loop. Swizzled q/k/v LDS (r8), XCD-chunked grid (r8).
__global__ __launch_bounds__(256) void attn_fwd(const bf16_t* __restrict__ qb,
                                                const bf16_t* __restrict__ kb,
                                                const bf16_t* __restrict__ vT,
                                                const bf16_t* __restrict__ biasb,
                                                bf16_t* __restrict__ o_mat) {
  __shared__ bf16_t qs[64 * 64], ks[64 * 64], vs[64 * 64];
  __shared__ bf16_t ps[4][16 * 72];
  const int tid = threadIdx.x, lane = tid & 63, w = tid >> 6;
  const int l16 = lane & 15, lq = lane >> 4;
  int wg = (blockIdx.x & 7) * 240 + (blockIdx.x >> 3);
  const int qt = wg % 10;
  const int rb = wg / 10;
  const int b_ = rb & 15, h = rb >> 4;
  const int bh = b_ * H_ + h;
  const int q0 = qt * 64;
  const int swr = (l16 & 7);

  const bf16_t* qsrc = qb + ((size_t)bh * NP + q0) * HD;
#pragma unroll
  for (int it = 0; it < 2; ++it) {
    int cb = it * 256 + w * 64, c = cb + lane;
    int row = c >> 3, sg = (c & 7) ^ ((c >> 3) & 7);
    gl_lds16(qsrc + row * 64 + sg * 8, qs + cb * 8);
  }
  __syncthreads();
  bf16x8 aq[2];
  aq[0] = *(const bf16x8*)(qs + (w * 16 + l16) * 64 + ((0 * 4 + lq) ^ swr) * 8);
  aq[1] = *(const bf16x8*)(qs + (w * 16 + l16) * 64 + ((1 * 4 + lq) ^ swr) * 8);

  float lsum[4] = {0.f, 0.f, 0.f, 0.f};
  f32x4 oacc[4] = {};
  const int qrow_base = q0 + w * 16 + lq * 4;

  // per-row bias pointers (row clamp hoisted; bias already has -8 folded)
  const bf16_t* bp[4];
#pragma unroll
  for (int r = 0; r < 4; ++r) {
    int qg = qrow_base + r;
    int qc = qg < N_ ? qg : (N_ - 1);
    bp[r] = biasb + (size_t)h * N_ * N_ + (size_t)qc * N_;
  }

  for (int kt = 0; kt < NP / 64; ++kt) {
    int n0k = kt * 64;
    const bf16_t* ksrc = kb + ((size_t)bh * NP + n0k) * HD;
#pragma unroll
    for (int it = 0; it < 2; ++it) {
      int cb = it * 256 + w * 64, c = cb + lane;
      int row = c >> 3, sg = (c & 7) ^ ((c >> 3) & 7);
      gl_lds16(ksrc + row * 64 + sg * 8, ks + cb * 8);
      gl_lds16(vT + ((size_t)bh * HD + row) * NP + n0k + sg * 8, vs + cb * 8);
    }
    __syncthreads();

    f32x4 sf[4];
#pragma unroll
    for (int f = 0; f < 4; ++f) {
      f32x4 z = {};
#pragma unroll
      for (int kk = 0; kk < 2; ++kk) {
        bf16x8 bk = *(const bf16x8*)(ks + (f * 16 + l16) * 64 + ((kk * 4 + lq) ^ swr) * 8);
        z = mfma16(aq[kk], bk, z);
      }
      sf[f] = z;
    }

    bf16_t* psw = ps[w];
    if (kt < NP / 64 - 1) {                 // all columns valid
#pragma unroll
      for (int f = 0; f < 4; ++f) {
        int kc = n0k + f * 16 + l16;
#pragma unroll
        for (int r = 0; r < 4; ++r) {
          float p = __expf(sf[f][r] + (float)bp[r][kc]);
          lsum[r] += p;
          psw[(lq * 4 + r) * 72 + f * 16 + l16] = (bf16_t)p;
        }
      }
    } else {                                // last tile: mask cols >= 616
#pragma unroll
      for (int f = 0; f < 4; ++f) {
        int kc = n0k + f * 16 + l16;
        bool ok = kc < N_;
        int kcs = ok ? kc : 0;
#pragma unroll
        for (int r = 0; r < 4; ++r) {
          float p = ok ? __expf(sf[f][r] + (float)bp[r][kcs]) : 0.f;
          lsum[r] += p;
          psw[(lq * 4 + r) * 72 + f * 16 + l16] = (bf16_t)p;
        }
      }
    }
    __syncthreads();

#pragma unroll
    for (int kk = 0; kk < 2; ++kk) {
      bf16x8 pa = *(const bf16x8*)(psw + l16 * 72 + kk * 32 + lq * 8);
#pragma unroll
      for (int df = 0; df < 4; ++df) {
        bf16x8 bv = *(const bf16x8*)(vs + (df * 16 + l16) * 64 + ((kk * 4 + lq) ^ swr) * 8);
        oacc[df] = mfma16(pa, bv, oacc[df]);
      }
    }
    __syncthreads();
  }

  // one cross-lane sum reduce (16-lane groups), then normalize + write
#pragma unroll
  for (int off = 1; off < 16; off <<= 1)
#pragma unroll
    for (int r = 0; r < 4; ++r)
      lsum[r] += __shfl_xor(lsum[r], off, 16);

#pragma unroll
  for (int r = 0; r < 4; ++r) {
    int qg = qrow_base + r;
    if (qg < N_) {
      float rl = 1.f / lsum[r];
      size_t orow = ((size_t)(b_ * N_ + qg)) * C_ + h * HD;
#pragma unroll
      for (int df = 0; df < 4; ++df)
        o_mat[orow + df * 16 + l16] = (bf16_t)(oacc[df][r] * rl);
    }
  }
}

// ---------------------------------------------------------------- launch
extern "C" void kernel_launch(void* const* d_in, const int* in_sizes, int n_in,
                              void* d_out, int out_size, void* d_ws, size_t ws_size,
                              hipStream_t stream) {
  const float* x      = (const float*)d_in[0];
  const float* rel    = (const float*)d_in[1];
  const float* ln1_g  = (const float*)d_in[2];
  const float* ln1_b  = (const float*)d_in[3];
  const float* w_qkv  = (const float*)d_in[4];
  const float* q_bias = (const float*)d_in[5];
  const float* v_bias = (const float*)d_in[6];
  const float* w_proj = (const float*)d_in[7];
  const float* b_proj = (const float*)d_in[8];
  const float* gamma1 = (const float*)d_in[9];
  const float* gamma2 = (const float*)d_in[10];
  const float* ln2t_g = (const float*)d_in[11];
  const float* ln2t_b = (const float*)d_in[12];
  const float* ln2i_g = (const float*)d_in[13];
  const float* ln2i_b = (const float*)d_in[14];
  const float* wt1    = (const float*)d_in[15];
  const float* bt1    = (const float*)d_in[16];
  const float* wt2    = (const float*)d_in[17];
  const float* bt2    = (const float*)d_in[18];
  const float* wi1    = (const float*)d_in[19];
  const float* bi1    = (const float*)d_in[20];
  const float* wi2    = (const float*)d_in[21];
  const float* bi2    = (const float*)d_in[22];
  float* out = (float*)d_out;

  char* ws = (char*)d_ws;
  bf16_t* wqkvb  = (bf16_t*)(ws + 0);
  bf16_t* wprojb = (bf16_t*)(ws + 3538944);
  bf16_t* wt1b   = (bf16_t*)(ws + 4718592);
  bf16_t* wi1b   = (bf16_t*)(ws + 9437184);
  bf16_t* wt2b   = (bf16_t*)(ws + 14155776);
  bf16_t* wi2b   = (bf16_t*)(ws + 18874368);
  bf16_t* n1     = (bf16_t*)(ws + 23592960);    // 9984x768 bf16; also n2p, o_mat
  float*  x1     = (float*) (ws + 38928384);    // 30.3MB; head doubles as vtmp
  bf16_t* qbuf   = (bf16_t*)(ws + 69206016);
  bf16_t* kbuf   = (bf16_t*)(ws + 84934656);
  bf16_t* vTbuf  = (bf16_t*)(ws + 100663296);
  bf16_t* biasb  = (bf16_t*)(ws + 116391936);   // 9.1 MB; dead before mlp1 reuses region
  bf16_t* vtmp   = (bf16_t*)(ws + 38928384);
  bf16_t* o_mat  = n1;
  bf16_t* n2p    = n1;
  bf16_t* hbuf   = qbuf;

  // one fused cast launch (weights + shifted bias)
  {
    CastArgs a;
    a.src[0] = w_qkv;  a.dst[0] = wqkvb;  a.n4[0] = (3 * C_ * C_) / 4;
    a.src[1] = w_proj; a.dst[1] = wprojb; a.n4[1] = (C_ * C_) / 4;
    a.src[2] = wt1;    a.dst[2] = wt1b;   a.n4[2] = (HID * C_) / 4;
    a.src[3] = wi1;    a.dst[3] = wi1b;   a.n4[3] = (HID * C_) / 4;
    a.src[4] = wt2;    a.dst[4] = wt2b;   a.n4[4] = (C_ * HID) / 4;
    a.src[5] = wi2;    a.dst[5] = wi2b;   a.n4[5] = (C_ * HID) / 4;
    a.src[6] = rel;    a.dst[6] = biasb;  a.n4[6] = (H_ * N_ * N_) / 4;
    int total4 = a.n4[0] + a.n4[1] + a.n4[2] + a.n4[3] + a.n4[4] + a.n4[5] + a.n4[6];
    cast_all<<<2048, 256, 0, stream>>>(a, total4);
  }
  ln_rows<<<M_REAL, 256, 0, stream>>>(x, ln1_g, ln1_b, n1);

  // QKV GEMM: 77 x 18 blocks
  {
    EpiP P{}; P.bias = q_bias; P.bias2 = v_bias;
    P.ob0 = qbuf; P.ob1 = kbuf; P.ob2 = vtmp;
    gemm128<0><<<77 * 18, 256, 0, stream>>>(n1, wqkvb, wqkvb, C_, 77, 18, 0, P);
  }
  transpose_v<<<dim3(NP / 64, B_ * H_), 256, 0, stream>>>(vtmp, vTbuf);
  attn_fwd<<<1920, 256, 0, stream>>>(qbuf, kbuf, vTbuf, biasb, o_mat);

  // proj + residual -> x1 : 77 x 6 blocks
  {
    EpiP P{}; P.bias = b_proj; P.bias_i = b_proj; P.gamma = gamma1; P.xres = x; P.outf = x1;
    gemm128<1><<<77 * 6, 256, 0, stream>>>(o_mat, wprojb, wprojb, C_, 77, 6, 0, P);
  }
  ln2_pack<<<M_PAD, 256, 0, stream>>>(x1, ln2t_g, ln2t_b, ln2i_g, ln2i_b, n2p);

  // MLP fc1 + gelu: 78 x 24 blocks (text m-blocks 0-5)
  {
    EpiP P{}; P.bias = bt1; P.bias_i = bi1; P.ob0 = hbuf;
    gemm128<2><<<78 * 24, 256, 0, stream>>>(n2p, wt1b, wi1b, C_, 78, 24, 6, P);
  }
  // MLP fc2 + gamma2 residual -> d_out: 78 x 6 blocks
  {
    EpiP P{}; P.bias = bt2; P.bias_i = bi2; P.gamma = gamma2; P.xres = x1; P.outf = out;
    gemm128<3><<<78 * 6, 256, 0, stream>>>(hbuf, wt2b, wi2b, HID, 78, 6, 6, P);
  }
}

// Round 10
// 350.189 us; speedup vs baseline: 1.7960x; 1.1098x over previous
//
#include <hip/hip_runtime.h>
#include <hip/hip_bf16.h>
#include <stdint.h>
#include <math.h>

#define AS1 __attribute__((address_space(1)))
#define AS3 __attribute__((address_space(3)))

typedef __bf16 bf16_t;
typedef __bf16 bf16x8 __attribute__((ext_vector_type(8)));
typedef float f32x4 __attribute__((ext_vector_type(4)));

static constexpr int B_ = 16, N_ = 616, C_ = 768, H_ = 12, HD = 64, HID = 3072;
static constexpr int NP = 640;           // padded seq len for q/k/vT
static constexpr int M_REAL = B_ * N_;   // 9856 = 77*128
static constexpr int M_PAD = 9984;       // 78*128 (packed MLP rows)
static constexpr int NT_ = 40, NI_ = 576;

__device__ __forceinline__ void gl_lds16(const void* g, void* l) {
  __builtin_amdgcn_global_load_lds((const AS1 void*)(uintptr_t)g,
                                   (AS3 void*)(uint32_t)(uintptr_t)l, 16, 0, 0);
}
__device__ __forceinline__ f32x4 mfma16(bf16x8 a, bf16x8 b, f32x4 c) {
  return __builtin_amdgcn_mfma_f32_16x16x32_bf16(a, b, c, 0, 0, 0);
}
__device__ __forceinline__ float gelu_f(float x) {
  float u = x * (0.7978845608f + 0.0356774081f * x * x);
  return x / (1.f + __expf(-2.f * u));
}

// ---------------------------------------------------------------- fused casts
struct CastArgs {
  const float* src[7];
  bf16_t* dst[7];
  int n4[7];        // quads per segment
};

__global__ __launch_bounds__(256) void cast_all(CastArgs a, int total4) {
  int i = blockIdx.x * blockDim.x + threadIdx.x;
  int st = gridDim.x * blockDim.x;
  for (; i < total4; i += st) {
    int off = i;
#pragma unroll
    for (int s = 0; s < 7; ++s) {
      if (off < a.n4[s]) {
        float4 v = ((const float4*)a.src[s])[off];
        float sub = (s == 6) ? 8.f : 0.f;
        bf16_t* d = a.dst[s] + (size_t)off * 4;
        d[0] = (bf16_t)(v.x - sub); d[1] = (bf16_t)(v.y - sub);
        d[2] = (bf16_t)(v.z - sub); d[3] = (bf16_t)(v.w - sub);
        break;
      }
      off -= a.n4[s];
    }
  }
}

// ---------------------------------------------------------------- layernorms
__global__ __launch_bounds__(256) void ln_rows(const float* __restrict__ x,
                                               const float* __restrict__ g,
                                               const float* __restrict__ b,
                                               bf16_t* __restrict__ out) {
  int r = blockIdx.x, t = threadIdx.x;
  bf16_t* orow = out + (size_t)r * C_;
  const float* xr = x + (size_t)r * C_;
  float v0 = xr[t], v1 = xr[t + 256], v2 = xr[t + 512];
  float s = v0 + v1 + v2, ss = v0 * v0 + v1 * v1 + v2 * v2;
#pragma unroll
  for (int off = 32; off > 0; off >>= 1) { s += __shfl_xor(s, off); ss += __shfl_xor(ss, off); }
  __shared__ float sm[8];
  int w = t >> 6;
  if ((t & 63) == 0) { sm[w] = s; sm[4 + w] = ss; }
  __syncthreads();
  s = sm[0] + sm[1] + sm[2] + sm[3];
  ss = sm[4] + sm[5] + sm[6] + sm[7];
  float mean = s * (1.f / C_);
  float var = ss * (1.f / C_) - mean * mean;
  float ri = rsqrtf(var + 1e-5f);
  orow[t]       = (bf16_t)((v0 - mean) * ri * g[t]       + b[t]);
  orow[t + 256] = (bf16_t)((v1 - mean) * ri * g[t + 256] + b[t + 256]);
  orow[t + 512] = (bf16_t)((v2 - mean) * ri * g[t + 512] + b[t + 512]);
}

// LN2 + pack: packed rows [0,640)=text, [640,768)=zero pad, [768,9984)=image
__global__ __launch_bounds__(256) void ln2_pack(const float* __restrict__ x1,
                                                const float* __restrict__ gt, const float* __restrict__ bt,
                                                const float* __restrict__ gi, const float* __restrict__ bi,
                                                bf16_t* __restrict__ out) {
  int m = blockIdx.x, t = threadIdx.x;
  if (m >= M_REAL) {
    bf16_t* orow = out + (size_t)(640 + (m - M_REAL)) * C_;
    orow[t] = (bf16_t)0.f; orow[t+256] = (bf16_t)0.f; orow[t+512] = (bf16_t)0.f;
    return;
  }
  int b_ = m / N_, nn = m - b_ * N_;
  const float* g; const float* bb; int dest;
  if (nn < NT_) { dest = b_ * NT_ + nn; g = gt; bb = bt; }
  else          { dest = 768 + b_ * NI_ + (nn - NT_); g = gi; bb = bi; }
  const float* xr = x1 + (size_t)m * C_;
  float v0 = xr[t], v1 = xr[t + 256], v2 = xr[t + 512];
  float s = v0 + v1 + v2, ss = v0 * v0 + v1 * v1 + v2 * v2;
#pragma unroll
  for (int off = 32; off > 0; off >>= 1) { s += __shfl_xor(s, off); ss += __shfl_xor(ss, off); }
  __shared__ float sm[8];
  int w = t >> 6;
  if ((t & 63) == 0) { sm[w] = s; sm[4 + w] = ss; }
  __syncthreads();
  s = sm[0] + sm[1] + sm[2] + sm[3];
  ss = sm[4] + sm[5] + sm[6] + sm[7];
  float mean = s * (1.f / C_);
  float var = ss * (1.f / C_) - mean * mean;
  float ri = rsqrtf(var + 1e-5f);
  bf16_t* orow = out + (size_t)dest * C_;
  orow[t]       = (bf16_t)((v0 - mean) * ri * g[t]       + bb[t]);
  orow[t + 256] = (bf16_t)((v1 - mean) * ri * g[t + 256] + bb[t + 256]);
  orow[t + 512] = (bf16_t)((v2 - mean) * ri * g[t + 512] + bb[t + 512]);
}

// ---------------------------------------------------------------- v transpose
__global__ __launch_bounds__(256) void transpose_v(const bf16_t* __restrict__ v,
                                                   bf16_t* __restrict__ vT) {
  __shared__ bf16_t t[64][80];
  int n0 = blockIdx.x * 64, bh = blockIdx.y;
  int tid = threadIdx.x;
  int r0 = tid >> 2, c0 = (tid & 3) * 16;
  int n = n0 + r0;
#pragma unroll
  for (int cc = 0; cc < 2; ++cc) {
    bf16x8 vv;
    if (n < N_) vv = *(const bf16x8*)(v + ((size_t)bh * N_ + n) * HD + c0 + cc * 8);
    else {
#pragma unroll
      for (int e = 0; e < 8; ++e) vv[e] = (bf16_t)0.f;
    }
#pragma unroll
    for (int e = 0; e < 8; ++e) t[c0 + cc * 8 + e][r0] = vv[e];
  }
  __syncthreads();
  int d = tid >> 2, nc = (tid & 3) * 16;
  bf16_t* dst = vT + ((size_t)(bh * HD + d)) * NP + n0 + nc;
  *(bf16x8*)dst       = *(const bf16x8*)&t[d][nc];
  *(bf16x8*)(dst + 8) = *(const bf16x8*)&t[d][nc + 8];
}

// ---------------------------------------------------------------- GEMM 128x128, m97 structure (validated r7)
struct EpiP {
  const float* bias;
  const float* bias_i;
  const float* bias2;
  const float* gamma;
  const float* xres;
  float* outf;
  bf16_t* ob0;
  bf16_t* ob1;
  bf16_t* ob2;
};

template <int EPI>
__global__ __launch_bounds__(256, 3) void gemm128(const bf16_t* __restrict__ A,
                                                  const bf16_t* __restrict__ Bt,
                                                  const bf16_t* __restrict__ Bi,
                                                  int K, int MBc, int nb, int tb, EpiP P) {
  __shared__ bf16_t As[8192], Bs[8192];   // 16 KB + 16 KB, single-buffered
  const int tid = threadIdx.x, lane = tid & 63, w = tid >> 6;
  const int l16 = lane & 15, lq = lane >> 4;
  const int wr = w >> 1, wc = w & 1;
  const int NTk = K >> 6;

  int mblk, nblk;
  {
    int nwg = MBc * nb;
    int bid = blockIdx.x;
    int q8 = nwg >> 3, r8 = nwg & 7;
    int xcd = bid & 7, sidx = bid >> 3;
    int wg = (xcd < r8 ? xcd * (q8 + 1) : r8 * (q8 + 1) + (xcd - r8) * q8) + sidx;
    nblk = wg / MBc; mblk = wg - nblk * MBc;
  }
  const int m0 = mblk * 128, n0 = nblk * 128;
  const bf16_t* Bw = (mblk < tb) ? Bt : Bi;

  f32x4 acc[4][4] = {};

  const int swsrc = ((lane & 7) ^ ((lane >> 3) & 7)) * 8;   // elems
  size_t aoff[4], boff[4];
  int ldsoff[4];
#pragma unroll
  for (int j = 0; j < 4; ++j) {
    int srow = j * 32 + w * 8 + (lane >> 3);
    aoff[j] = (size_t)(m0 + srow) * K + swsrc;
    boff[j] = (size_t)(n0 + srow) * K + swsrc;
    ldsoff[j] = (j * 256 + w * 64) * 8;     // wave-uniform elem offset
  }
  const int sw0 = ((0 * 4 + lq) ^ (l16 & 7)) * 8;
  const int sw1 = ((1 * 4 + lq) ^ (l16 & 7)) * 8;
  const int rbA = (wr * 64 + l16) * 64;
  const int rbB = (wc * 64 + l16) * 64;

  for (int t = 0; t < NTk; ++t) {
    const size_t kadd = (size_t)t * 64;
#pragma unroll
    for (int j = 0; j < 4; ++j) gl_lds16(A + aoff[j] + kadd, As + ldsoff[j]);
#pragma unroll
    for (int j = 0; j < 4; ++j) gl_lds16(Bw + boff[j] + kadd, Bs + ldsoff[j]);
    __syncthreads();

    bf16x8 av[4][2], bv[4][2];
#pragma unroll
    for (int i = 0; i < 4; ++i) {
      av[i][0] = *(const bf16x8*)(As + rbA + i * 1024 + sw0);
      av[i][1] = *(const bf16x8*)(As + rbA + i * 1024 + sw1);
      bv[i][0] = *(const bf16x8*)(Bs + rbB + i * 1024 + sw0);
      bv[i][1] = *(const bf16x8*)(Bs + rbB + i * 1024 + sw1);
    }
#pragma unroll
    for (int kk = 0; kk < 2; ++kk)
#pragma unroll
      for (int i = 0; i < 4; ++i)
#pragma unroll
        for (int j = 0; j < 4; ++j)
          acc[i][j] = mfma16(av[i][kk], bv[j][kk], acc[i][j]);
    __syncthreads();
  }

  const float* bsel = (mblk < tb) ? P.bias : P.bias_i;
  (void)bsel;
  int which = n0 / C_;
#pragma unroll
  for (int i = 0; i < 4; ++i) {
    int mb = m0 + wr * 64 + i * 16 + lq * 4;
#pragma unroll
    for (int j = 0; j < 4; ++j) {
      int jc = n0 + wc * 64 + j * 16 + l16;
#pragma unroll
      for (int rr = 0; rr < 4; ++rr) {
        int m = mb + rr;
        float v = acc[i][j][rr];
        if constexpr (EPI == 0) {
          int b_ = m / N_, nn = m - b_ * N_;
          int jj = jc - which * C_;
          int hh = jj >> 6, d = jj & 63;
          int bh = b_ * H_ + hh;
          if (which == 0) {
            P.ob0[((size_t)bh * NP + nn) * HD + d] = (bf16_t)((v + P.bias[jj]) * 0.125f);
          } else if (which == 1) {
            P.ob1[((size_t)bh * NP + nn) * HD + d] = (bf16_t)v;
          } else {
            P.ob2[((size_t)bh * N_ + nn) * HD + d] = (bf16_t)(v + P.bias2[jj]);
          }
        } else if constexpr (EPI == 1) {
          size_t idx = (size_t)m * C_ + jc;
          P.outf[idx] = P.xres[idx] + P.gamma[jc] * (v + P.bias[jc]);
        } else if constexpr (EPI == 2) {
          P.ob0[(size_t)m * HID + jc] = (bf16_t)gelu_f(v + bsel[jc]);
        } else {
          int orig = -1;
          if (m < 640)      orig = (m / NT_) * N_ + (m - (m / NT_) * NT_);
          else if (m >= 768) {
            int mi = m - 768;
            int bb = mi / NI_;
            orig = bb * N_ + NT_ + (mi - bb * NI_);
          }
          if (orig >= 0) {
            size_t idx = (size_t)orig * C_ + jc;
            P.outf[idx] = P.xres[idx] + P.gamma[jc] * (v + bsel[jc]);
          }
        }
      }
    }
  }
}

// ---------------------------------------------------------------- attention
// r10: double-buffered K/V + ONE barrier per kt.
//   - ps[w] is per-wave: P write->read is within-wave LDS ordering (compiler
//     inserts lgkmcnt) — the old mid-iteration __syncthreads was unnecessary.
//   - stage(c^1, kt+1) issues right after the top barrier, hiding DMA latency
//     under the whole iteration (QK + softmax + PV). The top barrier of the
//     NEXT iteration both drains that DMA (vmcnt) and guarantees all waves
//     finished reading buf c^1 before it is overwritten.
// Fixed-shift softmax (r9), swizzled LDS (r8), XCD-chunked grid (r8).
__global__ __launch_bounds__(256) void attn_fwd(const bf16_t* __restrict__ qb,
                                                const bf16_t* __restrict__ kb,
                                                const bf16_t* __restrict__ vT,
                                                const bf16_t* __restrict__ biasb,
                                                bf16_t* __restrict__ o_mat) {
  __shared__ bf16_t qs[64 * 64];
  __shared__ bf16_t ks[2][64 * 64], vs[2][64 * 64];
  __shared__ bf16_t ps[4][16 * 72];
  const int tid = threadIdx.x, lane = tid & 63, w = tid >> 6;
  const int l16 = lane & 15, lq = lane >> 4;
  int wg = (blockIdx.x & 7) * 240 + (blockIdx.x >> 3);
  const int qt = wg % 10;
  const int rb = wg / 10;
  const int b_ = rb & 15, h = rb >> 4;
  const int bh = b_ * H_ + h;
  const int q0 = qt * 64;
  const int swr = (l16 & 7);
  constexpr int NKT = NP / 64;

  const bf16_t* ksrc = kb + (size_t)bh * NP * HD;
  const bf16_t* vsrc = vT + (size_t)bh * HD * NP;

  auto stage_kv = [&](int c, int kt) {
    int n0k = kt * 64;
#pragma unroll
    for (int it = 0; it < 2; ++it) {
      int cb = it * 256 + w * 64, cc = cb + lane;
      int row = cc >> 3, sg = (cc & 7) ^ ((cc >> 3) & 7);
      gl_lds16(ksrc + ((size_t)(n0k + row)) * HD + sg * 8, ks[c] + cb * 8);
      gl_lds16(vsrc + (size_t)row * NP + n0k + sg * 8, vs[c] + cb * 8);
    }
  };

  // prologue: q + tile0 staged together, one drain
  const bf16_t* qsrc = qb + ((size_t)bh * NP + q0) * HD;
#pragma unroll
  for (int it = 0; it < 2; ++it) {
    int cb = it * 256 + w * 64, c = cb + lane;
    int row = c >> 3, sg = (c & 7) ^ ((c >> 3) & 7);
    gl_lds16(qsrc + row * 64 + sg * 8, qs + cb * 8);
  }
  stage_kv(0, 0);
  __syncthreads();

  bf16x8 aq[2];
  aq[0] = *(const bf16x8*)(qs + (w * 16 + l16) * 64 + ((0 * 4 + lq) ^ swr) * 8);
  aq[1] = *(const bf16x8*)(qs + (w * 16 + l16) * 64 + ((1 * 4 + lq) ^ swr) * 8);

  float lsum[4] = {0.f, 0.f, 0.f, 0.f};
  f32x4 oacc[4] = {};
  const int qrow_base = q0 + w * 16 + lq * 4;

  const bf16_t* bp[4];
#pragma unroll
  for (int r = 0; r < 4; ++r) {
    int qg = qrow_base + r;
    int qc = qg < N_ ? qg : (N_ - 1);
    bp[r] = biasb + (size_t)h * N_ * N_ + (size_t)qc * N_;
  }

  for (int kt = 0; kt < NKT; ++kt) {
    const int c = kt & 1;
    if (kt > 0) __syncthreads();            // stage(c) landed; buf c^1 reads retired
    if (kt + 1 < NKT) stage_kv(c ^ 1, kt + 1);  // hidden under this whole iteration

    f32x4 sf[4];
#pragma unroll
    for (int f = 0; f < 4; ++f) {
      f32x4 z = {};
#pragma unroll
      for (int kk = 0; kk < 2; ++kk) {
        bf16x8 bk = *(const bf16x8*)(ks[c] + (f * 16 + l16) * 64 + ((kk * 4 + lq) ^ swr) * 8);
        z = mfma16(aq[kk], bk, z);
      }
      sf[f] = z;
    }

    int n0k = kt * 64;
    bf16_t* psw = ps[w];
    if (kt < NKT - 1) {                     // all columns valid
#pragma unroll
      for (int f = 0; f < 4; ++f) {
        int kc = n0k + f * 16 + l16;
#pragma unroll
        for (int r = 0; r < 4; ++r) {
          float p = __expf(sf[f][r] + (float)bp[r][kc]);
          lsum[r] += p;
          psw[(lq * 4 + r) * 72 + f * 16 + l16] = (bf16_t)p;
        }
      }
    } else {                                // last tile: mask cols >= 616
#pragma unroll
      for (int f = 0; f < 4; ++f) {
        int kc = n0k + f * 16 + l16;
        bool ok = kc < N_;
        int kcs = ok ? kc : 0;
#pragma unroll
        for (int r = 0; r < 4; ++r) {
          float p = ok ? __expf(sf[f][r] + (float)bp[r][kcs]) : 0.f;
          lsum[r] += p;
          psw[(lq * 4 + r) * 72 + f * 16 + l16] = (bf16_t)p;
        }
      }
    }
    // no barrier: ps[w] is per-wave; compiler orders ds_write -> ds_read

#pragma unroll
    for (int kk = 0; kk < 2; ++kk) {
      bf16x8 pa = *(const bf16x8*)(psw + l16 * 72 + kk * 32 + lq * 8);
#pragma unroll
      for (int df = 0; df < 4; ++df) {
        bf16x8 bv = *(const bf16x8*)(vs[c] + (df * 16 + l16) * 64 + ((kk * 4 + lq) ^ swr) * 8);
        oacc[df] = mfma16(pa, bv, oacc[df]);
      }
    }
  }

  // one cross-lane sum reduce (16-lane groups), then normalize + write
#pragma unroll
  for (int off = 1; off < 16; off <<= 1)
#pragma unroll
    for (int r = 0; r < 4; ++r)
      lsum[r] += __shfl_xor(lsum[r], off, 16);

#pragma unroll
  for (int r = 0; r < 4; ++r) {
    int qg = qrow_base + r;
    if (qg < N_) {
      float rl = 1.f / lsum[r];
      size_t orow = ((size_t)(b_ * N_ + qg)) * C_ + h * HD;
#pragma unroll
      for (int df = 0; df < 4; ++df)
        o_mat[orow + df * 16 + l16] = (bf16_t)(oacc[df][r] * rl);
    }
  }
}

// ---------------------------------------------------------------- launch
extern "C" void kernel_launch(void* const* d_in, const int* in_sizes, int n_in,
                              void* d_out, int out_size, void* d_ws, size_t ws_size,
                              hipStream_t stream) {
  const float* x      = (const float*)d_in[0];
  const float* rel    = (const float*)d_in[1];
  const float* ln1_g  = (const float*)d_in[2];
  const float* ln1_b  = (const float*)d_in[3];
  const float* w_qkv  = (const float*)d_in[4];
  const float* q_bias = (const float*)d_in[5];
  const float* v_bias = (const float*)d_in[6];
  const float* w_proj = (const float*)d_in[7];
  const float* b_proj = (const float*)d_in[8];
  const float* gamma1 = (const float*)d_in[9];
  const float* gamma2 = (const float*)d_in[10];
  const float* ln2t_g = (const float*)d_in[11];
  const float* ln2t_b = (const float*)d_in[12];
  const float* ln2i_g = (const float*)d_in[13];
  const float* ln2i_b = (const float*)d_in[14];
  const float* wt1    = (const float*)d_in[15];
  const float* bt1    = (const float*)d_in[16];
  const float* wt2    = (const float*)d_in[17];
  const float* bt2    = (const float*)d_in[18];
  const float* wi1    = (const float*)d_in[19];
  const float* bi1    = (const float*)d_in[20];
  const float* wi2    = (const float*)d_in[21];
  const float* bi2    = (const float*)d_in[22];
  float* out = (float*)d_out;

  char* ws = (char*)d_ws;
  bf16_t* wqkvb  = (bf16_t*)(ws + 0);
  bf16_t* wprojb = (bf16_t*)(ws + 3538944);
  bf16_t* wt1b   = (bf16_t*)(ws + 4718592);
  bf16_t* wi1b   = (bf16_t*)(ws + 9437184);
  bf16_t* wt2b   = (bf16_t*)(ws + 14155776);
  bf16_t* wi2b   = (bf16_t*)(ws + 18874368);
  bf16_t* n1     = (bf16_t*)(ws + 23592960);    // 9984x768 bf16; also n2p, o_mat
  float*  x1     = (float*) (ws + 38928384);    // 30.3MB; head doubles as vtmp
  bf16_t* qbuf   = (bf16_t*)(ws + 69206016);
  bf16_t* kbuf   = (bf16_t*)(ws + 84934656);
  bf16_t* vTbuf  = (bf16_t*)(ws + 100663296);
  bf16_t* biasb  = (bf16_t*)(ws + 116391936);   // 9.1 MB; dead before mlp1 reuses region
  bf16_t* vtmp   = (bf16_t*)(ws + 38928384);
  bf16_t* o_mat  = n1;
  bf16_t* n2p    = n1;
  bf16_t* hbuf   = qbuf;

  // one fused cast launch (weights + shifted bias)
  {
    CastArgs a;
    a.src[0] = w_qkv;  a.dst[0] = wqkvb;  a.n4[0] = (3 * C_ * C_) / 4;
    a.src[1] = w_proj; a.dst[1] = wprojb; a.n4[1] = (C_ * C_) / 4;
    a.src[2] = wt1;    a.dst[2] = wt1b;   a.n4[2] = (HID * C_) / 4;
    a.src[3] = wi1;    a.dst[3] = wi1b;   a.n4[3] = (HID * C_) / 4;
    a.src[4] = wt2;    a.dst[4] = wt2b;   a.n4[4] = (C_ * HID) / 4;
    a.src[5] = wi2;    a.dst[5] = wi2b;   a.n4[5] = (C_ * HID) / 4;
    a.src[6] = rel;    a.dst[6] = biasb;  a.n4[6] = (H_ * N_ * N_) / 4;
    int total4 = a.n4[0] + a.n4[1] + a.n4[2] + a.n4[3] + a.n4[4] + a.n4[5] + a.n4[6];
    cast_all<<<2048, 256, 0, stream>>>(a, total4);
  }
  ln_rows<<<M_REAL, 256, 0, stream>>>(x, ln1_g, ln1_b, n1);

  // QKV GEMM: 77 x 18 blocks
  {
    EpiP P{}; P.bias = q_bias; P.bias2 = v_bias;
    P.ob0 = qbuf; P.ob1 = kbuf; P.ob2 = vtmp;
    gemm128<0><<<77 * 18, 256, 0, stream>>>(n1, wqkvb, wqkvb, C_, 77, 18, 0, P);
  }
  transpose_v<<<dim3(NP / 64, B_ * H_), 256, 0, stream>>>(vtmp, vTbuf);
  attn_fwd<<<1920, 256, 0, stream>>>(qbuf, kbuf, vTbuf, biasb, o_mat);

  // proj + residual -> x1 : 77 x 6 blocks
  {
    EpiP P{}; P.bias = b_proj; P.bias_i = b_proj; P.gamma = gamma1; P.xres = x; P.outf = x1;
    gemm128<1><<<77 * 6, 256, 0, stream>>>(o_mat, wprojb, wprojb, C_, 77, 6, 0, P);
  }
  ln2_pack<<<M_PAD, 256, 0, stream>>>(x1, ln2t_g, ln2t_b, ln2i_g, ln2i_b, n2p);

  // MLP fc1 + gelu: 78 x 24 blocks (text m-blocks 0-5)
  {
    EpiP P{}; P.bias = bt1; P.bias_i = bi1; P.ob0 = hbuf;
    gemm128<2><<<78 * 24, 256, 0, stream>>>(n2p, wt1b, wi1b, C_, 78, 24, 6, P);
  }
  // MLP fc2 + gamma2 residual -> d_out: 78 x 6 blocks
  {
    EpiP P{}; P.bias = bt2; P.bias_i = bi2; P.gamma = gamma2; P.xres = x1; P.outf = out;
    gemm128<3><<<78 * 6, 256, 0, stream>>>(hbuf, wt2b, wi2b, HID, 78, 6, 6, P);
  }
}

// Round 11
// 316.922 us; speedup vs baseline: 1.9845x; 1.1050x over previous
//
#include <hip/hip_runtime.h>
#include <hip/hip_bf16.h>
#include <stdint.h>
#include <math.h>

#define AS1 __attribute__((address_space(1)))
#define AS3 __attribute__((address_space(3)))

typedef __bf16 bf16_t;
typedef __bf16 bf16x8 __attribute__((ext_vector_type(8)));
typedef float f32x4 __attribute__((ext_vector_type(4)));

static constexpr int B_ = 16, N_ = 616, C_ = 768, H_ = 12, HD = 64, HID = 3072;
static constexpr int NP = 640;           // padded seq len for q/k/vT
static constexpr int M_REAL = B_ * N_;   // 9856 = 77*128
static constexpr int M_PAD = 9984;       // 78*128 (packed MLP rows)
static constexpr int NT_ = 40, NI_ = 576;

__device__ __forceinline__ void gl_lds16(const void* g, void* l) {
  __builtin_amdgcn_global_load_lds((const AS1 void*)(uintptr_t)g,
                                   (AS3 void*)(uint32_t)(uintptr_t)l, 16, 0, 0);
}
__device__ __forceinline__ f32x4 mfma16(bf16x8 a, bf16x8 b, f32x4 c) {
  return __builtin_amdgcn_mfma_f32_16x16x32_bf16(a, b, c, 0, 0, 0);
}
__device__ __forceinline__ float gelu_f(float x) {
  float u = x * (0.7978845608f + 0.0356774081f * x * x);
  return x / (1.f + __expf(-2.f * u));
}

// ---------------------------------------------------------------- fused casts
struct CastArgs {
  const float* src[7];
  bf16_t* dst[7];
  int n4[7];        // quads per segment
};

__global__ __launch_bounds__(256) void cast_all(CastArgs a, int total4) {
  int i = blockIdx.x * blockDim.x + threadIdx.x;
  int st = gridDim.x * blockDim.x;
  for (; i < total4; i += st) {
    int off = i;
#pragma unroll
    for (int s = 0; s < 7; ++s) {
      if (off < a.n4[s]) {
        float4 v = ((const float4*)a.src[s])[off];
        float sub = (s == 6) ? 8.f : 0.f;
        bf16_t* d = a.dst[s] + (size_t)off * 4;
        d[0] = (bf16_t)(v.x - sub); d[1] = (bf16_t)(v.y - sub);
        d[2] = (bf16_t)(v.z - sub); d[3] = (bf16_t)(v.w - sub);
        break;
      }
      off -= a.n4[s];
    }
  }
}

// ---------------------------------------------------------------- layernorms
__global__ __launch_bounds__(256) void ln_rows(const float* __restrict__ x,
                                               const float* __restrict__ g,
                                               const float* __restrict__ b,
                                               bf16_t* __restrict__ out) {
  int r = blockIdx.x, t = threadIdx.x;
  bf16_t* orow = out + (size_t)r * C_;
  const float* xr = x + (size_t)r * C_;
  float v0 = xr[t], v1 = xr[t + 256], v2 = xr[t + 512];
  float s = v0 + v1 + v2, ss = v0 * v0 + v1 * v1 + v2 * v2;
#pragma unroll
  for (int off = 32; off > 0; off >>= 1) { s += __shfl_xor(s, off); ss += __shfl_xor(ss, off); }
  __shared__ float sm[8];
  int w = t >> 6;
  if ((t & 63) == 0) { sm[w] = s; sm[4 + w] = ss; }
  __syncthreads();
  s = sm[0] + sm[1] + sm[2] + sm[3];
  ss = sm[4] + sm[5] + sm[6] + sm[7];
  float mean = s * (1.f / C_);
  float var = ss * (1.f / C_) - mean * mean;
  float ri = rsqrtf(var + 1e-5f);
  orow[t]       = (bf16_t)((v0 - mean) * ri * g[t]       + b[t]);
  orow[t + 256] = (bf16_t)((v1 - mean) * ri * g[t + 256] + b[t + 256]);
  orow[t + 512] = (bf16_t)((v2 - mean) * ri * g[t + 512] + b[t + 512]);
}

// LN2 + pack: packed rows [0,640)=text, [640,768)=zero pad, [768,9984)=image
__global__ __launch_bounds__(256) void ln2_pack(const float* __restrict__ x1,
                                                const float* __restrict__ gt, const float* __restrict__ bt,
                                                const float* __restrict__ gi, const float* __restrict__ bi,
                                                bf16_t* __restrict__ out) {
  int m = blockIdx.x, t = threadIdx.x;
  if (m >= M_REAL) {
    bf16_t* orow = out + (size_t)(640 + (m - M_REAL)) * C_;
    orow[t] = (bf16_t)0.f; orow[t+256] = (bf16_t)0.f; orow[t+512] = (bf16_t)0.f;
    return;
  }
  int b_ = m / N_, nn = m - b_ * N_;
  const float* g; const float* bb; int dest;
  if (nn < NT_) { dest = b_ * NT_ + nn; g = gt; bb = bt; }
  else          { dest = 768 + b_ * NI_ + (nn - NT_); g = gi; bb = bi; }
  const float* xr = x1 + (size_t)m * C_;
  float v0 = xr[t], v1 = xr[t + 256], v2 = xr[t + 512];
  float s = v0 + v1 + v2, ss = v0 * v0 + v1 * v1 + v2 * v2;
#pragma unroll
  for (int off = 32; off > 0; off >>= 1) { s += __shfl_xor(s, off); ss += __shfl_xor(ss, off); }
  __shared__ float sm[8];
  int w = t >> 6;
  if ((t & 63) == 0) { sm[w] = s; sm[4 + w] = ss; }
  __syncthreads();
  s = sm[0] + sm[1] + sm[2] + sm[3];
  ss = sm[4] + sm[5] + sm[6] + sm[7];
  float mean = s * (1.f / C_);
  float var = ss * (1.f / C_) - mean * mean;
  float ri = rsqrtf(var + 1e-5f);
  bf16_t* orow = out + (size_t)dest * C_;
  orow[t]       = (bf16_t)((v0 - mean) * ri * g[t]       + bb[t]);
  orow[t + 256] = (bf16_t)((v1 - mean) * ri * g[t + 256] + bb[t + 256]);
  orow[t + 512] = (bf16_t)((v2 - mean) * ri * g[t + 512] + bb[t + 512]);
}

// ---------------------------------------------------------------- v transpose
__global__ __launch_bounds__(256) void transpose_v(const bf16_t* __restrict__ v,
                                                   bf16_t* __restrict__ vT) {
  __shared__ bf16_t t[64][80];
  int n0 = blockIdx.x * 64, bh = blockIdx.y;
  int tid = threadIdx.x;
  int r0 = tid >> 2, c0 = (tid & 3) * 16;
  int n = n0 + r0;
#pragma unroll
  for (int cc = 0; cc < 2; ++cc) {
    bf16x8 vv;
    if (n < N_) vv = *(const bf16x8*)(v + ((size_t)bh * N_ + n) * HD + c0 + cc * 8);
    else {
#pragma unroll
      for (int e = 0; e < 8; ++e) vv[e] = (bf16_t)0.f;
    }
#pragma unroll
    for (int e = 0; e < 8; ++e) t[c0 + cc * 8 + e][r0] = vv[e];
  }
  __syncthreads();
  int d = tid >> 2, nc = (tid & 3) * 16;
  bf16_t* dst = vT + ((size_t)(bh * HD + d)) * NP + n0 + nc;
  *(bf16x8*)dst       = *(const bf16x8*)&t[d][nc];
  *(bf16x8*)(dst + 8) = *(const bf16x8*)&t[d][nc + 8];
}

// ---------------------------------------------------------------- GEMM 128x128, m97 structure (validated r7)
// r11: wg decode flipped to n-fast/m-outer — each m-block's A-panel (786 KB)
// is read from HBM once and reused across all n-blocks via the XCD's L2;
// B (weights, 1.2-4.7 MB) cycles L2-resident. Was m-fast: A re-streamed
// per n-column (mlp2: 202 MB FETCH observed vs ~100 ideal).
struct EpiP {
  const float* bias;
  const float* bias_i;
  const float* bias2;
  const float* gamma;
  const float* xres;
  float* outf;
  bf16_t* ob0;
  bf16_t* ob1;
  bf16_t* ob2;
};

template <int EPI>
__global__ __launch_bounds__(256, 3) void gemm128(const bf16_t* __restrict__ A,
                                                  const bf16_t* __restrict__ Bt,
                                                  const bf16_t* __restrict__ Bi,
                                                  int K, int MBc, int nb, int tb, EpiP P) {
  __shared__ bf16_t As[8192], Bs[8192];   // 16 KB + 16 KB, single-buffered
  const int tid = threadIdx.x, lane = tid & 63, w = tid >> 6;
  const int l16 = lane & 15, lq = lane >> 4;
  const int wr = w >> 1, wc = w & 1;
  const int NTk = K >> 6;

  int mblk, nblk;
  {
    int nwg = MBc * nb;
    int bid = blockIdx.x;
    int q8 = nwg >> 3, r8 = nwg & 7;
    int xcd = bid & 7, sidx = bid >> 3;
    int wg = (xcd < r8 ? xcd * (q8 + 1) : r8 * (q8 + 1) + (xcd - r8) * q8) + sidx;
    mblk = wg / nb; nblk = wg - mblk * nb;   // n-fast: A-panel L2 reuse
  }
  const int m0 = mblk * 128, n0 = nblk * 128;
  const bf16_t* Bw = (mblk < tb) ? Bt : Bi;

  f32x4 acc[4][4] = {};

  const int swsrc = ((lane & 7) ^ ((lane >> 3) & 7)) * 8;   // elems
  size_t aoff[4], boff[4];
  int ldsoff[4];
#pragma unroll
  for (int j = 0; j < 4; ++j) {
    int srow = j * 32 + w * 8 + (lane >> 3);
    aoff[j] = (size_t)(m0 + srow) * K + swsrc;
    boff[j] = (size_t)(n0 + srow) * K + swsrc;
    ldsoff[j] = (j * 256 + w * 64) * 8;     // wave-uniform elem offset
  }
  const int sw0 = ((0 * 4 + lq) ^ (l16 & 7)) * 8;
  const int sw1 = ((1 * 4 + lq) ^ (l16 & 7)) * 8;
  const int rbA = (wr * 64 + l16) * 64;
  const int rbB = (wc * 64 + l16) * 64;

  for (int t = 0; t < NTk; ++t) {
    const size_t kadd = (size_t)t * 64;
#pragma unroll
    for (int j = 0; j < 4; ++j) gl_lds16(A + aoff[j] + kadd, As + ldsoff[j]);
#pragma unroll
    for (int j = 0; j < 4; ++j) gl_lds16(Bw + boff[j] + kadd, Bs + ldsoff[j]);
    __syncthreads();

    bf16x8 av[4][2], bv[4][2];
#pragma unroll
    for (int i = 0; i < 4; ++i) {
      av[i][0] = *(const bf16x8*)(As + rbA + i * 1024 + sw0);
      av[i][1] = *(const bf16x8*)(As + rbA + i * 1024 + sw1);
      bv[i][0] = *(const bf16x8*)(Bs + rbB + i * 1024 + sw0);
      bv[i][1] = *(const bf16x8*)(Bs + rbB + i * 1024 + sw1);
    }
#pragma unroll
    for (int kk = 0; kk < 2; ++kk)
#pragma unroll
      for (int i = 0; i < 4; ++i)
#pragma unroll
        for (int j = 0; j < 4; ++j)
          acc[i][j] = mfma16(av[i][kk], bv[j][kk], acc[i][j]);
    __syncthreads();
  }

  const float* bsel = (mblk < tb) ? P.bias : P.bias_i;
  (void)bsel;
  int which = n0 / C_;
#pragma unroll
  for (int i = 0; i < 4; ++i) {
    int mb = m0 + wr * 64 + i * 16 + lq * 4;
#pragma unroll
    for (int j = 0; j < 4; ++j) {
      int jc = n0 + wc * 64 + j * 16 + l16;
#pragma unroll
      for (int rr = 0; rr < 4; ++rr) {
        int m = mb + rr;
        float v = acc[i][j][rr];
        if constexpr (EPI == 0) {
          int b_ = m / N_, nn = m - b_ * N_;
          int jj = jc - which * C_;
          int hh = jj >> 6, d = jj & 63;
          int bh = b_ * H_ + hh;
          if (which == 0) {
            P.ob0[((size_t)bh * NP + nn) * HD + d] = (bf16_t)((v + P.bias[jj]) * 0.125f);
          } else if (which == 1) {
            P.ob1[((size_t)bh * NP + nn) * HD + d] = (bf16_t)v;
          } else {
            P.ob2[((size_t)bh * N_ + nn) * HD + d] = (bf16_t)(v + P.bias2[jj]);
          }
        } else if constexpr (EPI == 1) {
          size_t idx = (size_t)m * C_ + jc;
          P.outf[idx] = P.xres[idx] + P.gamma[jc] * (v + P.bias[jc]);
        } else if constexpr (EPI == 2) {
          P.ob0[(size_t)m * HID + jc] = (bf16_t)gelu_f(v + bsel[jc]);
        } else {
          int orig = -1;
          if (m < 640)      orig = (m / NT_) * N_ + (m - (m / NT_) * NT_);
          else if (m >= 768) {
            int mi = m - 768;
            int bb = mi / NI_;
            orig = bb * N_ + NT_ + (mi - bb * NI_);
          }
          if (orig >= 0) {
            size_t idx = (size_t)orig * C_ + jc;
            P.outf[idx] = P.xres[idx] + P.gamma[jc] * (v + bsel[jc]);
          }
        }
      }
    }
  }
}

// ---------------------------------------------------------------- attention (validated r10)
__global__ __launch_bounds__(256) void attn_fwd(const bf16_t* __restrict__ qb,
                                                const bf16_t* __restrict__ kb,
                                                const bf16_t* __restrict__ vT,
                                                const bf16_t* __restrict__ biasb,
                                                bf16_t* __restrict__ o_mat) {
  __shared__ bf16_t qs[64 * 64];
  __shared__ bf16_t ks[2][64 * 64], vs[2][64 * 64];
  __shared__ bf16_t ps[4][16 * 72];
  const int tid = threadIdx.x, lane = tid & 63, w = tid >> 6;
  const int l16 = lane & 15, lq = lane >> 4;
  int wg = (blockIdx.x & 7) * 240 + (blockIdx.x >> 3);
  const int qt = wg % 10;
  const int rb = wg / 10;
  const int b_ = rb & 15, h = rb >> 4;
  const int bh = b_ * H_ + h;
  const int q0 = qt * 64;
  const int swr = (l16 & 7);
  constexpr int NKT = NP / 64;

  const bf16_t* ksrc = kb + (size_t)bh * NP * HD;
  const bf16_t* vsrc = vT + (size_t)bh * HD * NP;

  auto stage_kv = [&](int c, int kt) {
    int n0k = kt * 64;
#pragma unroll
    for (int it = 0; it < 2; ++it) {
      int cb = it * 256 + w * 64, cc = cb + lane;
      int row = cc >> 3, sg = (cc & 7) ^ ((cc >> 3) & 7);
      gl_lds16(ksrc + ((size_t)(n0k + row)) * HD + sg * 8, ks[c] + cb * 8);
      gl_lds16(vsrc + (size_t)row * NP + n0k + sg * 8, vs[c] + cb * 8);
    }
  };

  const bf16_t* qsrc = qb + ((size_t)bh * NP + q0) * HD;
#pragma unroll
  for (int it = 0; it < 2; ++it) {
    int cb = it * 256 + w * 64, c = cb + lane;
    int row = c >> 3, sg = (c & 7) ^ ((c >> 3) & 7);
    gl_lds16(qsrc + row * 64 + sg * 8, qs + cb * 8);
  }
  stage_kv(0, 0);
  __syncthreads();

  bf16x8 aq[2];
  aq[0] = *(const bf16x8*)(qs + (w * 16 + l16) * 64 + ((0 * 4 + lq) ^ swr) * 8);
  aq[1] = *(const bf16x8*)(qs + (w * 16 + l16) * 64 + ((1 * 4 + lq) ^ swr) * 8);

  float lsum[4] = {0.f, 0.f, 0.f, 0.f};
  f32x4 oacc[4] = {};
  const int qrow_base = q0 + w * 16 + lq * 4;

  const bf16_t* bp[4];
#pragma unroll
  for (int r = 0; r < 4; ++r) {
    int qg = qrow_base + r;
    int qc = qg < N_ ? qg : (N_ - 1);
    bp[r] = biasb + (size_t)h * N_ * N_ + (size_t)qc * N_;
  }

  for (int kt = 0; kt < NKT; ++kt) {
    const int c = kt & 1;
    if (kt > 0) __syncthreads();
    if (kt + 1 < NKT) stage_kv(c ^ 1, kt + 1);

    f32x4 sf[4];
#pragma unroll
    for (int f = 0; f < 4; ++f) {
      f32x4 z = {};
#pragma unroll
      for (int kk = 0; kk < 2; ++kk) {
        bf16x8 bk = *(const bf16x8*)(ks[c] + (f * 16 + l16) * 64 + ((kk * 4 + lq) ^ swr) * 8);
        z = mfma16(aq[kk], bk, z);
      }
      sf[f] = z;
    }

    int n0k = kt * 64;
    bf16_t* psw = ps[w];
    if (kt < NKT - 1) {
#pragma unroll
      for (int f = 0; f < 4; ++f) {
        int kc = n0k + f * 16 + l16;
#pragma unroll
        for (int r = 0; r < 4; ++r) {
          float p = __expf(sf[f][r] + (float)bp[r][kc]);
          lsum[r] += p;
          psw[(lq * 4 + r) * 72 + f * 16 + l16] = (bf16_t)p;
        }
      }
    } else {
#pragma unroll
      for (int f = 0; f < 4; ++f) {
        int kc = n0k + f * 16 + l16;
        bool ok = kc < N_;
        int kcs = ok ? kc : 0;
#pragma unroll
        for (int r = 0; r < 4; ++r) {
          float p = ok ? __expf(sf[f][r] + (float)bp[r][kcs]) : 0.f;
          lsum[r] += p;
          psw[(lq * 4 + r) * 72 + f * 16 + l16] = (bf16_t)p;
        }
      }
    }

#pragma unroll
    for (int kk = 0; kk < 2; ++kk) {
      bf16x8 pa = *(const bf16x8*)(psw + l16 * 72 + kk * 32 + lq * 8);
#pragma unroll
      for (int df = 0; df < 4; ++df) {
        bf16x8 bv = *(const bf16x8*)(vs[c] + (df * 16 + l16) * 64 + ((kk * 4 + lq) ^ swr) * 8);
        oacc[df] = mfma16(pa, bv, oacc[df]);
      }
    }
  }

#pragma unroll
  for (int off = 1; off < 16; off <<= 1)
#pragma unroll
    for (int r = 0; r < 4; ++r)
      lsum[r] += __shfl_xor(lsum[r], off, 16);

#pragma unroll
  for (int r = 0; r < 4; ++r) {
    int qg = qrow_base + r;
    if (qg < N_) {
      float rl = 1.f / lsum[r];
      size_t orow = ((size_t)(b_ * N_ + qg)) * C_ + h * HD;
#pragma unroll
      for (int df = 0; df < 4; ++df)
        o_mat[orow + df * 16 + l16] = (bf16_t)(oacc[df][r] * rl);
    }
  }
}

// ---------------------------------------------------------------- launch
extern "C" void kernel_launch(void* const* d_in, const int* in_sizes, int n_in,
                              void* d_out, int out_size, void* d_ws, size_t ws_size,
                              hipStream_t stream) {
  const float* x      = (const float*)d_in[0];
  const float* rel    = (const float*)d_in[1];
  const float* ln1_g  = (const float*)d_in[2];
  const float* ln1_b  = (const float*)d_in[3];
  const float* w_qkv  = (const float*)d_in[4];
  const float* q_bias = (const float*)d_in[5];
  const float* v_bias = (const float*)d_in[6];
  const float* w_proj = (const float*)d_in[7];
  const float* b_proj = (const float*)d_in[8];
  const float* gamma1 = (const float*)d_in[9];
  const float* gamma2 = (const float*)d_in[10];
  const float* ln2t_g = (const float*)d_in[11];
  const float* ln2t_b = (const float*)d_in[12];
  const float* ln2i_g = (const float*)d_in[13];
  const float* ln2i_b = (const float*)d_in[14];
  const float* wt1    = (const float*)d_in[15];
  const float* bt1    = (const float*)d_in[16];
  const float* wt2    = (const float*)d_in[17];
  const float* bt2    = (const float*)d_in[18];
  const float* wi1    = (const float*)d_in[19];
  const float* bi1    = (const float*)d_in[20];
  const float* wi2    = (const float*)d_in[21];
  const float* bi2    = (const float*)d_in[22];
  float* out = (float*)d_out;

  char* ws = (char*)d_ws;
  bf16_t* wqkvb  = (bf16_t*)(ws + 0);
  bf16_t* wprojb = (bf16_t*)(ws + 3538944);
  bf16_t* wt1b   = (bf16_t*)(ws + 4718592);
  bf16_t* wi1b   = (bf16_t*)(ws + 9437184);
  bf16_t* wt2b   = (bf16_t*)(ws + 14155776);
  bf16_t* wi2b   = (bf16_t*)(ws + 18874368);
  bf16_t* n1     = (bf16_t*)(ws + 23592960);    // 9984x768 bf16; also n2p, o_mat
  float*  x1     = (float*) (ws + 38928384);    // 30.3MB; head doubles as vtmp
  bf16_t* qbuf   = (bf16_t*)(ws + 69206016);
  bf16_t* kbuf   = (bf16_t*)(ws + 84934656);
  bf16_t* vTbuf  = (bf16_t*)(ws + 100663296);
  bf16_t* biasb  = (bf16_t*)(ws + 116391936);   // 9.1 MB; dead before mlp1 reuses region
  bf16_t* vtmp   = (bf16_t*)(ws + 38928384);
  bf16_t* o_mat  = n1;
  bf16_t* n2p    = n1;
  bf16_t* hbuf   = qbuf;

  // one fused cast launch (weights + shifted bias)
  {
    CastArgs a;
    a.src[0] = w_qkv;  a.dst[0] = wqkvb;  a.n4[0] = (3 * C_ * C_) / 4;
    a.src[1] = w_proj; a.dst[1] = wprojb; a.n4[1] = (C_ * C_) / 4;
    a.src[2] = wt1;    a.dst[2] = wt1b;   a.n4[2] = (HID * C_) / 4;
    a.src[3] = wi1;    a.dst[3] = wi1b;   a.n4[3] = (HID * C_) / 4;
    a.src[4] = wt2;    a.dst[4] = wt2b;   a.n4[4] = (C_ * HID) / 4;
    a.src[5] = wi2;    a.dst[5] = wi2b;   a.n4[5] = (C_ * HID) / 4;
    a.src[6] = rel;    a.dst[6] = biasb;  a.n4[6] = (H_ * N_ * N_) / 4;
    int total4 = a.n4[0] + a.n4[1] + a.n4[2] + a.n4[3] + a.n4[4] + a.n4[5] + a.n4[6];
    cast_all<<<2048, 256, 0, stream>>>(a, total4);
  }
  ln_rows<<<M_REAL, 256, 0, stream>>>(x, ln1_g, ln1_b, n1);

  // QKV GEMM: 77 x 18 blocks
  {
    EpiP P{}; P.bias = q_bias; P.bias2 = v_bias;
    P.ob0 = qbuf; P.ob1 = kbuf; P.ob2 = vtmp;
    gemm128<0><<<77 * 18, 256, 0, stream>>>(n1, wqkvb, wqkvb, C_, 77, 18, 0, P);
  }
  transpose_v<<<dim3(NP / 64, B_ * H_), 256, 0, stream>>>(vtmp, vTbuf);
  attn_fwd<<<1920, 256, 0, stream>>>(qbuf, kbuf, vTbuf, biasb, o_mat);

  // proj + residual -> x1 : 77 x 6 blocks
  {
    EpiP P{}; P.bias = b_proj; P.bias_i = b_proj; P.gamma = gamma1; P.xres = x; P.outf = x1;
    gemm128<1><<<77 * 6, 256, 0, stream>>>(o_mat, wprojb, wprojb, C_, 77, 6, 0, P);
  }
  ln2_pack<<<M_PAD, 256, 0, stream>>>(x1, ln2t_g, ln2t_b, ln2i_g, ln2i_b, n2p);

  // MLP fc1 + gelu: 78 x 24 blocks (text m-blocks 0-5)
  {
    EpiP P{}; P.bias = bt1; P.bias_i = bi1; P.ob0 = hbuf;
    gemm128<2><<<78 * 24, 256, 0, stream>>>(n2p, wt1b, wi1b, C_, 78, 24, 6, P);
  }
  // MLP fc2 + gamma2 residual -> d_out: 78 x 6 blocks
  {
    EpiP P{}; P.bias = bt2; P.bias_i = bi2; P.gamma = gamma2; P.xres = x1; P.outf = out;
    gemm128<3><<<78 * 6, 256, 0, stream>>>(hbuf, wt2b, wi2b, HID, 78, 6, 6, P);
  }
}

// Round 12
// 303.823 us; speedup vs baseline: 2.0700x; 1.0431x over previous
//
#include <hip/hip_runtime.h>
#include <hip/hip_bf16.h>
#include <stdint.h>
#include <math.h>

#define AS1 __attribute__((address_space(1)))
#define AS3 __attribute__((address_space(3)))

typedef __bf16 bf16_t;
typedef __bf16 bf16x8 __attribute__((ext_vector_type(8)));
typedef float f32x4 __attribute__((ext_vector_type(4)));

static constexpr int B_ = 16, N_ = 616, C_ = 768, H_ = 12, HD = 64, HID = 3072;
static constexpr int NP = 640;           // padded seq len for q/k/vT
static constexpr int M_REAL = B_ * N_;   // 9856 = 77*128 = 154*64
static constexpr int M_PAD = 9984;       // 78*128 = 156*64 (packed MLP rows)
static constexpr int NT_ = 40, NI_ = 576;

__device__ __forceinline__ void gl_lds16(const void* g, void* l) {
  __builtin_amdgcn_global_load_lds((const AS1 void*)(uintptr_t)g,
                                   (AS3 void*)(uint32_t)(uintptr_t)l, 16, 0, 0);
}
__device__ __forceinline__ f32x4 mfma16(bf16x8 a, bf16x8 b, f32x4 c) {
  return __builtin_amdgcn_mfma_f32_16x16x32_bf16(a, b, c, 0, 0, 0);
}
__device__ __forceinline__ float gelu_f(float x) {
  float u = x * (0.7978845608f + 0.0356774081f * x * x);
  return x / (1.f + __expf(-2.f * u));
}

// ---------------------------------------------------------------- fused casts
struct CastArgs {
  const float* src[7];
  bf16_t* dst[7];
  int n4[7];        // quads per segment
};

__global__ __launch_bounds__(256) void cast_all(CastArgs a, int total4) {
  int i = blockIdx.x * blockDim.x + threadIdx.x;
  int st = gridDim.x * blockDim.x;
  for (; i < total4; i += st) {
    int off = i;
#pragma unroll
    for (int s = 0; s < 7; ++s) {
      if (off < a.n4[s]) {
        float4 v = ((const float4*)a.src[s])[off];
        float sub = (s == 6) ? 8.f : 0.f;
        bf16_t* d = a.dst[s] + (size_t)off * 4;
        d[0] = (bf16_t)(v.x - sub); d[1] = (bf16_t)(v.y - sub);
        d[2] = (bf16_t)(v.z - sub); d[3] = (bf16_t)(v.w - sub);
        break;
      }
      off -= a.n4[s];
    }
  }
}

// ---------------------------------------------------------------- layernorms
__global__ __launch_bounds__(256) void ln_rows(const float* __restrict__ x,
                                               const float* __restrict__ g,
                                               const float* __restrict__ b,
                                               bf16_t* __restrict__ out) {
  int r = blockIdx.x, t = threadIdx.x;
  bf16_t* orow = out + (size_t)r * C_;
  const float* xr = x + (size_t)r * C_;
  float v0 = xr[t], v1 = xr[t + 256], v2 = xr[t + 512];
  float s = v0 + v1 + v2, ss = v0 * v0 + v1 * v1 + v2 * v2;
#pragma unroll
  for (int off = 32; off > 0; off >>= 1) { s += __shfl_xor(s, off); ss += __shfl_xor(ss, off); }
  __shared__ float sm[8];
  int w = t >> 6;
  if ((t & 63) == 0) { sm[w] = s; sm[4 + w] = ss; }
  __syncthreads();
  s = sm[0] + sm[1] + sm[2] + sm[3];
  ss = sm[4] + sm[5] + sm[6] + sm[7];
  float mean = s * (1.f / C_);
  float var = ss * (1.f / C_) - mean * mean;
  float ri = rsqrtf(var + 1e-5f);
  orow[t]       = (bf16_t)((v0 - mean) * ri * g[t]       + b[t]);
  orow[t + 256] = (bf16_t)((v1 - mean) * ri * g[t + 256] + b[t + 256]);
  orow[t + 512] = (bf16_t)((v2 - mean) * ri * g[t + 512] + b[t + 512]);
}

// LN2 + pack: packed rows [0,640)=text, [640,768)=zero pad, [768,9984)=image
__global__ __launch_bounds__(256) void ln2_pack(const float* __restrict__ x1,
                                                const float* __restrict__ gt, const float* __restrict__ bt,
                                                const float* __restrict__ gi, const float* __restrict__ bi,
                                                bf16_t* __restrict__ out) {
  int m = blockIdx.x, t = threadIdx.x;
  if (m >= M_REAL) {
    bf16_t* orow = out + (size_t)(640 + (m - M_REAL)) * C_;
    orow[t] = (bf16_t)0.f; orow[t+256] = (bf16_t)0.f; orow[t+512] = (bf16_t)0.f;
    return;
  }
  int b_ = m / N_, nn = m - b_ * N_;
  const float* g; const float* bb; int dest;
  if (nn < NT_) { dest = b_ * NT_ + nn; g = gt; bb = bt; }
  else          { dest = 768 + b_ * NI_ + (nn - NT_); g = gi; bb = bi; }
  const float* xr = x1 + (size_t)m * C_;
  float v0 = xr[t], v1 = xr[t + 256], v2 = xr[t + 512];
  float s = v0 + v1 + v2, ss = v0 * v0 + v1 * v1 + v2 * v2;
#pragma unroll
  for (int off = 32; off > 0; off >>= 1) { s += __shfl_xor(s, off); ss += __shfl_xor(ss, off); }
  __shared__ float sm[8];
  int w = t >> 6;
  if ((t & 63) == 0) { sm[w] = s; sm[4 + w] = ss; }
  __syncthreads();
  s = sm[0] + sm[1] + sm[2] + sm[3];
  ss = sm[4] + sm[5] + sm[6] + sm[7];
  float mean = s * (1.f / C_);
  float var = ss * (1.f / C_) - mean * mean;
  float ri = rsqrtf(var + 1e-5f);
  bf16_t* orow = out + (size_t)dest * C_;
  orow[t]       = (bf16_t)((v0 - mean) * ri * g[t]       + bb[t]);
  orow[t + 256] = (bf16_t)((v1 - mean) * ri * g[t + 256] + bb[t + 256]);
  orow[t + 512] = (bf16_t)((v2 - mean) * ri * g[t + 512] + bb[t + 512]);
}

// ---------------------------------------------------------------- v transpose
__global__ __launch_bounds__(256) void transpose_v(const bf16_t* __restrict__ v,
                                                   bf16_t* __restrict__ vT) {
  __shared__ bf16_t t[64][80];
  int n0 = blockIdx.x * 64, bh = blockIdx.y;
  int tid = threadIdx.x;
  int r0 = tid >> 2, c0 = (tid & 3) * 16;
  int n = n0 + r0;
#pragma unroll
  for (int cc = 0; cc < 2; ++cc) {
    bf16x8 vv;
    if (n < N_) vv = *(const bf16x8*)(v + ((size_t)bh * N_ + n) * HD + c0 + cc * 8);
    else {
#pragma unroll
      for (int e = 0; e < 8; ++e) vv[e] = (bf16_t)0.f;
    }
#pragma unroll
    for (int e = 0; e < 8; ++e) t[c0 + cc * 8 + e][r0] = vv[e];
  }
  __syncthreads();
  int d = tid >> 2, nc = (tid & 3) * 16;
  bf16_t* dst = vT + ((size_t)(bh * HD + d)) * NP + n0 + nc;
  *(bf16x8*)dst       = *(const bf16x8*)&t[d][nc];
  *(bf16x8*)(dst + 8) = *(const bf16x8*)&t[d][nc + 8];
}

// ---------------------------------------------------------------- shared epilogue params
struct EpiP {
  const float* bias;
  const float* bias_i;
  const float* bias2;
  const float* gamma;
  const float* xres;
  float* outf;
  bf16_t* ob0;
  bf16_t* ob1;
  bf16_t* ob2;
};

// ---------------------------------------------------------------- GEMM 128x128, m97 structure (validated r7, n-fast r11)
template <int EPI>
__global__ __launch_bounds__(256, 3) void gemm128(const bf16_t* __restrict__ A,
                                                  const bf16_t* __restrict__ Bt,
                                                  const bf16_t* __restrict__ Bi,
                                                  int K, int MBc, int nb, int tb, EpiP P) {
  __shared__ bf16_t As[8192], Bs[8192];   // 16 KB + 16 KB, single-buffered
  const int tid = threadIdx.x, lane = tid & 63, w = tid >> 6;
  const int l16 = lane & 15, lq = lane >> 4;
  const int wr = w >> 1, wc = w & 1;
  const int NTk = K >> 6;

  int mblk, nblk;
  {
    int nwg = MBc * nb;
    int bid = blockIdx.x;
    int q8 = nwg >> 3, r8 = nwg & 7;
    int xcd = bid & 7, sidx = bid >> 3;
    int wg = (xcd < r8 ? xcd * (q8 + 1) : r8 * (q8 + 1) + (xcd - r8) * q8) + sidx;
    mblk = wg / nb; nblk = wg - mblk * nb;   // n-fast: A-panel L2 reuse
  }
  const int m0 = mblk * 128, n0 = nblk * 128;
  const bf16_t* Bw = (mblk < tb) ? Bt : Bi;

  f32x4 acc[4][4] = {};

  const int swsrc = ((lane & 7) ^ ((lane >> 3) & 7)) * 8;   // elems
  size_t aoff[4], boff[4];
  int ldsoff[4];
#pragma unroll
  for (int j = 0; j < 4; ++j) {
    int srow = j * 32 + w * 8 + (lane >> 3);
    aoff[j] = (size_t)(m0 + srow) * K + swsrc;
    boff[j] = (size_t)(n0 + srow) * K + swsrc;
    ldsoff[j] = (j * 256 + w * 64) * 8;     // wave-uniform elem offset
  }
  const int sw0 = ((0 * 4 + lq) ^ (l16 & 7)) * 8;
  const int sw1 = ((1 * 4 + lq) ^ (l16 & 7)) * 8;
  const int rbA = (wr * 64 + l16) * 64;
  const int rbB = (wc * 64 + l16) * 64;

  for (int t = 0; t < NTk; ++t) {
    const size_t kadd = (size_t)t * 64;
#pragma unroll
    for (int j = 0; j < 4; ++j) gl_lds16(A + aoff[j] + kadd, As + ldsoff[j]);
#pragma unroll
    for (int j = 0; j < 4; ++j) gl_lds16(Bw + boff[j] + kadd, Bs + ldsoff[j]);
    __syncthreads();

    bf16x8 av[4][2], bv[4][2];
#pragma unroll
    for (int i = 0; i < 4; ++i) {
      av[i][0] = *(const bf16x8*)(As + rbA + i * 1024 + sw0);
      av[i][1] = *(const bf16x8*)(As + rbA + i * 1024 + sw1);
      bv[i][0] = *(const bf16x8*)(Bs + rbB + i * 1024 + sw0);
      bv[i][1] = *(const bf16x8*)(Bs + rbB + i * 1024 + sw1);
    }
#pragma unroll
    for (int kk = 0; kk < 2; ++kk)
#pragma unroll
      for (int i = 0; i < 4; ++i)
#pragma unroll
        for (int j = 0; j < 4; ++j)
          acc[i][j] = mfma16(av[i][kk], bv[j][kk], acc[i][j]);
    __syncthreads();
  }

  const float* bsel = (mblk < tb) ? P.bias : P.bias_i;
  (void)bsel;
  int which = n0 / C_;
#pragma unroll
  for (int i = 0; i < 4; ++i) {
    int mb = m0 + wr * 64 + i * 16 + lq * 4;
#pragma unroll
    for (int j = 0; j < 4; ++j) {
      int jc = n0 + wc * 64 + j * 16 + l16;
#pragma unroll
      for (int rr = 0; rr < 4; ++rr) {
        int m = mb + rr;
        float v = acc[i][j][rr];
        if constexpr (EPI == 0) {
          int b_ = m / N_, nn = m - b_ * N_;
          int jj = jc - which * C_;
          int hh = jj >> 6, d = jj & 63;
          int bh = b_ * H_ + hh;
          if (which == 0) {
            P.ob0[((size_t)bh * NP + nn) * HD + d] = (bf16_t)((v + P.bias[jj]) * 0.125f);
          } else if (which == 1) {
            P.ob1[((size_t)bh * NP + nn) * HD + d] = (bf16_t)v;
          } else {
            P.ob2[((size_t)bh * N_ + nn) * HD + d] = (bf16_t)(v + P.bias2[jj]);
          }
        } else if constexpr (EPI == 1) {
          size_t idx = (size_t)m * C_ + jc;
          P.outf[idx] = P.xres[idx] + P.gamma[jc] * (v + P.bias[jc]);
        } else if constexpr (EPI == 2) {
          P.ob0[(size_t)m * HID + jc] = (bf16_t)gelu_f(v + bsel[jc]);
        } else {
          int orig = -1;
          if (m < 640)      orig = (m / NT_) * N_ + (m - (m / NT_) * NT_);
          else if (m >= 768) {
            int mi = m - 768;
            int bb = mi / NI_;
            orig = bb * N_ + NT_ + (mi - bb * NI_);
          }
          if (orig >= 0) {
            size_t idx = (size_t)orig * C_ + jc;
            P.outf[idx] = P.xres[idx] + P.gamma[jc] * (v + bsel[jc]);
          }
        }
      }
    }
  }
}

// ---------------------------------------------------------------- GEMM 64x128 (r12)
// Same r7 swizzle/structure, BM=64: for grid-starved GEMMs (proj, mlp2).
// 4 waves, each owns 64 rows x 32-col strip (acc 4x2). 24 KB LDS ->
// 4-6 blocks/CU resident; grids ~930 -> R~3.6 restores m114 overlap.
template <int EPI>
__global__ __launch_bounds__(256, 4) void gemm64(const bf16_t* __restrict__ A,
                                                 const bf16_t* __restrict__ Bt,
                                                 const bf16_t* __restrict__ Bi,
                                                 int K, int MBc, int nb, int tb, EpiP P) {
  __shared__ bf16_t As[4096], Bs[8192];   // 8 KB + 16 KB
  const int tid = threadIdx.x, lane = tid & 63, w = tid >> 6;
  const int l16 = lane & 15, lq = lane >> 4;
  const int NTk = K >> 6;

  int mblk, nblk;
  {
    int nwg = MBc * nb;
    int bid = blockIdx.x;
    int q8 = nwg >> 3, r8 = nwg & 7;
    int xcd = bid & 7, sidx = bid >> 3;
    int wg = (xcd < r8 ? xcd * (q8 + 1) : r8 * (q8 + 1) + (xcd - r8) * q8) + sidx;
    mblk = wg / nb; nblk = wg - mblk * nb;   // n-fast
  }
  const int m0 = mblk * 64, n0 = nblk * 128;
  const bf16_t* Bw = (mblk < tb) ? Bt : Bi;

  f32x4 acc[4][2] = {};

  const int swsrc = ((lane & 7) ^ ((lane >> 3) & 7)) * 8;
  size_t aoff[2]; int aldso[2];
  size_t boff[4]; int bldso[4];
#pragma unroll
  for (int j = 0; j < 2; ++j) {
    int srow = w * 16 + j * 8 + (lane >> 3);          // A rows 0..63
    aoff[j] = (size_t)(m0 + srow) * K + swsrc;
    aldso[j] = (w * 128 + j * 64) * 8;
  }
#pragma unroll
  for (int j = 0; j < 4; ++j) {
    int srow = w * 32 + j * 8 + (lane >> 3);          // B rows (out cols) 0..127
    boff[j] = (size_t)(n0 + srow) * K + swsrc;
    bldso[j] = (w * 256 + j * 64) * 8;
  }
  const int sw0 = ((0 * 4 + lq) ^ (l16 & 7)) * 8;
  const int sw1 = ((1 * 4 + lq) ^ (l16 & 7)) * 8;
  const int rbA = l16 * 64;                 // all waves share all 64 A-rows
  const int rbB = (w * 32 + l16) * 64;      // wave col strip

  for (int t = 0; t < NTk; ++t) {
    const size_t kadd = (size_t)t * 64;
#pragma unroll
    for (int j = 0; j < 2; ++j) gl_lds16(A + aoff[j] + kadd, As + aldso[j]);
#pragma unroll
    for (int j = 0; j < 4; ++j) gl_lds16(Bw + boff[j] + kadd, Bs + bldso[j]);
    __syncthreads();

    bf16x8 av[4][2], bv[2][2];
#pragma unroll
    for (int i = 0; i < 4; ++i) {
      av[i][0] = *(const bf16x8*)(As + rbA + i * 1024 + sw0);
      av[i][1] = *(const bf16x8*)(As + rbA + i * 1024 + sw1);
    }
#pragma unroll
    for (int j = 0; j < 2; ++j) {
      bv[j][0] = *(const bf16x8*)(Bs + rbB + j * 1024 + sw0);
      bv[j][1] = *(const bf16x8*)(Bs + rbB + j * 1024 + sw1);
    }
#pragma unroll
    for (int kk = 0; kk < 2; ++kk)
#pragma unroll
      for (int i = 0; i < 4; ++i)
#pragma unroll
        for (int j = 0; j < 2; ++j)
          acc[i][j] = mfma16(av[i][kk], bv[j][kk], acc[i][j]);
    __syncthreads();
  }

  const float* bsel = (mblk < tb) ? P.bias : P.bias_i;
  (void)bsel;
#pragma unroll
  for (int i = 0; i < 4; ++i) {
    int mb = m0 + i * 16 + lq * 4;
#pragma unroll
    for (int j = 0; j < 2; ++j) {
      int jc = n0 + w * 32 + j * 16 + l16;
#pragma unroll
      for (int rr = 0; rr < 4; ++rr) {
        int m = mb + rr;
        float v = acc[i][j][rr];
        if constexpr (EPI == 1) {         // proj: x1 = x + gamma1*(o+b)
          size_t idx = (size_t)m * C_ + jc;
          P.outf[idx] = P.xres[idx] + P.gamma[jc] * (v + P.bias[jc]);
        } else {                          // mlp2: residual scatter to d_out
          int orig = -1;
          if (m < 640)      orig = (m / NT_) * N_ + (m - (m / NT_) * NT_);
          else if (m >= 768) {
            int mi = m - 768;
            int bb = mi / NI_;
            orig = bb * N_ + NT_ + (mi - bb * NI_);
          }
          if (orig >= 0) {
            size_t idx = (size_t)orig * C_ + jc;
            P.outf[idx] = P.xres[idx] + P.gamma[jc] * (v + bsel[jc]);
          }
        }
      }
    }
  }
}

// ---------------------------------------------------------------- attention (validated r10)
__global__ __launch_bounds__(256) void attn_fwd(const bf16_t* __restrict__ qb,
                                                const bf16_t* __restrict__ kb,
                                                const bf16_t* __restrict__ vT,
                                                const bf16_t* __restrict__ biasb,
                                                bf16_t* __restrict__ o_mat) {
  __shared__ bf16_t qs[64 * 64];
  __shared__ bf16_t ks[2][64 * 64], vs[2][64 * 64];
  __shared__ bf16_t ps[4][16 * 72];
  const int tid = threadIdx.x, lane = tid & 63, w = tid >> 6;
  const int l16 = lane & 15, lq = lane >> 4;
  int wg = (blockIdx.x & 7) * 240 + (blockIdx.x >> 3);
  const int qt = wg % 10;
  const int rb = wg / 10;
  const int b_ = rb & 15, h = rb >> 4;
  const int bh = b_ * H_ + h;
  const int q0 = qt * 64;
  const int swr = (l16 & 7);
  constexpr int NKT = NP / 64;

  const bf16_t* ksrc = kb + (size_t)bh * NP * HD;
  const bf16_t* vsrc = vT + (size_t)bh * HD * NP;

  auto stage_kv = [&](int c, int kt) {
    int n0k = kt * 64;
#pragma unroll
    for (int it = 0; it < 2; ++it) {
      int cb = it * 256 + w * 64, cc = cb + lane;
      int row = cc >> 3, sg = (cc & 7) ^ ((cc >> 3) & 7);
      gl_lds16(ksrc + ((size_t)(n0k + row)) * HD + sg * 8, ks[c] + cb * 8);
      gl_lds16(vsrc + (size_t)row * NP + n0k + sg * 8, vs[c] + cb * 8);
    }
  };

  const bf16_t* qsrc = qb + ((size_t)bh * NP + q0) * HD;
#pragma unroll
  for (int it = 0; it < 2; ++it) {
    int cb = it * 256 + w * 64, c = cb + lane;
    int row = c >> 3, sg = (c & 7) ^ ((c >> 3) & 7);
    gl_lds16(qsrc + row * 64 + sg * 8, qs + cb * 8);
  }
  stage_kv(0, 0);
  __syncthreads();

  bf16x8 aq[2];
  aq[0] = *(const bf16x8*)(qs + (w * 16 + l16) * 64 + ((0 * 4 + lq) ^ swr) * 8);
  aq[1] = *(const bf16x8*)(qs + (w * 16 + l16) * 64 + ((1 * 4 + lq) ^ swr) * 8);

  float lsum[4] = {0.f, 0.f, 0.f, 0.f};
  f32x4 oacc[4] = {};
  const int qrow_base = q0 + w * 16 + lq * 4;

  const bf16_t* bp[4];
#pragma unroll
  for (int r = 0; r < 4; ++r) {
    int qg = qrow_base + r;
    int qc = qg < N_ ? qg : (N_ - 1);
    bp[r] = biasb + (size_t)h * N_ * N_ + (size_t)qc * N_;
  }

  for (int kt = 0; kt < NKT; ++kt) {
    const int c = kt & 1;
    if (kt > 0) __syncthreads();
    if (kt + 1 < NKT) stage_kv(c ^ 1, kt + 1);

    f32x4 sf[4];
#pragma unroll
    for (int f = 0; f < 4; ++f) {
      f32x4 z = {};
#pragma unroll
      for (int kk = 0; kk < 2; ++kk) {
        bf16x8 bk = *(const bf16x8*)(ks[c] + (f * 16 + l16) * 64 + ((kk * 4 + lq) ^ swr) * 8);
        z = mfma16(aq[kk], bk, z);
      }
      sf[f] = z;
    }

    int n0k = kt * 64;
    bf16_t* psw = ps[w];
    if (kt < NKT - 1) {
#pragma unroll
      for (int f = 0; f < 4; ++f) {
        int kc = n0k + f * 16 + l16;
#pragma unroll
        for (int r = 0; r < 4; ++r) {
          float p = __expf(sf[f][r] + (float)bp[r][kc]);
          lsum[r] += p;
          psw[(lq * 4 + r) * 72 + f * 16 + l16] = (bf16_t)p;
        }
      }
    } else {
#pragma unroll
      for (int f = 0; f < 4; ++f) {
        int kc = n0k + f * 16 + l16;
        bool ok = kc < N_;
        int kcs = ok ? kc : 0;
#pragma unroll
        for (int r = 0; r < 4; ++r) {
          float p = ok ? __expf(sf[f][r] + (float)bp[r][kcs]) : 0.f;
          lsum[r] += p;
          psw[(lq * 4 + r) * 72 + f * 16 + l16] = (bf16_t)p;
        }
      }
    }

#pragma unroll
    for (int kk = 0; kk < 2; ++kk) {
      bf16x8 pa = *(const bf16x8*)(psw + l16 * 72 + kk * 32 + lq * 8);
#pragma unroll
      for (int df = 0; df < 4; ++df) {
        bf16x8 bv = *(const bf16x8*)(vs[c] + (df * 16 + l16) * 64 + ((kk * 4 + lq) ^ swr) * 8);
        oacc[df] = mfma16(pa, bv, oacc[df]);
      }
    }
  }

#pragma unroll
  for (int off = 1; off < 16; off <<= 1)
#pragma unroll
    for (int r = 0; r < 4; ++r)
      lsum[r] += __shfl_xor(lsum[r], off, 16);

#pragma unroll
  for (int r = 0; r < 4; ++r) {
    int qg = qrow_base + r;
    if (qg < N_) {
      float rl = 1.f / lsum[r];
      size_t orow = ((size_t)(b_ * N_ + qg)) * C_ + h * HD;
#pragma unroll
      for (int df = 0; df < 4; ++df)
        o_mat[orow + df * 16 + l16] = (bf16_t)(oacc[df][r] * rl);
    }
  }
}

// ---------------------------------------------------------------- launch
extern "C" void kernel_launch(void* const* d_in, const int* in_sizes, int n_in,
                              void* d_out, int out_size, void* d_ws, size_t ws_size,
                              hipStream_t stream) {
  const float* x      = (const float*)d_in[0];
  const float* rel    = (const float*)d_in[1];
  const float* ln1_g  = (const float*)d_in[2];
  const float* ln1_b  = (const float*)d_in[3];
  const float* w_qkv  = (const float*)d_in[4];
  const float* q_bias = (const float*)d_in[5];
  const float* v_bias = (const float*)d_in[6];
  const float* w_proj = (const float*)d_in[7];
  const float* b_proj = (const float*)d_in[8];
  const float* gamma1 = (const float*)d_in[9];
  const float* gamma2 = (const float*)d_in[10];
  const float* ln2t_g = (const float*)d_in[11];
  const float* ln2t_b = (const float*)d_in[12];
  const float* ln2i_g = (const float*)d_in[13];
  const float* ln2i_b = (const float*)d_in[14];
  const float* wt1    = (const float*)d_in[15];
  const float* bt1    = (const float*)d_in[16];
  const float* wt2    = (const float*)d_in[17];
  const float* bt2    = (const float*)d_in[18];
  const float* wi1    = (const float*)d_in[19];
  const float* bi1    = (const float*)d_in[20];
  const float* wi2    = (const float*)d_in[21];
  const float* bi2    = (const float*)d_in[22];
  float* out = (float*)d_out;

  char* ws = (char*)d_ws;
  bf16_t* wqkvb  = (bf16_t*)(ws + 0);
  bf16_t* wprojb = (bf16_t*)(ws + 3538944);
  bf16_t* wt1b   = (bf16_t*)(ws + 4718592);
  bf16_t* wi1b   = (bf16_t*)(ws + 9437184);
  bf16_t* wt2b   = (bf16_t*)(ws + 14155776);
  bf16_t* wi2b   = (bf16_t*)(ws + 18874368);
  bf16_t* n1     = (bf16_t*)(ws + 23592960);    // 9984x768 bf16; also n2p, o_mat
  float*  x1     = (float*) (ws + 38928384);    // 30.3MB; head doubles as vtmp
  bf16_t* qbuf   = (bf16_t*)(ws + 69206016);
  bf16_t* kbuf   = (bf16_t*)(ws + 84934656);
  bf16_t* vTbuf  = (bf16_t*)(ws + 100663296);
  bf16_t* biasb  = (bf16_t*)(ws + 116391936);   // 9.1 MB; dead before mlp1 reuses region
  bf16_t* vtmp   = (bf16_t*)(ws + 38928384);
  bf16_t* o_mat  = n1;
  bf16_t* n2p    = n1;
  bf16_t* hbuf   = qbuf;

  // one fused cast launch (weights + shifted bias)
  {
    CastArgs a;
    a.src[0] = w_qkv;  a.dst[0] = wqkvb;  a.n4[0] = (3 * C_ * C_) / 4;
    a.src[1] = w_proj; a.dst[1] = wprojb; a.n4[1] = (C_ * C_) / 4;
    a.src[2] = wt1;    a.dst[2] = wt1b;   a.n4[2] = (HID * C_) / 4;
    a.src[3] = wi1;    a.dst[3] = wi1b;   a.n4[3] = (HID * C_) / 4;
    a.src[4] = wt2;    a.dst[4] = wt2b;   a.n4[4] = (C_ * HID) / 4;
    a.src[5] = wi2;    a.dst[5] = wi2b;   a.n4[5] = (C_ * HID) / 4;
    a.src[6] = rel;    a.dst[6] = biasb;  a.n4[6] = (H_ * N_ * N_) / 4;
    int total4 = a.n4[0] + a.n4[1] + a.n4[2] + a.n4[3] + a.n4[4] + a.n4[5] + a.n4[6];
    cast_all<<<2048, 256, 0, stream>>>(a, total4);
  }
  ln_rows<<<M_REAL, 256, 0, stream>>>(x, ln1_g, ln1_b, n1);

  // QKV GEMM: 77 x 18 blocks (BM=128; grid already residency-capped)
  {
    EpiP P{}; P.bias = q_bias; P.bias2 = v_bias;
    P.ob0 = qbuf; P.ob1 = kbuf; P.ob2 = vtmp;
    gemm128<0><<<77 * 18, 256, 0, stream>>>(n1, wqkvb, wqkvb, C_, 77, 18, 0, P);
  }
  transpose_v<<<dim3(NP / 64, B_ * H_), 256, 0, stream>>>(vtmp, vTbuf);
  attn_fwd<<<1920, 256, 0, stream>>>(qbuf, kbuf, vTbuf, biasb, o_mat);

  // proj + residual -> x1 : BM=64 variant, 154 x 6 blocks (R ~3.6)
  {
    EpiP P{}; P.bias = b_proj; P.bias_i = b_proj; P.gamma = gamma1; P.xres = x; P.outf = x1;
    gemm64<1><<<154 * 6, 256, 0, stream>>>(o_mat, wprojb, wprojb, C_, 154, 6, 0, P);
  }
  ln2_pack<<<M_PAD, 256, 0, stream>>>(x1, ln2t_g, ln2t_b, ln2i_g, ln2i_b, n2p);

  // MLP fc1 + gelu: 78 x 24 blocks (BM=128; grid residency-capped)
  {
    EpiP P{}; P.bias = bt1; P.bias_i = bi1; P.ob0 = hbuf;
    gemm128<2><<<78 * 24, 256, 0, stream>>>(n2p, wt1b, wi1b, C_, 78, 24, 6, P);
  }
  // MLP fc2 + gamma2 residual -> d_out: BM=64 variant, 156 x 6 blocks
  // text/pad m-blocks 0-11 (rows <768), image 12+  -> tb=12
  {
    EpiP P{}; P.bias = bt2; P.bias_i = bi2; P.gamma = gamma2; P.xres = x1; P.outf = out;
    gemm64<3><<<156 * 6, 256, 0, stream>>>(hbuf, wt2b, wi2b, HID, 156, 6, 12, P);
  }
}